// Round 1
// baseline (2711.428 us; speedup 1.0000x reference)
//
#include <hip/hip_runtime.h>
#include <stdint.h>

// Problem constants (from reference setup_inputs)
#define B_ 2
#define T_ 2048
#define S_ 77
#define C_ 1024
#define E_ 4
#define H_ 2816
#define NH_ 8
#define HD_ 128
#define N_ (B_*T_)          // 4096 tokens
#define MAXGB (N_/64 + E_)  // max grouped row-tiles (68)

// JAX RNG mode: threefry "partitionable" (default True since jax 0.4.36):
//   bits32[i] = o0 ^ o1 of threefry2x32(key, (0, i)).
// If validation fails with large scattered per-row errors, flip to 0
// (legacy mode: pair (i, i+size/2), take o0 for first half / o1 for second).
#define JAX_PARTITIONABLE 1

// ---------------- Threefry-2x32 (JAX-compatible) ----------------
__device__ __forceinline__ uint32_t rotl32(uint32_t v, int r){ return (v<<r)|(v>>(32-r)); }

__device__ __forceinline__ void threefry2x32(uint32_t k0, uint32_t k1,
                                             uint32_t x, uint32_t y,
                                             uint32_t& o0, uint32_t& o1){
  uint32_t k2 = k0 ^ k1 ^ 0x1BD11BDAu;
  x += k0; y += k1;
#define TFR(r) { x += y; y = rotl32(y, r); y ^= x; }
  TFR(13) TFR(15) TFR(26) TFR(6)   x += k1; y += k2 + 1u;
  TFR(17) TFR(29) TFR(16) TFR(24)  x += k2; y += k0 + 2u;
  TFR(13) TFR(15) TFR(26) TFR(6)   x += k0; y += k1 + 3u;
  TFR(17) TFR(29) TFR(16) TFR(24)  x += k1; y += k2 + 4u;
  TFR(13) TFR(15) TFR(26) TFR(6)   x += k2; y += k0 + 5u;
#undef TFR
  o0 = x; o1 = y;
}

__device__ __forceinline__ float gumbel_from_bits(uint32_t bits){
  // replicate jax.random.uniform(minval=tiny, maxval=1) -> -log(-log(u))
  const float TINY = 1.17549435e-38f;
  float f = __uint_as_float((bits >> 9) | 0x3f800000u) - 1.0f; // [0,1)
  float u = fmaxf(TINY, f + TINY);
  return -logf(-logf(u));
}

__device__ __forceinline__ float jax_gumbel(uint32_t k0, uint32_t k1, uint32_t idx, uint32_t half){
  uint32_t a, b;
#if JAX_PARTITIONABLE
  threefry2x32(k0, k1, 0u, idx, a, b);
  return gumbel_from_bits(a ^ b);
#else
  if (idx < half){ threefry2x32(k0, k1, idx, idx + half, a, b); return gumbel_from_bits(a); }
  threefry2x32(k0, k1, idx - half, idx, a, b); return gumbel_from_bits(b);
#endif
}

// ---------------- small setup: language gating ----------------
__global__ __launch_bounds__(256) void setup_lang(
    const float* __restrict__ lang_embed, const float* __restrict__ gate_w,
    const float* __restrict__ gate_b, const int* __restrict__ language,
    float* __restrict__ langP, int* __restrict__ lang_sel, int* __restrict__ counts)
{
  __shared__ float red[256];
  __shared__ float logits[8];
  int tid = threadIdx.x;
  for (int be = 0; be < 8; ++be){
    int b = be >> 2, e = be & 3;
    const float* emb = lang_embed + (size_t)language[b] * C_;
    const float* gw  = gate_w + (size_t)e * C_;
    float p = 0.f;
    for (int c = tid; c < C_; c += 256) p += emb[c] * gw[c];
    red[tid] = p; __syncthreads();
    for (int s = 128; s > 0; s >>= 1){
      if (tid < s) red[tid] += red[tid + s];
      __syncthreads();
    }
    if (tid == 0) logits[be] = red[0] + gate_b[e];
    __syncthreads();
  }
  if (tid == 0){
    for (int b = 0; b < B_; ++b){
      float z[E_], m = -3.4e38f;
      for (int e = 0; e < E_; ++e){
        float g = jax_gumbel(0u, 1u, (uint32_t)(b*E_ + e), 4u);
        z[e] = (logits[b*E_ + e] + g) * 0.5f;   // / TEMP(=2)
        m = fmaxf(m, z[e]);
      }
      float y[E_], sum = 0.f;
      for (int e = 0; e < E_; ++e){ y[e] = expf(z[e] - m); sum += y[e]; }
      for (int e = 0; e < E_; ++e) y[e] = y[e] / sum;
      int best = 0; float bv = y[0];
      for (int e = 1; e < E_; ++e) if (y[e] > bv){ bv = y[e]; best = e; }
      lang_sel[b] = best;
      for (int e = 0; e < E_; ++e)
        langP[b*E_ + e] = ((e == best) ? 1.0f : 0.0f) - y[e] + y[e]; // ST-estimator value
    }
    for (int e = 0; e < E_; ++e) counts[e] = 0;
  }
}

// ---------------- shared GEMM helpers (NT: C = A * B^T) ----------------
// 256 threads, 64x64 tile, BK=16, each thread 4x4 micro-tile.
#define GEMM_PROLOG \
  int tid = threadIdx.x; \
  int tr = tid >> 4, tc = tid & 15; \
  int lr = tid >> 2, lk = (tid & 3) << 2;

#define FMA16(acc, a, b) \
  acc[0][0] += a.x*b.x; acc[0][1] += a.x*b.y; acc[0][2] += a.x*b.z; acc[0][3] += a.x*b.w; \
  acc[1][0] += a.y*b.x; acc[1][1] += a.y*b.y; acc[1][2] += a.y*b.z; acc[1][3] += a.y*b.w; \
  acc[2][0] += a.z*b.x; acc[2][1] += a.z*b.y; acc[2][2] += a.z*b.z; acc[2][3] += a.z*b.w; \
  acc[3][0] += a.w*b.x; acc[3][1] += a.w*b.y; acc[3][2] += a.w*b.z; acc[3][3] += a.w*b.w;

#define STORE_T(Sm, v) \
  Sm[(lk+0)*64 + lr] = v.x; Sm[(lk+1)*64 + lr] = v.y; \
  Sm[(lk+2)*64 + lr] = v.z; Sm[(lk+3)*64 + lr] = v.w;

// generic NT GEMM + bias (used for q/kv/out projections); N % 64 == 0, K % 16 == 0
__global__ __launch_bounds__(256) void gemm_nt_bias(
    const float* __restrict__ A, int lda,
    const float* __restrict__ Bm, int ldb,
    const float* __restrict__ bias,
    float* __restrict__ Cm, int ldc,
    int M, int K)
{
  __shared__ __align__(16) float As[16*64];
  __shared__ __align__(16) float Bs[16*64];
  GEMM_PROLOG
  int m0 = blockIdx.y << 6, n0 = blockIdx.x << 6;
  float acc[4][4] = {};
  bool aok = (m0 + lr) < M;
  const float4* Ap = (const float4*)(A + (size_t)(m0 + lr) * lda + lk);
  const float4* Bp = (const float4*)(Bm + (size_t)(n0 + lr) * ldb + lk);
  for (int k0 = 0; k0 < K; k0 += 16){
    float4 av = aok ? Ap[k0 >> 2] : float4{0.f,0.f,0.f,0.f};
    float4 bv = Bp[k0 >> 2];
    STORE_T(As, av) STORE_T(Bs, bv)
    __syncthreads();
#pragma unroll
    for (int kk = 0; kk < 16; ++kk){
      float4 a = *(const float4*)&As[kk*64 + (tr<<2)];
      float4 b = *(const float4*)&Bs[kk*64 + (tc<<2)];
      FMA16(acc, a, b)
    }
    __syncthreads();
  }
#pragma unroll
  for (int i = 0; i < 4; ++i){
    int m = m0 + (tr<<2) + i;
    if (m >= M) continue;
#pragma unroll
    for (int j = 0; j < 4; ++j){
      int n = n0 + (tc<<2) + j;
      Cm[(size_t)m*ldc + n] = acc[i][j] + bias[n];
    }
  }
}

// stage-1 expert FFN, gate half: H = silu(X W1[e]^T) * (X W3[e]^T), e per batch
__global__ __launch_bounds__(256) void ffn1_gate(
    const float* __restrict__ X, const float* __restrict__ W1,
    const float* __restrict__ W3, const int* __restrict__ lang_sel,
    float* __restrict__ Hout)
{
  __shared__ __align__(16) float As[16*64];
  __shared__ __align__(16) float B1s[16*64];
  __shared__ __align__(16) float B3s[16*64];
  GEMM_PROLOG
  int m0 = blockIdx.y << 6, n0 = blockIdx.x << 6;
  int e = lang_sel[(m0 >= T_) ? 1 : 0];
  float acc1[4][4] = {}, acc3[4][4] = {};
  const float4* Ap  = (const float4*)(X + (size_t)(m0 + lr) * C_ + lk);
  const float4* B1p = (const float4*)(W1 + (size_t)e*H_*C_ + (size_t)(n0 + lr) * C_ + lk);
  const float4* B3p = (const float4*)(W3 + (size_t)e*H_*C_ + (size_t)(n0 + lr) * C_ + lk);
  for (int k0 = 0; k0 < C_; k0 += 16){
    float4 av = Ap[k0 >> 2];
    float4 b1 = B1p[k0 >> 2];
    float4 b3 = B3p[k0 >> 2];
    STORE_T(As, av) STORE_T(B1s, b1) STORE_T(B3s, b3)
    __syncthreads();
#pragma unroll
    for (int kk = 0; kk < 16; ++kk){
      float4 a = *(const float4*)&As[kk*64 + (tr<<2)];
      float4 b = *(const float4*)&B1s[kk*64 + (tc<<2)];
      float4 c = *(const float4*)&B3s[kk*64 + (tc<<2)];
      FMA16(acc1, a, b)
      FMA16(acc3, a, c)
    }
    __syncthreads();
  }
#pragma unroll
  for (int i = 0; i < 4; ++i){
    int m = m0 + (tr<<2) + i;
#pragma unroll
    for (int j = 0; j < 4; ++j){
      int n = n0 + (tc<<2) + j;
      float s1 = acc1[i][j];
      float hgv = (s1 / (1.0f + expf(-s1))) * acc3[i][j]; // silu(s1)*s3
      Hout[(size_t)m*H_ + n] = hgv;
    }
  }
}

// stage-1 expert FFN, out half: F = H W2[e]^T  (W2[e] is [C,H] row-major)
__global__ __launch_bounds__(256) void ffn1_out(
    const float* __restrict__ Hin, const float* __restrict__ W2,
    const int* __restrict__ lang_sel, float* __restrict__ F)
{
  __shared__ __align__(16) float As[16*64];
  __shared__ __align__(16) float Bs[16*64];
  GEMM_PROLOG
  int m0 = blockIdx.y << 6, n0 = blockIdx.x << 6;
  int e = lang_sel[(m0 >= T_) ? 1 : 0];
  float acc[4][4] = {};
  const float4* Ap = (const float4*)(Hin + (size_t)(m0 + lr) * H_ + lk);
  const float4* Bp = (const float4*)(W2 + (size_t)e*C_*H_ + (size_t)(n0 + lr) * H_ + lk);
  for (int k0 = 0; k0 < H_; k0 += 16){
    float4 av = Ap[k0 >> 2];
    float4 bv = Bp[k0 >> 2];
    STORE_T(As, av) STORE_T(Bs, bv)
    __syncthreads();
#pragma unroll
    for (int kk = 0; kk < 16; ++kk){
      float4 a = *(const float4*)&As[kk*64 + (tr<<2)];
      float4 b = *(const float4*)&Bs[kk*64 + (tc<<2)];
      FMA16(acc, a, b)
    }
    __syncthreads();
  }
#pragma unroll
  for (int i = 0; i < 4; ++i){
    int m = m0 + (tr<<2) + i;
#pragma unroll
    for (int j = 0; j < 4; ++j){
      int n = n0 + (tc<<2) + j;
      F[(size_t)m*C_ + n] = acc[i][j];
    }
  }
}

// ---------------- cross attention ----------------
// grid (T/64, NH, B); K then V staged in LDS; scores tile in LDS.
__global__ __launch_bounds__(256) void attn_kernel(
    const float* __restrict__ Q, const float* __restrict__ KV, float* __restrict__ AO)
{
  __shared__ float kvs[S_*HD_];      // 77*128 floats, K then reused for V
  __shared__ float sc[64*80];        // scores [64 q][77 k], padded
  int tid = threadIdx.x;
  int b = blockIdx.z, h = blockIdx.y, q0 = blockIdx.x << 6;
  const float scale = 0.08838834764831845f; // 1/sqrt(128)
  for (int i = tid; i < S_*HD_; i += 256){
    int s = i >> 7, d = i & 127;
    kvs[i] = KV[((size_t)(b*S_ + s)) * (2*C_) + h*HD_ + d];
  }
  __syncthreads();
  for (int i = tid; i < 64*S_; i += 256){
    int q = i / S_; int k = i - q*S_;
    const float* qp = Q + ((size_t)(b*T_ + q0 + q)) * C_ + h*HD_;
    const float* kp = &kvs[k*HD_];
    float acc = 0.f;
#pragma unroll 4
    for (int d = 0; d < HD_; ++d) acc += qp[d] * kp[d];
    sc[q*80 + k] = acc * scale;
  }
  __syncthreads();
  if (tid < 64){
    float m = -3.4e38f;
    for (int k = 0; k < S_; ++k) m = fmaxf(m, sc[tid*80 + k]);
    float sum = 0.f;
    for (int k = 0; k < S_; ++k){ float ev = expf(sc[tid*80 + k] - m); sc[tid*80 + k] = ev; sum += ev; }
    for (int k = 0; k < S_; ++k) sc[tid*80 + k] = sc[tid*80 + k] / sum;
  }
  __syncthreads();
  for (int i = tid; i < S_*HD_; i += 256){
    int s = i >> 7, d = i & 127;
    kvs[i] = KV[((size_t)(b*S_ + s)) * (2*C_) + C_ + h*HD_ + d];  // V
  }
  __syncthreads();
  for (int i = tid; i < 64*HD_; i += 256){
    int q = i >> 7, d = i & 127;
    float acc = 0.f;
    for (int k = 0; k < S_; ++k) acc += sc[q*80 + k] * kvs[k*HD_ + d];
    AO[((size_t)(b*T_ + q0 + q)) * C_ + h*HD_ + d] = acc;
  }
}

// ---------------- caption gating (per token) ----------------
__global__ __launch_bounds__(256) void cap_gate(
    const float* __restrict__ CR, const float* __restrict__ gw, const float* __restrict__ gb,
    int* __restrict__ cap_sel, float* __restrict__ capP, int* __restrict__ counts)
{
  int tid = threadIdx.x, wave = tid >> 6, lane = tid & 63;
  for (int r = 0; r < 4; ++r){
    int row = (blockIdx.x << 4) + (wave << 2) + r;   // grid 256 -> 4096 rows
    const float* xp = CR + (size_t)row * C_;
    float l[E_];
#pragma unroll
    for (int e = 0; e < E_; ++e){
      const float* w = gw + (size_t)e * C_;
      float p = 0.f;
      for (int c = lane; c < C_; c += 64) p += xp[c] * w[c];
#pragma unroll
      for (int off = 32; off; off >>= 1) p += __shfl_xor(p, off);
      l[e] = p + gb[e];
    }
    if (lane == 0){
      float z[E_], m = -3.4e38f;
      for (int e = 0; e < E_; ++e){
        float g = jax_gumbel(0u, 2u, (uint32_t)(row*E_ + e), (uint32_t)(N_*E_/2));
        z[e] = (l[e] + g) * 0.5f;
        m = fmaxf(m, z[e]);
      }
      float y[E_], sum = 0.f;
      for (int e = 0; e < E_; ++e){ y[e] = expf(z[e] - m); sum += y[e]; }
      for (int e = 0; e < E_; ++e) y[e] = y[e] / sum;
      int best = 0; float bv = y[0];
      for (int e = 1; e < E_; ++e) if (y[e] > bv){ bv = y[e]; best = e; }
      cap_sel[row] = best;
      atomicAdd(&counts[best], 1);
      for (int e = 0; e < E_; ++e)
        capP[(size_t)row*E_ + e] = ((e == best) ? 1.0f : 0.0f) - y[e] + y[e];
    }
  }
}

// ---------------- expert grouping ----------------
__global__ void build_groups(const int* __restrict__ counts, int* __restrict__ offs,
                             int* __restrict__ cursor, int* __restrict__ bmap_e,
                             int* __restrict__ bmap_s)
{
  offs[0] = 0;
  for (int e = 0; e < E_; ++e){ offs[e+1] = offs[e] + counts[e]; cursor[e] = offs[e]; }
  int idx = 0;
  for (int e = 0; e < E_; ++e)
    for (int s = offs[e]; s < offs[e+1]; s += 64){ bmap_e[idx] = e; bmap_s[idx] = s; ++idx; }
  for (; idx < MAXGB; ++idx) bmap_e[idx] = -1;
}

__global__ __launch_bounds__(256) void scatter_perm(
    const int* __restrict__ cap_sel, int* __restrict__ cursor, int* __restrict__ perm)
{
  int row = blockIdx.x * 256 + threadIdx.x;
  int e = cap_sel[row];
  int pos = atomicAdd(&cursor[e], 1);
  perm[pos] = row;
}

// stage-2 expert FFN (grouped by cap_sel), gate half; rows gathered via perm
__global__ __launch_bounds__(256) void ffn2_gate(
    const float* __restrict__ F, const float* __restrict__ W1, const float* __restrict__ W3,
    const int* __restrict__ bmap_e, const int* __restrict__ bmap_s,
    const int* __restrict__ offs, const int* __restrict__ perm,
    float* __restrict__ Hout)
{
  int e = bmap_e[blockIdx.y];
  if (e < 0) return;
  int sbase = bmap_s[blockIdx.y];
  int valid = offs[e+1] - sbase; if (valid > 64) valid = 64;
  __shared__ __align__(16) float As[16*64];
  __shared__ __align__(16) float B1s[16*64];
  __shared__ __align__(16) float B3s[16*64];
  GEMM_PROLOG
  int n0 = blockIdx.x << 6;
  float acc1[4][4] = {}, acc3[4][4] = {};
  bool aok = lr < valid;
  const float4* Ap  = (const float4*)(F + (size_t)(aok ? perm[sbase + lr] : 0) * C_ + lk);
  const float4* B1p = (const float4*)(W1 + (size_t)e*H_*C_ + (size_t)(n0 + lr) * C_ + lk);
  const float4* B3p = (const float4*)(W3 + (size_t)e*H_*C_ + (size_t)(n0 + lr) * C_ + lk);
  for (int k0 = 0; k0 < C_; k0 += 16){
    float4 av = aok ? Ap[k0 >> 2] : float4{0.f,0.f,0.f,0.f};
    float4 b1 = B1p[k0 >> 2];
    float4 b3 = B3p[k0 >> 2];
    STORE_T(As, av) STORE_T(B1s, b1) STORE_T(B3s, b3)
    __syncthreads();
#pragma unroll
    for (int kk = 0; kk < 16; ++kk){
      float4 a = *(const float4*)&As[kk*64 + (tr<<2)];
      float4 b = *(const float4*)&B1s[kk*64 + (tc<<2)];
      float4 c = *(const float4*)&B3s[kk*64 + (tc<<2)];
      FMA16(acc1, a, b)
      FMA16(acc3, a, c)
    }
    __syncthreads();
  }
#pragma unroll
  for (int i = 0; i < 4; ++i){
    int rloc = (tr<<2) + i;
    if (rloc >= valid) continue;
#pragma unroll
    for (int j = 0; j < 4; ++j){
      int n = n0 + (tc<<2) + j;
      float s1 = acc1[i][j];
      Hout[(size_t)(sbase + rloc)*H_ + n] = (s1 / (1.0f + expf(-s1))) * acc3[i][j];
    }
  }
}

// stage-2 out half + final sum: out[orig] = F[orig] + H2 W2[e]^T
__global__ __launch_bounds__(256) void ffn2_out(
    const float* __restrict__ Hin, const float* __restrict__ W2,
    const int* __restrict__ bmap_e, const int* __restrict__ bmap_s,
    const int* __restrict__ offs, const int* __restrict__ perm,
    const float* __restrict__ F, float* __restrict__ out)
{
  int e = bmap_e[blockIdx.y];
  if (e < 0) return;
  int sbase = bmap_s[blockIdx.y];
  int valid = offs[e+1] - sbase; if (valid > 64) valid = 64;
  __shared__ __align__(16) float As[16*64];
  __shared__ __align__(16) float Bs[16*64];
  GEMM_PROLOG
  int n0 = blockIdx.x << 6;
  float acc[4][4] = {};
  bool aok = lr < valid;
  const float4* Ap = (const float4*)(Hin + (size_t)(sbase + (aok ? lr : 0)) * H_ + lk);
  const float4* Bp = (const float4*)(W2 + (size_t)e*C_*H_ + (size_t)(n0 + lr) * H_ + lk);
  for (int k0 = 0; k0 < H_; k0 += 16){
    float4 av = aok ? Ap[k0 >> 2] : float4{0.f,0.f,0.f,0.f};
    float4 bv = Bp[k0 >> 2];
    STORE_T(As, av) STORE_T(Bs, bv)
    __syncthreads();
#pragma unroll
    for (int kk = 0; kk < 16; ++kk){
      float4 a = *(const float4*)&As[kk*64 + (tr<<2)];
      float4 b = *(const float4*)&Bs[kk*64 + (tc<<2)];
      FMA16(acc, a, b)
    }
    __syncthreads();
  }
#pragma unroll
  for (int i = 0; i < 4; ++i){
    int rloc = (tr<<2) + i;
    if (rloc >= valid) continue;
    int orig = perm[sbase + rloc];
#pragma unroll
    for (int j = 0; j < 4; ++j){
      int n = n0 + (tc<<2) + j;
      out[(size_t)orig*C_ + n] = F[(size_t)orig*C_ + n] + acc[i][j];
    }
  }
}

// ---------------- loss ----------------
__global__ __launch_bounds__(256) void loss_kernel(
    const float* __restrict__ capP, const float* __restrict__ langP, float* __restrict__ out_loss)
{
  __shared__ float red[4][256];
  int tid = threadIdx.x;
  float p0=0.f, p1=0.f, p2=0.f, p3=0.f;
  for (int r = tid; r < N_; r += 256){
    const float* p = capP + (size_t)r*E_;
    p0 += p[0]; p1 += p[1]; p2 += p[2]; p3 += p[3];
  }
  red[0][tid]=p0; red[1][tid]=p1; red[2][tid]=p2; red[3][tid]=p3;
  __syncthreads();
  for (int s = 128; s > 0; s >>= 1){
    if (tid < s){
      red[0][tid]+=red[0][tid+s]; red[1][tid]+=red[1][tid+s];
      red[2][tid]+=red[2][tid+s]; red[3][tid]+=red[3][tid+s];
    }
    __syncthreads();
  }
  if (tid == 0){
    float loss = 0.f;
    for (int e = 0; e < E_; ++e){
      float ul = (langP[e] + langP[E_ + e]) * 0.5f;
      loss += ul * logf(ul + 1e-10f);
    }
    for (int e = 0; e < E_; ++e){
      float uc = red[e][0] * (1.0f / N_);
      loss += uc * logf(uc + 1e-10f);
    }
    out_loss[0] = loss;
  }
}

// ---------------- host launch ----------------
extern "C" void kernel_launch(void* const* d_in, const int* in_sizes, int n_in,
                              void* d_out, int out_size, void* d_ws, size_t ws_size,
                              hipStream_t stream)
{
  const float* x          = (const float*)d_in[0];
  const float* caption    = (const float*)d_in[2];
  const int*   language   = (const int*)  d_in[3];
  const float* lang_embed = (const float*)d_in[4];
  const float* lang_gw    = (const float*)d_in[5];
  const float* lang_gb    = (const float*)d_in[6];
  const float* lang_w1    = (const float*)d_in[7];
  const float* lang_w2    = (const float*)d_in[8];
  const float* lang_w3    = (const float*)d_in[9];
  const float* in_w       = (const float*)d_in[10];
  const float* in_b       = (const float*)d_in[11];
  const float* out_w      = (const float*)d_in[12];
  const float* out_b      = (const float*)d_in[13];
  const float* cap_gw     = (const float*)d_in[14];
  const float* cap_gb     = (const float*)d_in[15];
  const float* cap_w1     = (const float*)d_in[16];
  const float* cap_w2     = (const float*)d_in[17];
  const float* cap_w3     = (const float*)d_in[18];
  float* out = (float*)d_out;

  // ws layout (~98 MB)
  float* ws   = (float*)d_ws;
  float* F    = ws;                          // N*C   first_out
  float* Hb   = F  + (size_t)N_*C_;          // N*H   FFN hidden (stage1, then stage2 perm-order)
  float* Qb   = Hb + (size_t)N_*H_;          // N*C   q, then reused as cross
  float* AOb  = Qb + (size_t)N_*C_;          // N*C   attention out
  float* KVb  = AOb + (size_t)N_*C_;         // B*S*2C  k|v
  float* capP = KVb + (size_t)B_*S_*2*C_;    // N*E   cap ST-probs
  float* langP= capP + (size_t)N_*E_;        // 8
  int* ip       = (int*)(langP + 8);
  int* lang_sel = ip;  ip += 2;
  int* cap_sel  = ip;  ip += N_;
  int* counts   = ip;  ip += E_;
  int* offs     = ip;  ip += E_ + 1;
  int* cursor   = ip;  ip += E_;
  int* bmap_e   = ip;  ip += MAXGB;
  int* bmap_s   = ip;  ip += MAXGB;
  int* perm     = ip;  ip += N_;

  setup_lang<<<1, 256, 0, stream>>>(lang_embed, lang_gw, lang_gb, language, langP, lang_sel, counts);
  ffn1_gate<<<dim3(H_/64, N_/64), 256, 0, stream>>>(x, lang_w1, lang_w3, lang_sel, Hb);
  ffn1_out <<<dim3(C_/64, N_/64), 256, 0, stream>>>(Hb, lang_w2, lang_sel, F);
  // q projection
  gemm_nt_bias<<<dim3(C_/64, N_/64), 256, 0, stream>>>(F, C_, in_w, C_, in_b, Qb, C_, N_, C_);
  // k|v projection of caption
  gemm_nt_bias<<<dim3((2*C_)/64, (B_*S_ + 63)/64), 256, 0, stream>>>(
      caption, C_, in_w + (size_t)C_*C_, C_, in_b + C_, KVb, 2*C_, B_*S_, C_);
  attn_kernel<<<dim3(T_/64, NH_, B_), 256, 0, stream>>>(Qb, KVb, AOb);
  // out projection -> cross (reuse Qb)
  gemm_nt_bias<<<dim3(C_/64, N_/64), 256, 0, stream>>>(AOb, C_, out_w, C_, out_b, Qb, C_, N_, C_);
  cap_gate<<<N_/16, 256, 0, stream>>>(Qb, cap_gw, cap_gb, cap_sel, capP, counts);
  build_groups<<<1, 1, 0, stream>>>(counts, offs, cursor, bmap_e, bmap_s);
  scatter_perm<<<N_/256, 256, 0, stream>>>(cap_sel, cursor, perm);
  ffn2_gate<<<dim3(H_/64, MAXGB), 256, 0, stream>>>(F, cap_w1, cap_w3, bmap_e, bmap_s, offs, perm, Hb);
  ffn2_out <<<dim3(C_/64, MAXGB), 256, 0, stream>>>(Hb, cap_w2, bmap_e, bmap_s, offs, perm, F, out);
  loss_kernel<<<1, 256, 0, stream>>>(capP, langP, out + (size_t)N_*C_);
}

// Round 2
// 1009.494 us; speedup vs baseline: 2.6859x; 2.6859x over previous
//
#include <hip/hip_runtime.h>
#include <stdint.h>

// Problem constants
#define B_ 2
#define T_ 2048
#define S_ 77
#define C_ 1024
#define E_ 4
#define H_ 2816
#define NH_ 8
#define HD_ 128
#define N_ (B_*T_)            // 4096 tokens
#define GTILE 128
#define MAXGB (N_/GTILE + E_) // 36 grouped row-tiles
#define PEsz ((size_t)H_*C_)  // per-expert matrix elems (2,883,584)

typedef _Float16 h8 __attribute__((ext_vector_type(8)));
typedef _Float16 h4 __attribute__((ext_vector_type(4)));
typedef float f4 __attribute__((ext_vector_type(4)));

#define SWZ(r) (((r)>>1)&3)

__device__ __forceinline__ void gload16(const void* g, void* l){
  __builtin_amdgcn_global_load_lds((const __attribute__((address_space(1))) void*)g,
                                   (__attribute__((address_space(3))) void*)l, 16, 0, 0);
}

// ---------------- Threefry-2x32 (JAX partitionable) ----------------
__device__ __forceinline__ uint32_t rotl32(uint32_t v, int r){ return (v<<r)|(v>>(32-r)); }
__device__ __forceinline__ void threefry2x32(uint32_t k0, uint32_t k1,
                                             uint32_t x, uint32_t y,
                                             uint32_t& o0, uint32_t& o1){
  uint32_t k2 = k0 ^ k1 ^ 0x1BD11BDAu;
  x += k0; y += k1;
#define TFR(r) { x += y; y = rotl32(y, r); y ^= x; }
  TFR(13) TFR(15) TFR(26) TFR(6)   x += k1; y += k2 + 1u;
  TFR(17) TFR(29) TFR(16) TFR(24)  x += k2; y += k0 + 2u;
  TFR(13) TFR(15) TFR(26) TFR(6)   x += k0; y += k1 + 3u;
  TFR(17) TFR(29) TFR(16) TFR(24)  x += k1; y += k2 + 4u;
  TFR(13) TFR(15) TFR(26) TFR(6)   x += k2; y += k0 + 5u;
#undef TFR
  o0 = x; o1 = y;
}
__device__ __forceinline__ float gumbel_from_bits(uint32_t bits){
  const float TINY = 1.17549435e-38f;
  float f = __uint_as_float((bits >> 9) | 0x3f800000u) - 1.0f;
  float u = fmaxf(TINY, f + TINY);
  return -logf(-logf(u));
}
__device__ __forceinline__ float jax_gumbel(uint32_t k0, uint32_t k1, uint32_t idx){
  uint32_t a, b;
  threefry2x32(k0, k1, 0u, idx, a, b);
  return gumbel_from_bits(a ^ b);
}

// ---------------- language gating ----------------
__global__ __launch_bounds__(256) void setup_lang(
    const float* __restrict__ lang_embed, const float* __restrict__ gate_w,
    const float* __restrict__ gate_b, const int* __restrict__ language,
    float* __restrict__ langP, int* __restrict__ lang_sel, int* __restrict__ counts)
{
  __shared__ float red[256];
  __shared__ float logits[8];
  int tid = threadIdx.x;
  for (int be = 0; be < 8; ++be){
    int b = be >> 2, e = be & 3;
    const float* emb = lang_embed + (size_t)language[b] * C_;
    const float* gw  = gate_w + (size_t)e * C_;
    float p = 0.f;
    for (int c = tid; c < C_; c += 256) p += emb[c] * gw[c];
    red[tid] = p; __syncthreads();
    for (int s = 128; s > 0; s >>= 1){
      if (tid < s) red[tid] += red[tid + s];
      __syncthreads();
    }
    if (tid == 0) logits[be] = red[0] + gate_b[e];
    __syncthreads();
  }
  if (tid == 0){
    for (int b = 0; b < B_; ++b){
      float z[E_], m = -3.4e38f;
      for (int e = 0; e < E_; ++e){
        float gmb = jax_gumbel(0u, 1u, (uint32_t)(b*E_ + e));
        z[e] = (logits[b*E_ + e] + gmb) * 0.5f;
        m = fmaxf(m, z[e]);
      }
      float y[E_], sum = 0.f;
      for (int e = 0; e < E_; ++e){ y[e] = expf(z[e] - m); sum += y[e]; }
      for (int e = 0; e < E_; ++e) y[e] = y[e] / sum;
      int best = 0; float bv = y[0];
      for (int e = 1; e < E_; ++e) if (y[e] > bv){ bv = y[e]; best = e; }
      lang_sel[b] = best;
      for (int e = 0; e < E_; ++e)
        langP[b*E_ + e] = ((e == best) ? 1.0f : 0.0f) - y[e] + y[e];
    }
    for (int e = 0; e < E_; ++e) counts[e] = 0;
  }
}

// ---------------- conversion kernels ----------------
__global__ __launch_bounds__(256) void conv_split(const float* __restrict__ s,
    _Float16* __restrict__ hi, _Float16* __restrict__ lo, long n4){
  long i = (long)blockIdx.x*256 + threadIdx.x;
  long stride = (long)gridDim.x*256;
  for (; i < n4; i += stride){
    float4 v = ((const float4*)s)[i];
    h4 h, L;
    h[0]=(_Float16)v.x; h[1]=(_Float16)v.y; h[2]=(_Float16)v.z; h[3]=(_Float16)v.w;
    L[0]=(_Float16)(v.x-(float)h[0]); L[1]=(_Float16)(v.y-(float)h[1]);
    L[2]=(_Float16)(v.z-(float)h[2]); L[3]=(_Float16)(v.w-(float)h[3]);
    ((h4*)hi)[i] = h; ((h4*)lo)[i] = L;
  }
}
__global__ __launch_bounds__(256) void conv_plain(const float* __restrict__ s,
    _Float16* __restrict__ d, long n4){
  long i = (long)blockIdx.x*256 + threadIdx.x;
  long stride = (long)gridDim.x*256;
  for (; i < n4; i += stride){
    float4 v = ((const float4*)s)[i];
    h4 h;
    h[0]=(_Float16)v.x; h[1]=(_Float16)v.y; h[2]=(_Float16)v.z; h[3]=(_Float16)v.w;
    ((h4*)d)[i] = h;
  }
}
__global__ __launch_bounds__(256) void conv_split_sel(const float* __restrict__ base,
    const int* __restrict__ sel, int slot,
    _Float16* __restrict__ hi, _Float16* __restrict__ lo, long n4){
  const float* s = base + (size_t)sel[slot]*PEsz;
  long i = (long)blockIdx.x*256 + threadIdx.x;
  long stride = (long)gridDim.x*256;
  for (; i < n4; i += stride){
    float4 v = ((const float4*)s)[i];
    h4 h, L;
    h[0]=(_Float16)v.x; h[1]=(_Float16)v.y; h[2]=(_Float16)v.z; h[3]=(_Float16)v.w;
    L[0]=(_Float16)(v.x-(float)h[0]); L[1]=(_Float16)(v.y-(float)h[1]);
    L[2]=(_Float16)(v.z-(float)h[2]); L[3]=(_Float16)(v.w-(float)h[3]);
    ((h4*)hi)[i] = h; ((h4*)lo)[i] = L;
  }
}

// ---------------- gate GEMM: H = silu(A W1^T) * (A W3^T) ----------------
// tile M=128, N=64; 4 waves (2x2), wave-tile 64x32; BK=32; K=C_=1024
// SPLIT=1: ffn1 (A hi/lo, B hi/lo, 3-MFMA, expert slot by m-block, out H hi/lo)
// SPLIT=0: ffn2 (A=F_hi gathered via perm, B plain f16 by bmap expert, out H2 f16)
template<bool SPLIT>
__global__ __launch_bounds__(256) void gemm_gate(
    const _Float16* __restrict__ Ahi, const _Float16* __restrict__ Alo,
    const _Float16* __restrict__ B1h, const _Float16* __restrict__ B1l,
    const _Float16* __restrict__ B3h, const _Float16* __restrict__ B3l,
    const int* __restrict__ bmap_e, const int* __restrict__ bmap_s,
    const int* __restrict__ offs, const int* __restrict__ perm,
    _Float16* __restrict__ Hhi, _Float16* __restrict__ Hlo)
{
  __shared__ __align__(16) _Float16 AT_h[128*32];
  __shared__ __align__(16) _Float16 AT_l[SPLIT ? 128*32 : 8];
  __shared__ __align__(16) _Float16 BT[(SPLIT?4:2)*64*32];

  const int tid=threadIdx.x, w=tid>>6, l=tid&63;
  const int n0 = blockIdx.x<<6;
  int m0, valid;
  size_t boff;
  if constexpr (SPLIT){
    m0 = blockIdx.y<<7; valid = 128;
    boff = (m0>=T_) ? PEsz : 0;
  } else {
    int e = bmap_e[blockIdx.y]; if (e<0) return;
    m0 = bmap_s[blockIdx.y];
    int v = offs[e+1]-m0; valid = v>128?128:v;
    boff = (size_t)e*PEsz;
  }
  const int ra0 = w*16 + (l>>2), ra1 = 64 + w*16 + (l>>2);
  const int rb  = w*16 + (l>>2);
  const int sA = l&3;
  size_t ga0, ga1;
  if constexpr (SPLIT){ ga0 = (size_t)(m0+ra0); ga1 = (size_t)(m0+ra1); }
  else {
    int i0 = m0+ra0; if (i0>=N_) i0=m0;
    int i1 = m0+ra1; if (i1>=N_) i1=m0;
    ga0 = (size_t)perm[i0]; ga1 = (size_t)perm[i1];
  }
  const _Float16* pA0h = Ahi + ga0*C_ + ((sA^SWZ(ra0))<<3);
  const _Float16* pA1h = Ahi + ga1*C_ + ((sA^SWZ(ra1))<<3);
  const _Float16* pA0l = SPLIT ? (Alo + ga0*C_ + ((sA^SWZ(ra0))<<3)) : (const _Float16*)nullptr;
  const _Float16* pA1l = SPLIT ? (Alo + ga1*C_ + ((sA^SWZ(ra1))<<3)) : (const _Float16*)nullptr;
  const size_t gb = boff + (size_t)(n0+rb)*C_ + ((sA^SWZ(rb))<<3);
  const _Float16* pB1h = B1h + gb;
  const _Float16* pB3h = B3h + gb;
  const _Float16* pB1l = SPLIT ? (B1l + gb) : (const _Float16*)nullptr;
  const _Float16* pB3l = SPLIT ? (B3l + gb) : (const _Float16*)nullptr;

  const int g = l>>4, lm = l&15;
  int aoff[4], bofn[2];
#pragma unroll
  for (int m=0;m<4;++m){ int r=(w>>1)*64+m*16+lm; aoff[m]=r*32+((g^SWZ(r))<<3); }
#pragma unroll
  for (int n=0;n<2;++n){ int r=(w&1)*32+n*16+lm; bofn[n]=r*32+((g^SWZ(r))<<3); }

  f4 acc1[4][2] = {}; f4 acc3[4][2] = {};
  constexpr int B3T = (SPLIT?2:1)*2048;

  for (int k0=0;k0<C_;k0+=32){
    gload16(pA0h + k0, &AT_h[(size_t)w*512]);
    gload16(pA1h + k0, &AT_h[(size_t)(4+w)*512]);
    if constexpr (SPLIT){
      gload16(pA0l + k0, &AT_l[(size_t)w*512]);
      gload16(pA1l + k0, &AT_l[(size_t)(4+w)*512]);
    }
    gload16(pB1h + k0, &BT[(size_t)w*512]);
    gload16(pB3h + k0, &BT[(size_t)B3T + w*512]);
    if constexpr (SPLIT){
      gload16(pB1l + k0, &BT[(size_t)2048 + w*512]);
      gload16(pB3l + k0, &BT[(size_t)3*2048 + w*512]);
    }
    __syncthreads();
    h8 ah[4], al[4];
#pragma unroll
    for (int m=0;m<4;++m){
      ah[m] = *(const h8*)&AT_h[aoff[m]];
      if constexpr (SPLIT) al[m] = *(const h8*)&AT_l[aoff[m]];
    }
#pragma unroll
    for (int n=0;n<2;++n){
      h8 b1 = *(const h8*)&BT[bofn[n]];
      h8 b3 = *(const h8*)&BT[B3T + bofn[n]];
      h8 b1L, b3L;
      if constexpr (SPLIT){
        b1L = *(const h8*)&BT[2048 + bofn[n]];
        b3L = *(const h8*)&BT[3*2048 + bofn[n]];
      }
#pragma unroll
      for (int m=0;m<4;++m){
        acc1[m][n] = __builtin_amdgcn_mfma_f32_16x16x32_f16(ah[m], b1, acc1[m][n],0,0,0);
        acc3[m][n] = __builtin_amdgcn_mfma_f32_16x16x32_f16(ah[m], b3, acc3[m][n],0,0,0);
        if constexpr (SPLIT){
          acc1[m][n] = __builtin_amdgcn_mfma_f32_16x16x32_f16(al[m], b1, acc1[m][n],0,0,0);
          acc1[m][n] = __builtin_amdgcn_mfma_f32_16x16x32_f16(ah[m], b1L, acc1[m][n],0,0,0);
          acc3[m][n] = __builtin_amdgcn_mfma_f32_16x16x32_f16(al[m], b3, acc3[m][n],0,0,0);
          acc3[m][n] = __builtin_amdgcn_mfma_f32_16x16x32_f16(ah[m], b3L, acc3[m][n],0,0,0);
        }
      }
    }
    __syncthreads();
  }
#pragma unroll
  for (int m=0;m<4;++m){
#pragma unroll
    for (int n=0;n<2;++n){
#pragma unroll
      for (int j=0;j<4;++j){
        int rl = (w>>1)*64 + m*16 + (g<<2) + j;
        if (rl >= valid) continue;
        int col = n0 + (w&1)*32 + n*16 + lm;
        float s1 = acc1[m][n][j], s3 = acc3[m][n][j];
        float hval = s1/(1.f+expf(-s1))*s3;
        size_t row = (size_t)(m0 + rl);
        if constexpr (SPLIT){
          _Float16 hh=(_Float16)hval;
          Hhi[row*H_ + col] = hh;
          Hlo[row*H_ + col] = (_Float16)(hval - (float)hh);
        } else {
          Hhi[row*H_ + col] = (_Float16)hval;
        }
      }
    }
  }
}

// ---------------- linear GEMM: C = A B^T (+bias / +F / ->hi,lo) ----------------
// tile 128x128; 4 waves (2x2), wave-tile 64x64; BK=32
// OUTM: 0 = f32 + bias (Cf32, width Nw); 1 = f16 hi/lo (Ohi/Olo, width C_);
//       2 = f32 scatter: out[perm] = Fhi+Flo+acc (Ohi/Olo are F inputs)
// EXPM: 0 none; 1 lang slot by m-block (B += slot*PEsz); 2 grouped rows (bmap)
template<bool SPLIT, int OUTM, int EXPM>
__global__ __launch_bounds__(256) void gemm_lin(
    const _Float16* __restrict__ Ahi, const _Float16* __restrict__ Alo,
    const _Float16* __restrict__ Bhi, const _Float16* __restrict__ Blo,
    const float* __restrict__ bias,
    float* __restrict__ Cf32,
    _Float16* __restrict__ Ohi, _Float16* __restrict__ Olo,
    const int* __restrict__ bmap_e, const int* __restrict__ bmap_s,
    const int* __restrict__ offs, const int* __restrict__ perm,
    int M, int K, int Nw)
{
  __shared__ __align__(16) _Float16 AT_h[128*32];
  __shared__ __align__(16) _Float16 AT_l[SPLIT?128*32:8];
  __shared__ __align__(16) _Float16 BT_h[128*32];
  __shared__ __align__(16) _Float16 BT_l[SPLIT?128*32:8];

  const int tid=threadIdx.x, w=tid>>6, l=tid&63;
  const int n0 = blockIdx.x<<7;
  int m0, valid=128; size_t boff=0;
  if constexpr (EXPM==2){
    int e = bmap_e[blockIdx.y]; if (e<0) return;
    m0 = bmap_s[blockIdx.y];
    int v = offs[e+1]-m0; valid = v>128?128:v;
    boff = (size_t)e*PEsz;
  } else {
    m0 = blockIdx.y<<7;
    if constexpr (EXPM==1) boff = (m0>=T_)? PEsz : 0;
  }
  const int r0 = (w*2)*16 + (l>>2), r1 = (w*2+1)*16 + (l>>2);
  const int sA = l&3;
  int ia0 = m0+r0, ia1 = m0+r1;
  int lim = (EXPM==2) ? N_ : M;
  if (ia0>=lim) ia0=lim-1;
  if (ia1>=lim) ia1=lim-1;
  const size_t ga0=(size_t)ia0, ga1=(size_t)ia1;
  const _Float16* pA0h = Ahi + ga0*K + ((sA^SWZ(r0))<<3);
  const _Float16* pA1h = Ahi + ga1*K + ((sA^SWZ(r1))<<3);
  const _Float16* pA0l = SPLIT ? (Alo + ga0*K + ((sA^SWZ(r0))<<3)) : (const _Float16*)nullptr;
  const _Float16* pA1l = SPLIT ? (Alo + ga1*K + ((sA^SWZ(r1))<<3)) : (const _Float16*)nullptr;
  const size_t gb0 = boff + (size_t)(n0+r0)*K + ((sA^SWZ(r0))<<3);
  const size_t gb1 = boff + (size_t)(n0+r1)*K + ((sA^SWZ(r1))<<3);
  const _Float16* pB0h = Bhi + gb0;
  const _Float16* pB1h = Bhi + gb1;
  const _Float16* pB0l = SPLIT ? (Blo + gb0) : (const _Float16*)nullptr;
  const _Float16* pB1l = SPLIT ? (Blo + gb1) : (const _Float16*)nullptr;

  const int g = l>>4, lm = l&15;
  int aoff[4], bofn[4];
#pragma unroll
  for (int m=0;m<4;++m){ int r=(w>>1)*64+m*16+lm; aoff[m]=r*32+((g^SWZ(r))<<3); }
#pragma unroll
  for (int n=0;n<4;++n){ int r=(w&1)*64+n*16+lm; bofn[n]=r*32+((g^SWZ(r))<<3); }

  f4 acc[4][4]={};
  for (int k0=0;k0<K;k0+=32){
    gload16(pA0h+k0, &AT_h[(size_t)(2*w)*512]);
    gload16(pA1h+k0, &AT_h[(size_t)(2*w+1)*512]);
    gload16(pB0h+k0, &BT_h[(size_t)(2*w)*512]);
    gload16(pB1h+k0, &BT_h[(size_t)(2*w+1)*512]);
    if constexpr (SPLIT){
      gload16(pA0l+k0, &AT_l[(size_t)(2*w)*512]);
      gload16(pA1l+k0, &AT_l[(size_t)(2*w+1)*512]);
      gload16(pB0l+k0, &BT_l[(size_t)(2*w)*512]);
      gload16(pB1l+k0, &BT_l[(size_t)(2*w+1)*512]);
    }
    __syncthreads();
    h8 ah[4], al[4], bh[4], bl[4];
#pragma unroll
    for (int m=0;m<4;++m){
      ah[m] = *(const h8*)&AT_h[aoff[m]];
      if constexpr (SPLIT) al[m] = *(const h8*)&AT_l[aoff[m]];
    }
#pragma unroll
    for (int n=0;n<4;++n){
      bh[n] = *(const h8*)&BT_h[bofn[n]];
      if constexpr (SPLIT) bl[n] = *(const h8*)&BT_l[bofn[n]];
    }
#pragma unroll
    for (int m=0;m<4;++m){
#pragma unroll
      for (int n=0;n<4;++n){
        acc[m][n] = __builtin_amdgcn_mfma_f32_16x16x32_f16(ah[m], bh[n], acc[m][n],0,0,0);
        if constexpr (SPLIT){
          acc[m][n] = __builtin_amdgcn_mfma_f32_16x16x32_f16(al[m], bh[n], acc[m][n],0,0,0);
          acc[m][n] = __builtin_amdgcn_mfma_f32_16x16x32_f16(ah[m], bl[n], acc[m][n],0,0,0);
        }
      }
    }
    __syncthreads();
  }
#pragma unroll
  for (int m=0;m<4;++m){
#pragma unroll
    for (int n=0;n<4;++n){
#pragma unroll
      for (int j=0;j<4;++j){
        int rl = (w>>1)*64 + m*16 + (g<<2) + j;
        int col = n0 + (w&1)*64 + n*16 + lm;
        float v = acc[m][n][j];
        if constexpr (OUTM==0){
          int grow = m0+rl;
          if (grow<M) Cf32[(size_t)grow*Nw + col] = v + bias[col];
        } else if constexpr (OUTM==1){
          size_t grow = (size_t)(m0+rl);
          _Float16 hh = (_Float16)v;
          Ohi[grow*C_+col]=hh;
          Olo[grow*C_+col]=(_Float16)(v-(float)hh);
        } else {
          if (rl<valid){
            int orig = perm[m0+rl];
            size_t o = (size_t)orig*C_+col;
            Cf32[o] = (float)Ohi[o] + (float)Olo[o] + v;
          }
        }
      }
    }
  }
}

// ---------------- cross attention (fp32 VALU, small) ----------------
__global__ __launch_bounds__(256) void attn_kernel(
    const float* __restrict__ Q, const float* __restrict__ KV,
    _Float16* __restrict__ AOhi, _Float16* __restrict__ AOlo)
{
  __shared__ float kvs[S_*HD_];
  __shared__ float sc[64*80];
  int tid = threadIdx.x;
  int b = blockIdx.z, h = blockIdx.y, q0 = blockIdx.x << 6;
  const float scale = 0.08838834764831845f;
  for (int i = tid; i < S_*HD_; i += 256){
    int s = i >> 7, d = i & 127;
    kvs[i] = KV[((size_t)(b*S_ + s)) * (2*C_) + h*HD_ + d];
  }
  __syncthreads();
  for (int i = tid; i < 64*S_; i += 256){
    int q = i / S_; int k = i - q*S_;
    const float* qp = Q + ((size_t)(b*T_ + q0 + q)) * C_ + h*HD_;
    const float* kp = &kvs[k*HD_];
    float acc = 0.f;
#pragma unroll 4
    for (int d = 0; d < HD_; ++d) acc += qp[d] * kp[d];
    sc[q*80 + k] = acc * scale;
  }
  __syncthreads();
  if (tid < 64){
    float m = -3.4e38f;
    for (int k = 0; k < S_; ++k) m = fmaxf(m, sc[tid*80 + k]);
    float sum = 0.f;
    for (int k = 0; k < S_; ++k){ float ev = expf(sc[tid*80 + k] - m); sc[tid*80 + k] = ev; sum += ev; }
    for (int k = 0; k < S_; ++k) sc[tid*80 + k] = sc[tid*80 + k] / sum;
  }
  __syncthreads();
  for (int i = tid; i < S_*HD_; i += 256){
    int s = i >> 7, d = i & 127;
    kvs[i] = KV[((size_t)(b*S_ + s)) * (2*C_) + C_ + h*HD_ + d];
  }
  __syncthreads();
  for (int i = tid; i < 64*HD_; i += 256){
    int q = i >> 7, d = i & 127;
    float acc = 0.f;
    for (int k = 0; k < S_; ++k) acc += sc[q*80 + k] * kvs[k*HD_ + d];
    size_t o = ((size_t)(b*T_ + q0 + q)) * C_ + h*HD_ + d;
    _Float16 hh = (_Float16)acc;
    AOhi[o] = hh;
    AOlo[o] = (_Float16)(acc - (float)hh);
  }
}

// ---------------- caption gating ----------------
__global__ __launch_bounds__(256) void cap_gate(
    const float* __restrict__ CR, const float* __restrict__ gw, const float* __restrict__ gb,
    int* __restrict__ cap_sel, float* __restrict__ capP, int* __restrict__ counts)
{
  int tid = threadIdx.x, wave = tid >> 6, lane = tid & 63;
  for (int r = 0; r < 4; ++r){
    int row = (blockIdx.x << 4) + (wave << 2) + r;
    const float* xp = CR + (size_t)row * C_;
    float lg[E_];
#pragma unroll
    for (int e = 0; e < E_; ++e){
      const float* wv = gw + (size_t)e * C_;
      float p = 0.f;
      for (int c = lane; c < C_; c += 64) p += xp[c] * wv[c];
#pragma unroll
      for (int off = 32; off; off >>= 1) p += __shfl_xor(p, off);
      lg[e] = p + gb[e];
    }
    if (lane == 0){
      float z[E_], m = -3.4e38f;
      for (int e = 0; e < E_; ++e){
        float gmb = jax_gumbel(0u, 2u, (uint32_t)(row*E_ + e));
        z[e] = (lg[e] + gmb) * 0.5f;
        m = fmaxf(m, z[e]);
      }
      float y[E_], sum = 0.f;
      for (int e = 0; e < E_; ++e){ y[e] = expf(z[e] - m); sum += y[e]; }
      for (int e = 0; e < E_; ++e) y[e] = y[e] / sum;
      int best = 0; float bv = y[0];
      for (int e = 1; e < E_; ++e) if (y[e] > bv){ bv = y[e]; best = e; }
      cap_sel[row] = best;
      atomicAdd(&counts[best], 1);
      for (int e = 0; e < E_; ++e)
        capP[(size_t)row*E_ + e] = ((e == best) ? 1.0f : 0.0f) - y[e] + y[e];
    }
  }
}

// ---------------- expert grouping ----------------
__global__ void build_groups(const int* __restrict__ counts, int* __restrict__ offs,
                             int* __restrict__ cursor, int* __restrict__ bmap_e,
                             int* __restrict__ bmap_s)
{
  offs[0] = 0;
  for (int e = 0; e < E_; ++e){ offs[e+1] = offs[e] + counts[e]; cursor[e] = offs[e]; }
  int idx = 0;
  for (int e = 0; e < E_; ++e)
    for (int s = offs[e]; s < offs[e+1]; s += GTILE){ bmap_e[idx] = e; bmap_s[idx] = s; ++idx; }
  for (; idx < MAXGB; ++idx) bmap_e[idx] = -1;
}

__global__ __launch_bounds__(256) void scatter_perm(
    const int* __restrict__ cap_sel, int* __restrict__ cursor, int* __restrict__ perm)
{
  int row = blockIdx.x * 256 + threadIdx.x;
  int e = cap_sel[row];
  int pos = atomicAdd(&cursor[e], 1);
  perm[pos] = row;
}

// ---------------- loss ----------------
__global__ __launch_bounds__(256) void loss_kernel(
    const float* __restrict__ capP, const float* __restrict__ langP, float* __restrict__ out_loss)
{
  __shared__ float red[4][256];
  int tid = threadIdx.x;
  float p0=0.f, p1=0.f, p2=0.f, p3=0.f;
  for (int r = tid; r < N_; r += 256){
    const float* p = capP + (size_t)r*E_;
    p0 += p[0]; p1 += p[1]; p2 += p[2]; p3 += p[3];
  }
  red[0][tid]=p0; red[1][tid]=p1; red[2][tid]=p2; red[3][tid]=p3;
  __syncthreads();
  for (int s = 128; s > 0; s >>= 1){
    if (tid < s){
      red[0][tid]+=red[0][tid+s]; red[1][tid]+=red[1][tid+s];
      red[2][tid]+=red[2][tid+s]; red[3][tid]+=red[3][tid+s];
    }
    __syncthreads();
  }
  if (tid == 0){
    float loss = 0.f;
    for (int e = 0; e < E_; ++e){
      float ul = (langP[e] + langP[E_ + e]) * 0.5f;
      loss += ul * logf(ul + 1e-10f);
    }
    for (int e = 0; e < E_; ++e){
      float uc = red[e][0] * (1.0f / N_);
      loss += uc * logf(uc + 1e-10f);
    }
    out_loss[0] = loss;
  }
}

// ---------------- host launch ----------------
extern "C" void kernel_launch(void* const* d_in, const int* in_sizes, int n_in,
                              void* d_out, int out_size, void* d_ws, size_t ws_size,
                              hipStream_t stream)
{
  const float* x          = (const float*)d_in[0];
  const float* caption    = (const float*)d_in[2];
  const int*   language   = (const int*)  d_in[3];
  const float* lang_embed = (const float*)d_in[4];
  const float* lang_gw    = (const float*)d_in[5];
  const float* lang_gb    = (const float*)d_in[6];
  const float* lang_w1    = (const float*)d_in[7];
  const float* lang_w2    = (const float*)d_in[8];
  const float* lang_w3    = (const float*)d_in[9];
  const float* in_w       = (const float*)d_in[10];
  const float* in_b       = (const float*)d_in[11];
  const float* out_w      = (const float*)d_in[12];
  const float* out_b      = (const float*)d_in[13];
  const float* cap_gw     = (const float*)d_in[14];
  const float* cap_gb     = (const float*)d_in[15];
  const float* cap_w1     = (const float*)d_in[16];
  const float* cap_w2     = (const float*)d_in[17];
  const float* cap_w3     = (const float*)d_in[18];
  float* out = (float*)d_out;

  const size_t NC = (size_t)N_*C_;          // 4,194,304
  const size_t NH = (size_t)N_*H_;          // 11,534,336
  const size_t KVel = (size_t)B_*S_*2*C_;   // 315,392
  const size_t CAPel = (size_t)B_*S_*C_;    // 157,696

  // ---- workspace layout (bytes, 256-aligned) ----
  char* base = (char*)d_ws;
  size_t cur = 0;
  auto alloc = [&](size_t bytes)->char*{
    char* p = base + cur;
    cur += (bytes + 255) & ~(size_t)255;
    return p;
  };
  float* Qcross = (float*)alloc(NC*4);            // Q, then cross
  float* KVb    = (float*)alloc(KVel*4);
  float* capP   = (float*)alloc((size_t)N_*E_*4);
  float* langP  = (float*)alloc(64);
  int* lang_sel = (int*)alloc(64);
  int* cap_sel  = (int*)alloc(N_*4);
  int* counts   = (int*)alloc(64);
  int* offs     = (int*)alloc(64);
  int* cursor   = (int*)alloc(64);
  int* bmap_e   = (int*)alloc(MAXGB*4);
  int* bmap_s   = (int*)alloc(MAXGB*4);
  int* perm     = (int*)alloc(N_*4);
  _Float16* xAO_hi = (_Float16*)alloc(NC*2);      // x_hi, then AO_hi
  _Float16* xAO_lo = (_Float16*)alloc(NC*2);
  _Float16* cap_hi = (_Float16*)alloc(CAPel*2);
  _Float16* cap_lo = (_Float16*)alloc(CAPel*2);
  _Float16* Hb_hi  = (_Float16*)alloc(NH*2);      // stage-1 hidden hi, then H2
  _Float16* Hb_lo  = (_Float16*)alloc(NH*2);
  _Float16* F_hi   = (_Float16*)alloc(NC*2);
  _Float16* F_lo   = (_Float16*)alloc(NC*2);
  // time-shared weight region: phase1 = lang split (12*PEsz halves = 69.2MB)
  //                            phase2 = in_w/out_w split + cap plain (43.0M halves = 86MB)
  _Float16* Wreg = (_Float16*)alloc(2*( (size_t)3*C_*C_*2 + (size_t)C_*C_*2 + 3*4*PEsz ));
  // phase1 pointers
  _Float16* w1hi = Wreg;              _Float16* w1lo = Wreg + 2*PEsz;
  _Float16* w3hi = Wreg + 4*PEsz;     _Float16* w3lo = Wreg + 6*PEsz;
  _Float16* w2hi = Wreg + 8*PEsz;     _Float16* w2lo = Wreg + 10*PEsz;
  // phase2 pointers
  _Float16* inw_hi  = Wreg;
  _Float16* inw_lo  = inw_hi + (size_t)3*C_*C_;
  _Float16* outw_hi = inw_lo + (size_t)3*C_*C_;
  _Float16* outw_lo = outw_hi + (size_t)C_*C_;
  _Float16* capw1f  = outw_lo + (size_t)C_*C_;
  _Float16* capw3f  = capw1f + 4*PEsz;
  _Float16* capw2f  = capw3f + 4*PEsz;

  // ---- phase 0: gating setup + input conversions ----
  setup_lang<<<1, 256, 0, stream>>>(lang_embed, lang_gw, lang_gb, language, langP, lang_sel, counts);
  for (int slot = 0; slot < 2; ++slot){
    conv_split_sel<<<2048, 256, 0, stream>>>(lang_w1, lang_sel, slot, w1hi+slot*PEsz, w1lo+slot*PEsz, (long)(PEsz/4));
    conv_split_sel<<<2048, 256, 0, stream>>>(lang_w3, lang_sel, slot, w3hi+slot*PEsz, w3lo+slot*PEsz, (long)(PEsz/4));
    conv_split_sel<<<2048, 256, 0, stream>>>(lang_w2, lang_sel, slot, w2hi+slot*PEsz, w2lo+slot*PEsz, (long)(PEsz/4));
  }
  conv_split<<<2048, 256, 0, stream>>>(x, xAO_hi, xAO_lo, (long)(NC/4));
  conv_split<<<256, 256, 0, stream>>>(caption, cap_hi, cap_lo, (long)(CAPel/4));

  // ---- stage-1 FFN (split fp16, 3-MFMA) ----
  gemm_gate<true><<<dim3(H_/64, N_/128), 256, 0, stream>>>(
      xAO_hi, xAO_lo, w1hi, w1lo, w3hi, w3lo,
      nullptr, nullptr, nullptr, nullptr, Hb_hi, Hb_lo);
  gemm_lin<true,1,1><<<dim3(C_/128, N_/128), 256, 0, stream>>>(
      Hb_hi, Hb_lo, w2hi, w2lo, nullptr, nullptr, F_hi, F_lo,
      nullptr, nullptr, nullptr, nullptr, N_, H_, C_);

  // ---- phase-2 weight conversions (reuse Wreg; serialized by stream) ----
  conv_split<<<2048, 256, 0, stream>>>(in_w, inw_hi, inw_lo, (long)((size_t)3*C_*C_/4));
  conv_split<<<1024, 256, 0, stream>>>(out_w, outw_hi, outw_lo, (long)((size_t)C_*C_/4));
  conv_plain<<<2048, 256, 0, stream>>>(cap_w1, capw1f, (long)(4*PEsz/4));
  conv_plain<<<2048, 256, 0, stream>>>(cap_w3, capw3f, (long)(4*PEsz/4));
  conv_plain<<<2048, 256, 0, stream>>>(cap_w2, capw2f, (long)(4*PEsz/4));

  // ---- projections + attention ----
  gemm_lin<true,0,0><<<dim3(C_/128, N_/128), 256, 0, stream>>>(      // Q
      F_hi, F_lo, inw_hi, inw_lo, in_b, Qcross, nullptr, nullptr,
      nullptr, nullptr, nullptr, nullptr, N_, C_, C_);
  gemm_lin<true,0,0><<<dim3((2*C_)/128, 2), 256, 0, stream>>>(       // K|V
      cap_hi, cap_lo, inw_hi + (size_t)C_*C_, inw_lo + (size_t)C_*C_, in_b + C_,
      KVb, nullptr, nullptr,
      nullptr, nullptr, nullptr, nullptr, B_*S_, C_, 2*C_);
  attn_kernel<<<dim3(T_/64, NH_, B_), 256, 0, stream>>>(Qcross, KVb, xAO_hi, xAO_lo);
  gemm_lin<true,0,0><<<dim3(C_/128, N_/128), 256, 0, stream>>>(      // out-proj -> cross
      xAO_hi, xAO_lo, outw_hi, outw_lo, out_b, Qcross, nullptr, nullptr,
      nullptr, nullptr, nullptr, nullptr, N_, C_, C_);

  // ---- caption gating + grouping ----
  cap_gate<<<N_/16, 256, 0, stream>>>(Qcross, cap_gw, cap_gb, cap_sel, capP, counts);
  build_groups<<<1, 1, 0, stream>>>(counts, offs, cursor, bmap_e, bmap_s);
  scatter_perm<<<N_/256, 256, 0, stream>>>(cap_sel, cursor, perm);

  // ---- stage-2 FFN (plain fp16) ----
  _Float16* H2 = Hb_hi;  // reuse
  gemm_gate<false><<<dim3(H_/64, MAXGB), 256, 0, stream>>>(
      F_hi, nullptr, capw1f, nullptr, capw3f, nullptr,
      bmap_e, bmap_s, offs, perm, H2, nullptr);
  gemm_lin<false,2,2><<<dim3(C_/128, MAXGB), 256, 0, stream>>>(
      H2, nullptr, capw2f, nullptr, nullptr, out, F_hi, F_lo,
      bmap_e, bmap_s, offs, perm, N_, H_, C_);

  loss_kernel<<<1, 256, 0, stream>>>(capP, langP, out + NC);
}

// Round 3
// 859.757 us; speedup vs baseline: 3.1537x; 1.1742x over previous
//
#include <hip/hip_runtime.h>
#include <stdint.h>

// Problem constants
#define B_ 2
#define T_ 2048
#define S_ 77
#define C_ 1024
#define E_ 4
#define H_ 2816
#define NH_ 8
#define HD_ 128
#define N_ (B_*T_)            // 4096 tokens
#define GTILE 128
#define MAXGB (N_/GTILE + E_) // 36 grouped row-tiles
#define PEsz ((size_t)H_*C_)  // per-expert matrix elems

typedef _Float16 h8 __attribute__((ext_vector_type(8)));
typedef _Float16 h4 __attribute__((ext_vector_type(4)));
typedef float f4 __attribute__((ext_vector_type(4)));

#define SWZ(r) (((r)>>1)&3)

__device__ __forceinline__ void gload16(const void* g, void* l){
  __builtin_amdgcn_global_load_lds((const __attribute__((address_space(1))) void*)g,
                                   (__attribute__((address_space(3))) void*)l, 16, 0, 0);
}

// bijective XCD swizzle (m204): contiguous grid chunks per XCD for L2 locality
__device__ __forceinline__ void xcd_swizzle(int& bx, int& by){
  int nx = gridDim.x, ny = gridDim.y;
  int nwg = nx*ny;
  int wg = by*nx + bx;
  int q = nwg >> 3, r = nwg & 7;
  int xcd = wg & 7, idx = wg >> 3;
  int s = (xcd < r ? xcd*(q+1) : r*(q+1) + (xcd-r)*q) + idx;
  bx = s % nx; by = s / nx;
}

// ---------------- Threefry-2x32 (JAX partitionable) ----------------
__device__ __forceinline__ uint32_t rotl32(uint32_t v, int r){ return (v<<r)|(v>>(32-r)); }
__device__ __forceinline__ void threefry2x32(uint32_t k0, uint32_t k1,
                                             uint32_t x, uint32_t y,
                                             uint32_t& o0, uint32_t& o1){
  uint32_t k2 = k0 ^ k1 ^ 0x1BD11BDAu;
  x += k0; y += k1;
#define TFR(r) { x += y; y = rotl32(y, r); y ^= x; }
  TFR(13) TFR(15) TFR(26) TFR(6)   x += k1; y += k2 + 1u;
  TFR(17) TFR(29) TFR(16) TFR(24)  x += k2; y += k0 + 2u;
  TFR(13) TFR(15) TFR(26) TFR(6)   x += k0; y += k1 + 3u;
  TFR(17) TFR(29) TFR(16) TFR(24)  x += k1; y += k2 + 4u;
  TFR(13) TFR(15) TFR(26) TFR(6)   x += k2; y += k0 + 5u;
#undef TFR
  o0 = x; o1 = y;
}
__device__ __forceinline__ float gumbel_from_bits(uint32_t bits){
  const float TINY = 1.17549435e-38f;
  float f = __uint_as_float((bits >> 9) | 0x3f800000u) - 1.0f;
  float u = fmaxf(TINY, f + TINY);
  return -logf(-logf(u));
}
__device__ __forceinline__ float jax_gumbel(uint32_t k0, uint32_t k1, uint32_t idx){
  uint32_t a, b;
  threefry2x32(k0, k1, 0u, idx, a, b);
  return gumbel_from_bits(a ^ b);
}

// ---------------- language gating ----------------
__global__ __launch_bounds__(256) void setup_lang(
    const float* __restrict__ lang_embed, const float* __restrict__ gate_w,
    const float* __restrict__ gate_b, const int* __restrict__ language,
    float* __restrict__ langP, int* __restrict__ lang_sel, int* __restrict__ counts)
{
  __shared__ float red[256];
  __shared__ float logits[8];
  int tid = threadIdx.x;
  for (int be = 0; be < 8; ++be){
    int b = be >> 2, e = be & 3;
    const float* emb = lang_embed + (size_t)language[b] * C_;
    const float* gw  = gate_w + (size_t)e * C_;
    float p = 0.f;
    for (int c = tid; c < C_; c += 256) p += emb[c] * gw[c];
    red[tid] = p; __syncthreads();
    for (int s = 128; s > 0; s >>= 1){
      if (tid < s) red[tid] += red[tid + s];
      __syncthreads();
    }
    if (tid == 0) logits[be] = red[0] + gate_b[e];
    __syncthreads();
  }
  if (tid == 0){
    for (int b = 0; b < B_; ++b){
      float z[E_], m = -3.4e38f;
      for (int e = 0; e < E_; ++e){
        float gmb = jax_gumbel(0u, 1u, (uint32_t)(b*E_ + e));
        z[e] = (logits[b*E_ + e] + gmb) * 0.5f;
        m = fmaxf(m, z[e]);
      }
      float y[E_], sum = 0.f;
      for (int e = 0; e < E_; ++e){ y[e] = expf(z[e] - m); sum += y[e]; }
      for (int e = 0; e < E_; ++e) y[e] = y[e] / sum;
      int best = 0; float bv = y[0];
      for (int e = 1; e < E_; ++e) if (y[e] > bv){ bv = y[e]; best = e; }
      lang_sel[b] = best;
      for (int e = 0; e < E_; ++e)
        langP[b*E_ + e] = ((e == best) ? 1.0f : 0.0f) - y[e] + y[e];
    }
    for (int e = 0; e < E_; ++e) counts[e] = 0;
  }
}

// ---------------- conversion kernels ----------------
__global__ __launch_bounds__(256) void conv_split(const float* __restrict__ s,
    _Float16* __restrict__ hi, _Float16* __restrict__ lo, long n4){
  long i = (long)blockIdx.x*256 + threadIdx.x;
  long stride = (long)gridDim.x*256;
  for (; i < n4; i += stride){
    float4 v = ((const float4*)s)[i];
    h4 h, L;
    h[0]=(_Float16)v.x; h[1]=(_Float16)v.y; h[2]=(_Float16)v.z; h[3]=(_Float16)v.w;
    L[0]=(_Float16)(v.x-(float)h[0]); L[1]=(_Float16)(v.y-(float)h[1]);
    L[2]=(_Float16)(v.z-(float)h[2]); L[3]=(_Float16)(v.w-(float)h[3]);
    ((h4*)hi)[i] = h; ((h4*)lo)[i] = L;
  }
}
__global__ __launch_bounds__(256) void conv_plain(const float* __restrict__ s,
    _Float16* __restrict__ d, long n4){
  long i = (long)blockIdx.x*256 + threadIdx.x;
  long stride = (long)gridDim.x*256;
  for (; i < n4; i += stride){
    float4 v = ((const float4*)s)[i];
    h4 h;
    h[0]=(_Float16)v.x; h[1]=(_Float16)v.y; h[2]=(_Float16)v.z; h[3]=(_Float16)v.w;
    ((h4*)d)[i] = h;
  }
}
__global__ __launch_bounds__(256) void conv_split_sel(const float* __restrict__ base,
    const int* __restrict__ sel, int slot,
    _Float16* __restrict__ hi, _Float16* __restrict__ lo, long n4){
  const float* s = base + (size_t)sel[slot]*PEsz;
  long i = (long)blockIdx.x*256 + threadIdx.x;
  long stride = (long)gridDim.x*256;
  for (; i < n4; i += stride){
    float4 v = ((const float4*)s)[i];
    h4 h, L;
    h[0]=(_Float16)v.x; h[1]=(_Float16)v.y; h[2]=(_Float16)v.z; h[3]=(_Float16)v.w;
    L[0]=(_Float16)(v.x-(float)h[0]); L[1]=(_Float16)(v.y-(float)h[1]);
    L[2]=(_Float16)(v.z-(float)h[2]); L[3]=(_Float16)(v.w-(float)h[3]);
    ((h4*)hi)[i] = h; ((h4*)lo)[i] = L;
  }
}

// ---------------- gate GEMM: H = silu(A W1^T) * (A W3^T) ----------------
template<bool SPLIT>
__global__ __launch_bounds__(256) void gemm_gate(
    const _Float16* __restrict__ Ahi, const _Float16* __restrict__ Alo,
    const _Float16* __restrict__ B1h, const _Float16* __restrict__ B1l,
    const _Float16* __restrict__ B3h, const _Float16* __restrict__ B3l,
    const int* __restrict__ bmap_e, const int* __restrict__ bmap_s,
    const int* __restrict__ offs, const int* __restrict__ perm,
    _Float16* __restrict__ Hhi, _Float16* __restrict__ Hlo)
{
  __shared__ __align__(16) _Float16 AT_h[128*32];
  __shared__ __align__(16) _Float16 AT_l[SPLIT ? 128*32 : 8];
  __shared__ __align__(16) _Float16 BT[(SPLIT?4:2)*64*32];

  const int tid=threadIdx.x, w=tid>>6, l=tid&63;
  int bx = blockIdx.x, by = blockIdx.y;
  xcd_swizzle(bx, by);
  const int n0 = bx<<6;
  int m0, valid;
  size_t boff;
  if constexpr (SPLIT){
    m0 = by<<7; valid = 128;
    boff = (m0>=T_) ? PEsz : 0;
  } else {
    int e = bmap_e[by]; if (e<0) return;
    m0 = bmap_s[by];
    int v = offs[e+1]-m0; valid = v>128?128:v;
    boff = (size_t)e*PEsz;
  }
  const int ra0 = w*16 + (l>>2), ra1 = 64 + w*16 + (l>>2);
  const int rb  = w*16 + (l>>2);
  const int sA = l&3;
  size_t ga0, ga1;
  if constexpr (SPLIT){ ga0 = (size_t)(m0+ra0); ga1 = (size_t)(m0+ra1); }
  else {
    int i0 = m0+ra0; if (i0>=N_) i0=m0;
    int i1 = m0+ra1; if (i1>=N_) i1=m0;
    ga0 = (size_t)perm[i0]; ga1 = (size_t)perm[i1];
  }
  const _Float16* pA0h = Ahi + ga0*C_ + ((sA^SWZ(ra0))<<3);
  const _Float16* pA1h = Ahi + ga1*C_ + ((sA^SWZ(ra1))<<3);
  const _Float16* pA0l = SPLIT ? (Alo + ga0*C_ + ((sA^SWZ(ra0))<<3)) : (const _Float16*)nullptr;
  const _Float16* pA1l = SPLIT ? (Alo + ga1*C_ + ((sA^SWZ(ra1))<<3)) : (const _Float16*)nullptr;
  const size_t gb = boff + (size_t)(n0+rb)*C_ + ((sA^SWZ(rb))<<3);
  const _Float16* pB1h = B1h + gb;
  const _Float16* pB3h = B3h + gb;
  const _Float16* pB1l = SPLIT ? (B1l + gb) : (const _Float16*)nullptr;
  const _Float16* pB3l = SPLIT ? (B3l + gb) : (const _Float16*)nullptr;

  const int g = l>>4, lm = l&15;
  int aoff[4], bofn[2];
#pragma unroll
  for (int m=0;m<4;++m){ int r=(w>>1)*64+m*16+lm; aoff[m]=r*32+((g^SWZ(r))<<3); }
#pragma unroll
  for (int n=0;n<2;++n){ int r=(w&1)*32+n*16+lm; bofn[n]=r*32+((g^SWZ(r))<<3); }

  f4 acc1[4][2] = {}; f4 acc3[4][2] = {};
  constexpr int B3T = (SPLIT?2:1)*2048;

  for (int k0=0;k0<C_;k0+=32){
    gload16(pA0h + k0, &AT_h[(size_t)w*512]);
    gload16(pA1h + k0, &AT_h[(size_t)(4+w)*512]);
    if constexpr (SPLIT){
      gload16(pA0l + k0, &AT_l[(size_t)w*512]);
      gload16(pA1l + k0, &AT_l[(size_t)(4+w)*512]);
    }
    gload16(pB1h + k0, &BT[(size_t)w*512]);
    gload16(pB3h + k0, &BT[(size_t)B3T + w*512]);
    if constexpr (SPLIT){
      gload16(pB1l + k0, &BT[(size_t)2048 + w*512]);
      gload16(pB3l + k0, &BT[(size_t)3*2048 + w*512]);
    }
    __syncthreads();
    h8 ah[4], al[4];
#pragma unroll
    for (int m=0;m<4;++m){
      ah[m] = *(const h8*)&AT_h[aoff[m]];
      if constexpr (SPLIT) al[m] = *(const h8*)&AT_l[aoff[m]];
    }
#pragma unroll
    for (int n=0;n<2;++n){
      h8 b1 = *(const h8*)&BT[bofn[n]];
      h8 b3 = *(const h8*)&BT[B3T + bofn[n]];
      h8 b1L, b3L;
      if constexpr (SPLIT){
        b1L = *(const h8*)&BT[2048 + bofn[n]];
        b3L = *(const h8*)&BT[3*2048 + bofn[n]];
      }
#pragma unroll
      for (int m=0;m<4;++m){
        acc1[m][n] = __builtin_amdgcn_mfma_f32_16x16x32_f16(ah[m], b1, acc1[m][n],0,0,0);
        acc3[m][n] = __builtin_amdgcn_mfma_f32_16x16x32_f16(ah[m], b3, acc3[m][n],0,0,0);
        if constexpr (SPLIT){
          acc1[m][n] = __builtin_amdgcn_mfma_f32_16x16x32_f16(al[m], b1, acc1[m][n],0,0,0);
          acc1[m][n] = __builtin_amdgcn_mfma_f32_16x16x32_f16(ah[m], b1L, acc1[m][n],0,0,0);
          acc3[m][n] = __builtin_amdgcn_mfma_f32_16x16x32_f16(al[m], b3, acc3[m][n],0,0,0);
          acc3[m][n] = __builtin_amdgcn_mfma_f32_16x16x32_f16(ah[m], b3L, acc3[m][n],0,0,0);
        }
      }
    }
    __syncthreads();
  }
#pragma unroll
  for (int m=0;m<4;++m){
#pragma unroll
    for (int n=0;n<2;++n){
#pragma unroll
      for (int j=0;j<4;++j){
        int rl = (w>>1)*64 + m*16 + (g<<2) + j;
        if (rl >= valid) continue;
        int col = n0 + (w&1)*32 + n*16 + lm;
        float s1 = acc1[m][n][j], s3 = acc3[m][n][j];
        float hval = s1/(1.f+expf(-s1))*s3;
        size_t row = (size_t)(m0 + rl);
        if constexpr (SPLIT){
          _Float16 hh=(_Float16)hval;
          Hhi[row*H_ + col] = hh;
          Hlo[row*H_ + col] = (_Float16)(hval - (float)hh);
        } else {
          Hhi[row*H_ + col] = (_Float16)hval;
        }
      }
    }
  }
}

// ---------------- linear GEMM: C = A B^T (+bias / +F / ->hi,lo) ----------------
// OUTM: 0 = f32 + bias (Cf32, width Nw); 1 = f16 hi/lo (+optional bias), width Nw;
//       2 = f32 scatter: out[perm] = Fhi+Flo+acc
// EXPM: 0 none; 1 lang slot by m-block; 2 grouped rows (bmap)
template<bool SPLIT, int OUTM, int EXPM>
__global__ __launch_bounds__(256) void gemm_lin(
    const _Float16* __restrict__ Ahi, const _Float16* __restrict__ Alo,
    const _Float16* __restrict__ Bhi, const _Float16* __restrict__ Blo,
    const float* __restrict__ bias,
    float* __restrict__ Cf32,
    _Float16* __restrict__ Ohi, _Float16* __restrict__ Olo,
    const int* __restrict__ bmap_e, const int* __restrict__ bmap_s,
    const int* __restrict__ offs, const int* __restrict__ perm,
    int M, int K, int Nw)
{
  __shared__ __align__(16) _Float16 AT_h[128*32];
  __shared__ __align__(16) _Float16 AT_l[SPLIT?128*32:8];
  __shared__ __align__(16) _Float16 BT_h[128*32];
  __shared__ __align__(16) _Float16 BT_l[SPLIT?128*32:8];

  const int tid=threadIdx.x, w=tid>>6, l=tid&63;
  int bx = blockIdx.x, by = blockIdx.y;
  xcd_swizzle(bx, by);
  const int n0 = bx<<7;
  int m0, valid=128; size_t boff=0;
  if constexpr (EXPM==2){
    int e = bmap_e[by]; if (e<0) return;
    m0 = bmap_s[by];
    int v = offs[e+1]-m0; valid = v>128?128:v;
    boff = (size_t)e*PEsz;
  } else {
    m0 = by<<7;
    if constexpr (EXPM==1) boff = (m0>=T_)? PEsz : 0;
  }
  const int r0 = (w*2)*16 + (l>>2), r1 = (w*2+1)*16 + (l>>2);
  const int sA = l&3;
  int ia0 = m0+r0, ia1 = m0+r1;
  int lim = (EXPM==2) ? N_ : M;
  if (ia0>=lim) ia0=lim-1;
  if (ia1>=lim) ia1=lim-1;
  const size_t ga0=(size_t)ia0, ga1=(size_t)ia1;
  const _Float16* pA0h = Ahi + ga0*K + ((sA^SWZ(r0))<<3);
  const _Float16* pA1h = Ahi + ga1*K + ((sA^SWZ(r1))<<3);
  const _Float16* pA0l = SPLIT ? (Alo + ga0*K + ((sA^SWZ(r0))<<3)) : (const _Float16*)nullptr;
  const _Float16* pA1l = SPLIT ? (Alo + ga1*K + ((sA^SWZ(r1))<<3)) : (const _Float16*)nullptr;
  const size_t gb0 = boff + (size_t)(n0+r0)*K + ((sA^SWZ(r0))<<3);
  const size_t gb1 = boff + (size_t)(n0+r1)*K + ((sA^SWZ(r1))<<3);
  const _Float16* pB0h = Bhi + gb0;
  const _Float16* pB1h = Bhi + gb1;
  const _Float16* pB0l = SPLIT ? (Blo + gb0) : (const _Float16*)nullptr;
  const _Float16* pB1l = SPLIT ? (Blo + gb1) : (const _Float16*)nullptr;

  const int g = l>>4, lm = l&15;
  int aoff[4], bofn[4];
#pragma unroll
  for (int m=0;m<4;++m){ int r=(w>>1)*64+m*16+lm; aoff[m]=r*32+((g^SWZ(r))<<3); }
#pragma unroll
  for (int n=0;n<4;++n){ int r=(w&1)*64+n*16+lm; bofn[n]=r*32+((g^SWZ(r))<<3); }

  f4 acc[4][4]={};
  for (int k0=0;k0<K;k0+=32){
    gload16(pA0h+k0, &AT_h[(size_t)(2*w)*512]);
    gload16(pA1h+k0, &AT_h[(size_t)(2*w+1)*512]);
    gload16(pB0h+k0, &BT_h[(size_t)(2*w)*512]);
    gload16(pB1h+k0, &BT_h[(size_t)(2*w+1)*512]);
    if constexpr (SPLIT){
      gload16(pA0l+k0, &AT_l[(size_t)(2*w)*512]);
      gload16(pA1l+k0, &AT_l[(size_t)(2*w+1)*512]);
      gload16(pB0l+k0, &BT_l[(size_t)(2*w)*512]);
      gload16(pB1l+k0, &BT_l[(size_t)(2*w+1)*512]);
    }
    __syncthreads();
    h8 ah[4], al[4], bh[4], bl[4];
#pragma unroll
    for (int m=0;m<4;++m){
      ah[m] = *(const h8*)&AT_h[aoff[m]];
      if constexpr (SPLIT) al[m] = *(const h8*)&AT_l[aoff[m]];
    }
#pragma unroll
    for (int n=0;n<4;++n){
      bh[n] = *(const h8*)&BT_h[bofn[n]];
      if constexpr (SPLIT) bl[n] = *(const h8*)&BT_l[bofn[n]];
    }
#pragma unroll
    for (int m=0;m<4;++m){
#pragma unroll
      for (int n=0;n<4;++n){
        acc[m][n] = __builtin_amdgcn_mfma_f32_16x16x32_f16(ah[m], bh[n], acc[m][n],0,0,0);
        if constexpr (SPLIT){
          acc[m][n] = __builtin_amdgcn_mfma_f32_16x16x32_f16(al[m], bh[n], acc[m][n],0,0,0);
          acc[m][n] = __builtin_amdgcn_mfma_f32_16x16x32_f16(ah[m], bl[n], acc[m][n],0,0,0);
        }
      }
    }
    __syncthreads();
  }
#pragma unroll
  for (int m=0;m<4;++m){
#pragma unroll
    for (int n=0;n<4;++n){
#pragma unroll
      for (int j=0;j<4;++j){
        int rl = (w>>1)*64 + m*16 + (g<<2) + j;
        int col = n0 + (w&1)*64 + n*16 + lm;
        float v = acc[m][n][j];
        if constexpr (OUTM==0){
          int grow = m0+rl;
          if (grow<M) Cf32[(size_t)grow*Nw + col] = v + bias[col];
        } else if constexpr (OUTM==1){
          int grow = m0+rl;
          if (grow<M){
            float vb = v + (bias ? bias[col] : 0.f);
            _Float16 hh = (_Float16)vb;
            Ohi[(size_t)grow*Nw+col]=hh;
            Olo[(size_t)grow*Nw+col]=(_Float16)(vb-(float)hh);
          }
        } else {
          if (rl<valid){
            int orig = perm[m0+rl];
            size_t o = (size_t)orig*C_+col;
            Cf32[o] = (float)Ohi[o] + (float)Olo[o] + v;
          }
        }
      }
    }
  }
}

// ---------------- MFMA cross attention ----------------
// grid (T/64, NH, B), 256 threads (4 waves; wave w owns q-rows w*16..w*16+15)
#define SP5 5        // 80/16 n-tiles for scores
#define KSTR 136     // K LDS row stride (f16): 2-way bank aliasing only
#define VSTR 104     // V^T / P LDS row stride (f16)
__global__ __launch_bounds__(256) void attn_mfma(
    const _Float16* __restrict__ Qh, const _Float16* __restrict__ Ql,
    const _Float16* __restrict__ KVh, const _Float16* __restrict__ KVl,
    _Float16* __restrict__ AOh, _Float16* __restrict__ AOl)
{
  __shared__ __align__(16) _Float16 Usm[2*128*VSTR];  // K[80][136] hi/lo, then V^T[128][104] hi/lo
  __shared__ __align__(16) _Float16 Psm[2*64*VSTR];   // P[64][104] hi/lo
  _Float16* Kh_s = Usm;
  _Float16* Kl_s = Usm + 128*VSTR;
  _Float16* VTh  = Usm;
  _Float16* VTl  = Usm + 128*VSTR;
  _Float16* Ph   = Psm;
  _Float16* Pl   = Psm + 64*VSTR;

  const int tid = threadIdx.x;
  const int w = tid>>6, l = tid&63, lm = l&15, g = l>>4;
  const int b = blockIdx.z, h = blockIdx.y, q0 = blockIdx.x<<6;
  const float scale = 0.08838834764831845f; // 1/sqrt(128)

  // zero P (covers padded key cols 77..95)
  for (int i = tid; i < 64*VSTR; i += 256) ((uint32_t*)Psm)[i] = 0;

  // stage K hi/lo: rows 0..79 (77 valid, rest zero)
  {
    int oct = tid & 15, s0 = tid >> 4;
    for (int s = s0; s < 80; s += 16){
      h8 vh = {}, vl = {};
      if (s < S_){
        size_t ga = ((size_t)(b*S_ + s))*(2*C_) + h*HD_ + oct*8;
        vh = *(const h8*)(KVh + ga);
        vl = *(const h8*)(KVl + ga);
      }
      *(h8*)(Kh_s + s*KSTR + oct*8) = vh;
      *(h8*)(Kl_s + s*KSTR + oct*8) = vl;
    }
  }
  // Q fragments from global (row = q0 + w*16 + lm, k-octet g)
  h8 qh[4], ql[4];
  {
    size_t qrow = (size_t)(b*T_ + q0 + w*16 + lm);
    const _Float16* qph = Qh + qrow*C_ + h*HD_ + g*8;
    const _Float16* qpl = Ql + qrow*C_ + h*HD_ + g*8;
#pragma unroll
    for (int ks=0; ks<4; ++ks){ qh[ks] = *(const h8*)(qph + ks*32); ql[ks] = *(const h8*)(qpl + ks*32); }
  }
  __syncthreads();

  // QK^T (split 3-MFMA)
  f4 sc[SP5] = {};
#pragma unroll
  for (int ks=0; ks<4; ++ks){
#pragma unroll
    for (int nt=0; nt<SP5; ++nt){
      h8 kh = *(const h8*)(Kh_s + (nt*16+lm)*KSTR + ks*32 + g*8);
      h8 kl = *(const h8*)(Kl_s + (nt*16+lm)*KSTR + ks*32 + g*8);
      sc[nt] = __builtin_amdgcn_mfma_f32_16x16x32_f16(qh[ks], kh, sc[nt],0,0,0);
      sc[nt] = __builtin_amdgcn_mfma_f32_16x16x32_f16(ql[ks], kh, sc[nt],0,0,0);
      sc[nt] = __builtin_amdgcn_mfma_f32_16x16x32_f16(qh[ks], kl, sc[nt],0,0,0);
    }
  }

  // softmax: lane holds rows g*4+j, key col nt*16+lm; reduce across lm (16-lane groups)
  float mx[4] = {-3e38f,-3e38f,-3e38f,-3e38f};
#pragma unroll
  for (int nt=0; nt<SP5; ++nt){
    bool valid = (nt*16+lm) < S_;
#pragma unroll
    for (int j=0;j<4;++j){
      float v = valid ? sc[nt][j]*scale : -3e38f;
      sc[nt][j] = v;
      mx[j] = fmaxf(mx[j], v);
    }
  }
#pragma unroll
  for (int off=1; off<16; off<<=1){
#pragma unroll
    for (int j=0;j<4;++j) mx[j] = fmaxf(mx[j], __shfl_xor(mx[j], off));
  }
  float sm[4] = {0,0,0,0};
#pragma unroll
  for (int nt=0; nt<SP5; ++nt){
    bool valid = (nt*16+lm) < S_;
#pragma unroll
    for (int j=0;j<4;++j){
      float p = valid ? expf(sc[nt][j]-mx[j]) : 0.f;
      sc[nt][j] = p; sm[j] += p;
    }
  }
#pragma unroll
  for (int off=1; off<16; off<<=1){
#pragma unroll
    for (int j=0;j<4;++j) sm[j] += __shfl_xor(sm[j], off);
  }
#pragma unroll
  for (int nt=0; nt<SP5; ++nt){
#pragma unroll
    for (int j=0;j<4;++j){
      int col = nt*16 + lm;
      if (col < S_){
        float p = sc[nt][j] / sm[j];
        int row = w*16 + g*4 + j;
        _Float16 ph = (_Float16)p;
        Ph[row*VSTR + col] = ph;
        Pl[row*VSTR + col] = (_Float16)(p - (float)ph);
      }
    }
  }
  __syncthreads();   // waves done with K-region reads + P visible

  // zero V^T region then stage V transposed (VT[d][s] = V[s][d])
  for (int i = tid; i < 128*VSTR; i += 256) ((uint32_t*)Usm)[i] = 0;
  __syncthreads();
  {
    int oct = tid & 15, s0 = tid >> 4;
    for (int s = s0; s < S_; s += 16){
      size_t ga = ((size_t)(b*S_ + s))*(2*C_) + C_ + h*HD_ + oct*8;
      h8 vh = *(const h8*)(KVh + ga);
      h8 vl = *(const h8*)(KVl + ga);
#pragma unroll
      for (int i=0;i<8;++i){
        VTh[(oct*8+i)*VSTR + s] = vh[i];
        VTl[(oct*8+i)*VSTR + s] = vl[i];
      }
    }
  }
  __syncthreads();

  // PV (split 3-MFMA): K-dim = 96 (3 steps), N = 128 (8 tiles)
  h8 pah[3], pal[3];
#pragma unroll
  for (int ks=0;ks<3;++ks){
    pah[ks] = *(const h8*)(Ph + (w*16+lm)*VSTR + ks*32 + g*8);
    pal[ks] = *(const h8*)(Pl + (w*16+lm)*VSTR + ks*32 + g*8);
  }
#pragma unroll
  for (int nt=0; nt<8; ++nt){
    f4 o = {};
#pragma unroll
    for (int ks=0;ks<3;++ks){
      h8 vh = *(const h8*)(VTh + (nt*16+lm)*VSTR + ks*32 + g*8);
      h8 vl = *(const h8*)(VTl + (nt*16+lm)*VSTR + ks*32 + g*8);
      o = __builtin_amdgcn_mfma_f32_16x16x32_f16(pah[ks], vh, o,0,0,0);
      o = __builtin_amdgcn_mfma_f32_16x16x32_f16(pal[ks], vh, o,0,0,0);
      o = __builtin_amdgcn_mfma_f32_16x16x32_f16(pah[ks], vl, o,0,0,0);
    }
#pragma unroll
    for (int j=0;j<4;++j){
      size_t orow = (size_t)(b*T_ + q0 + w*16 + g*4 + j);
      size_t oa = orow*C_ + h*HD_ + nt*16 + lm;
      _Float16 hh = (_Float16)o[j];
      AOh[oa] = hh;
      AOl[oa] = (_Float16)(o[j] - (float)hh);
    }
  }
}

// ---------------- caption gating ----------------
__global__ __launch_bounds__(256) void cap_gate(
    const float* __restrict__ CR, const float* __restrict__ gw, const float* __restrict__ gb,
    int* __restrict__ cap_sel, float* __restrict__ capP, int* __restrict__ counts)
{
  int tid = threadIdx.x, wave = tid >> 6, lane = tid & 63;
  for (int r = 0; r < 4; ++r){
    int row = (blockIdx.x << 4) + (wave << 2) + r;
    const float* xp = CR + (size_t)row * C_;
    float lg[E_];
#pragma unroll
    for (int e = 0; e < E_; ++e){
      const float* wv = gw + (size_t)e * C_;
      float p = 0.f;
      for (int c = lane; c < C_; c += 64) p += xp[c] * wv[c];
#pragma unroll
      for (int off = 32; off; off >>= 1) p += __shfl_xor(p, off);
      lg[e] = p + gb[e];
    }
    if (lane == 0){
      float z[E_], m = -3.4e38f;
      for (int e = 0; e < E_; ++e){
        float gmb = jax_gumbel(0u, 2u, (uint32_t)(row*E_ + e));
        z[e] = (lg[e] + gmb) * 0.5f;
        m = fmaxf(m, z[e]);
      }
      float y[E_], sum = 0.f;
      for (int e = 0; e < E_; ++e){ y[e] = expf(z[e] - m); sum += y[e]; }
      for (int e = 0; e < E_; ++e) y[e] = y[e] / sum;
      int best = 0; float bv = y[0];
      for (int e = 1; e < E_; ++e) if (y[e] > bv){ bv = y[e]; best = e; }
      cap_sel[row] = best;
      atomicAdd(&counts[best], 1);
      for (int e = 0; e < E_; ++e)
        capP[(size_t)row*E_ + e] = ((e == best) ? 1.0f : 0.0f) - y[e] + y[e];
    }
  }
}

// ---------------- expert grouping ----------------
__global__ void build_groups(const int* __restrict__ counts, int* __restrict__ offs,
                             int* __restrict__ cursor, int* __restrict__ bmap_e,
                             int* __restrict__ bmap_s)
{
  offs[0] = 0;
  for (int e = 0; e < E_; ++e){ offs[e+1] = offs[e] + counts[e]; cursor[e] = offs[e]; }
  int idx = 0;
  for (int e = 0; e < E_; ++e)
    for (int s = offs[e]; s < offs[e+1]; s += GTILE){ bmap_e[idx] = e; bmap_s[idx] = s; ++idx; }
  for (; idx < MAXGB; ++idx) bmap_e[idx] = -1;
}

__global__ __launch_bounds__(256) void scatter_perm(
    const int* __restrict__ cap_sel, int* __restrict__ cursor, int* __restrict__ perm)
{
  int row = blockIdx.x * 256 + threadIdx.x;
  int e = cap_sel[row];
  int pos = atomicAdd(&cursor[e], 1);
  perm[pos] = row;
}

// ---------------- loss ----------------
__global__ __launch_bounds__(256) void loss_kernel(
    const float* __restrict__ capP, const float* __restrict__ langP, float* __restrict__ out_loss)
{
  __shared__ float red[4][256];
  int tid = threadIdx.x;
  float p0=0.f, p1=0.f, p2=0.f, p3=0.f;
  for (int r = tid; r < N_; r += 256){
    const float* p = capP + (size_t)r*E_;
    p0 += p[0]; p1 += p[1]; p2 += p[2]; p3 += p[3];
  }
  red[0][tid]=p0; red[1][tid]=p1; red[2][tid]=p2; red[3][tid]=p3;
  __syncthreads();
  for (int s = 128; s > 0; s >>= 1){
    if (tid < s){
      red[0][tid]+=red[0][tid+s]; red[1][tid]+=red[1][tid+s];
      red[2][tid]+=red[2][tid+s]; red[3][tid]+=red[3][tid+s];
    }
    __syncthreads();
  }
  if (tid == 0){
    float loss = 0.f;
    for (int e = 0; e < E_; ++e){
      float ul = (langP[e] + langP[E_ + e]) * 0.5f;
      loss += ul * logf(ul + 1e-10f);
    }
    for (int e = 0; e < E_; ++e){
      float uc = red[e][0] * (1.0f / N_);
      loss += uc * logf(uc + 1e-10f);
    }
    out_loss[0] = loss;
  }
}

// ---------------- host launch ----------------
extern "C" void kernel_launch(void* const* d_in, const int* in_sizes, int n_in,
                              void* d_out, int out_size, void* d_ws, size_t ws_size,
                              hipStream_t stream)
{
  const float* x          = (const float*)d_in[0];
  const float* caption    = (const float*)d_in[2];
  const int*   language   = (const int*)  d_in[3];
  const float* lang_embed = (const float*)d_in[4];
  const float* lang_gw    = (const float*)d_in[5];
  const float* lang_gb    = (const float*)d_in[6];
  const float* lang_w1    = (const float*)d_in[7];
  const float* lang_w2    = (const float*)d_in[8];
  const float* lang_w3    = (const float*)d_in[9];
  const float* in_w       = (const float*)d_in[10];
  const float* in_b       = (const float*)d_in[11];
  const float* out_w      = (const float*)d_in[12];
  const float* out_b      = (const float*)d_in[13];
  const float* cap_gw     = (const float*)d_in[14];
  const float* cap_gb     = (const float*)d_in[15];
  const float* cap_w1     = (const float*)d_in[16];
  const float* cap_w2     = (const float*)d_in[17];
  const float* cap_w3     = (const float*)d_in[18];
  float* out = (float*)d_out;

  const size_t NC = (size_t)N_*C_;
  const size_t NHe = (size_t)N_*H_;
  const size_t KVel = (size_t)B_*S_*2*C_;
  const size_t CAPel = (size_t)B_*S_*C_;

  char* base = (char*)d_ws;
  size_t cur = 0;
  auto alloc = [&](size_t bytes)->char*{
    char* p = base + cur;
    cur += (bytes + 255) & ~(size_t)255;
    return p;
  };
  // region R1: phase A = Q hi/lo f16, phase B = cross f32 (out-proj result)
  float* Qcross = (float*)alloc(NC*4);
  _Float16* Qh = (_Float16*)Qcross;
  _Float16* Ql = Qh + NC;
  // region R2: KV hi/lo f16
  char* kvreg = alloc(KVel*4);
  _Float16* KVh = (_Float16*)kvreg;
  _Float16* KVl = KVh + KVel;
  float* capP   = (float*)alloc((size_t)N_*E_*4);
  float* langP  = (float*)alloc(64);
  int* lang_sel = (int*)alloc(64);
  int* cap_sel  = (int*)alloc(N_*4);
  int* counts   = (int*)alloc(64);
  int* offs     = (int*)alloc(64);
  int* cursor   = (int*)alloc(64);
  int* bmap_e   = (int*)alloc(MAXGB*4);
  int* bmap_s   = (int*)alloc(MAXGB*4);
  int* perm     = (int*)alloc(N_*4);
  _Float16* xAO_hi = (_Float16*)alloc(NC*2);      // x_hi, then AO_hi
  _Float16* xAO_lo = (_Float16*)alloc(NC*2);
  _Float16* cap_hi = (_Float16*)alloc(CAPel*2);
  _Float16* cap_lo = (_Float16*)alloc(CAPel*2);
  _Float16* Hb_hi  = (_Float16*)alloc(NHe*2);     // stage-1 hidden hi, then H2
  _Float16* Hb_lo  = (_Float16*)alloc(NHe*2);
  _Float16* F_hi   = (_Float16*)alloc(NC*2);
  _Float16* F_lo   = (_Float16*)alloc(NC*2);
  _Float16* Wreg = (_Float16*)alloc(2*( (size_t)3*C_*C_*2 + (size_t)C_*C_*2 + 3*4*PEsz ));
  // phase1 (lang expert split)
  _Float16* w1hi = Wreg;              _Float16* w1lo = Wreg + 2*PEsz;
  _Float16* w3hi = Wreg + 4*PEsz;     _Float16* w3lo = Wreg + 6*PEsz;
  _Float16* w2hi = Wreg + 8*PEsz;     _Float16* w2lo = Wreg + 10*PEsz;
  // phase2 (proj split + cap plain)
  _Float16* inw_hi  = Wreg;
  _Float16* inw_lo  = inw_hi + (size_t)3*C_*C_;
  _Float16* outw_hi = inw_lo + (size_t)3*C_*C_;
  _Float16* outw_lo = outw_hi + (size_t)C_*C_;
  _Float16* capw1f  = outw_lo + (size_t)C_*C_;
  _Float16* capw3f  = capw1f + 4*PEsz;
  _Float16* capw2f  = capw3f + 4*PEsz;

  // ---- phase 0: gating setup + conversions ----
  setup_lang<<<1, 256, 0, stream>>>(lang_embed, lang_gw, lang_gb, language, langP, lang_sel, counts);
  for (int slot = 0; slot < 2; ++slot){
    conv_split_sel<<<2048, 256, 0, stream>>>(lang_w1, lang_sel, slot, w1hi+slot*PEsz, w1lo+slot*PEsz, (long)(PEsz/4));
    conv_split_sel<<<2048, 256, 0, stream>>>(lang_w3, lang_sel, slot, w3hi+slot*PEsz, w3lo+slot*PEsz, (long)(PEsz/4));
    conv_split_sel<<<2048, 256, 0, stream>>>(lang_w2, lang_sel, slot, w2hi+slot*PEsz, w2lo+slot*PEsz, (long)(PEsz/4));
  }
  conv_split<<<2048, 256, 0, stream>>>(x, xAO_hi, xAO_lo, (long)(NC/4));
  conv_split<<<256, 256, 0, stream>>>(caption, cap_hi, cap_lo, (long)(CAPel/4));

  // ---- stage-1 FFN (split) ----
  gemm_gate<true><<<dim3(H_/64, N_/128), 256, 0, stream>>>(
      xAO_hi, xAO_lo, w1hi, w1lo, w3hi, w3lo,
      nullptr, nullptr, nullptr, nullptr, Hb_hi, Hb_lo);
  gemm_lin<true,1,1><<<dim3(C_/128, N_/128), 256, 0, stream>>>(
      Hb_hi, Hb_lo, w2hi, w2lo, nullptr, nullptr, F_hi, F_lo,
      nullptr, nullptr, nullptr, nullptr, N_, H_, C_);

  // ---- phase-2 weight conversions (reuse Wreg) ----
  conv_split<<<2048, 256, 0, stream>>>(in_w, inw_hi, inw_lo, (long)((size_t)3*C_*C_/4));
  conv_split<<<1024, 256, 0, stream>>>(out_w, outw_hi, outw_lo, (long)((size_t)C_*C_/4));
  conv_plain<<<2048, 256, 0, stream>>>(cap_w1, capw1f, (long)(4*PEsz/4));
  conv_plain<<<2048, 256, 0, stream>>>(cap_w3, capw3f, (long)(4*PEsz/4));
  conv_plain<<<2048, 256, 0, stream>>>(cap_w2, capw2f, (long)(4*PEsz/4));

  // ---- projections (f16 hi/lo outputs) + MFMA attention ----
  gemm_lin<true,1,0><<<dim3(C_/128, N_/128), 256, 0, stream>>>(       // Q -> Qh/Ql
      F_hi, F_lo, inw_hi, inw_lo, in_b, nullptr, Qh, Ql,
      nullptr, nullptr, nullptr, nullptr, N_, C_, C_);
  gemm_lin<true,1,0><<<dim3((2*C_)/128, 2), 256, 0, stream>>>(        // K|V -> KVh/KVl
      cap_hi, cap_lo, inw_hi + (size_t)C_*C_, inw_lo + (size_t)C_*C_, in_b + C_,
      nullptr, KVh, KVl,
      nullptr, nullptr, nullptr, nullptr, B_*S_, C_, 2*C_);
  attn_mfma<<<dim3(T_/64, NH_, B_), 256, 0, stream>>>(Qh, Ql, KVh, KVl, xAO_hi, xAO_lo);
  gemm_lin<true,0,0><<<dim3(C_/128, N_/128), 256, 0, stream>>>(       // out-proj -> cross (f32)
      xAO_hi, xAO_lo, outw_hi, outw_lo, out_b, Qcross, nullptr, nullptr,
      nullptr, nullptr, nullptr, nullptr, N_, C_, C_);

  // ---- caption gating + grouping ----
  cap_gate<<<N_/16, 256, 0, stream>>>(Qcross, cap_gw, cap_gb, cap_sel, capP, counts);
  build_groups<<<1, 1, 0, stream>>>(counts, offs, cursor, bmap_e, bmap_s);
  scatter_perm<<<N_/256, 256, 0, stream>>>(cap_sel, cursor, perm);

  // ---- stage-2 FFN (plain f16) ----
  _Float16* H2 = Hb_hi;
  gemm_gate<false><<<dim3(H_/64, MAXGB), 256, 0, stream>>>(
      F_hi, nullptr, capw1f, nullptr, capw3f, nullptr,
      bmap_e, bmap_s, offs, perm, H2, nullptr);
  gemm_lin<false,2,2><<<dim3(C_/128, MAXGB), 256, 0, stream>>>(
      H2, nullptr, capw2f, nullptr, nullptr, out, F_hi, F_lo,
      bmap_e, bmap_s, offs, perm, N_, H_, C_);

  loss_kernel<<<1, 256, 0, stream>>>(capP, langP, out + NC);
}

// Round 4
// 801.628 us; speedup vs baseline: 3.3824x; 1.0725x over previous
//
#include <hip/hip_runtime.h>
#include <stdint.h>

// Problem constants
#define B_ 2
#define T_ 2048
#define S_ 77
#define C_ 1024
#define E_ 4
#define H_ 2816
#define NH_ 8
#define HD_ 128
#define N_ (B_*T_)            // 4096 tokens
#define GTILE 128
#define MAXGB (N_/GTILE + E_) // 36 grouped row-tiles
#define PEsz ((size_t)H_*C_)  // per-expert matrix elems (H*C)

typedef _Float16 h8 __attribute__((ext_vector_type(8)));
typedef _Float16 h4 __attribute__((ext_vector_type(4)));
typedef float f4 __attribute__((ext_vector_type(4)));

__device__ __forceinline__ void gload16(const void* g, void* l){
  __builtin_amdgcn_global_load_lds((const __attribute__((address_space(1))) void*)g,
                                   (__attribute__((address_space(3))) void*)l, 16, 0, 0);
}

// bijective XCD swizzle (m204)
__device__ __forceinline__ void xcd_swizzle(int& bx, int& by){
  int nx = gridDim.x, ny = gridDim.y;
  int nwg = nx*ny;
  int wg = by*nx + bx;
  int q = nwg >> 3, r = nwg & 7;
  int xcd = wg & 7, idx = wg >> 3;
  int s = (xcd < r ? xcd*(q+1) : r*(q+1) + (xcd-r)*q) + idx;
  bx = s % nx; by = s / nx;
}

// ---------------- Threefry-2x32 (JAX partitionable) ----------------
__device__ __forceinline__ uint32_t rotl32(uint32_t v, int r){ return (v<<r)|(v>>(32-r)); }
__device__ __forceinline__ void threefry2x32(uint32_t k0, uint32_t k1,
                                             uint32_t x, uint32_t y,
                                             uint32_t& o0, uint32_t& o1){
  uint32_t k2 = k0 ^ k1 ^ 0x1BD11BDAu;
  x += k0; y += k1;
#define TFR(r) { x += y; y = rotl32(y, r); y ^= x; }
  TFR(13) TFR(15) TFR(26) TFR(6)   x += k1; y += k2 + 1u;
  TFR(17) TFR(29) TFR(16) TFR(24)  x += k2; y += k0 + 2u;
  TFR(13) TFR(15) TFR(26) TFR(6)   x += k0; y += k1 + 3u;
  TFR(17) TFR(29) TFR(16) TFR(24)  x += k1; y += k2 + 4u;
  TFR(13) TFR(15) TFR(26) TFR(6)   x += k2; y += k0 + 5u;
#undef TFR
  o0 = x; o1 = y;
}
__device__ __forceinline__ float gumbel_from_bits(uint32_t bits){
  const float TINY = 1.17549435e-38f;
  float f = __uint_as_float((bits >> 9) | 0x3f800000u) - 1.0f;
  float u = fmaxf(TINY, f + TINY);
  return -logf(-logf(u));
}
__device__ __forceinline__ float jax_gumbel(uint32_t k0, uint32_t k1, uint32_t idx){
  uint32_t a, b;
  threefry2x32(k0, k1, 0u, idx, a, b);
  return gumbel_from_bits(a ^ b);
}

// ---------------- language gating ----------------
__global__ __launch_bounds__(256) void setup_lang(
    const float* __restrict__ lang_embed, const float* __restrict__ gate_w,
    const float* __restrict__ gate_b, const int* __restrict__ language,
    float* __restrict__ langP, int* __restrict__ lang_sel, int* __restrict__ counts)
{
  __shared__ float red[256];
  __shared__ float logits[8];
  int tid = threadIdx.x;
  for (int be = 0; be < 8; ++be){
    int b = be >> 2, e = be & 3;
    const float* emb = lang_embed + (size_t)language[b] * C_;
    const float* gw  = gate_w + (size_t)e * C_;
    float p = 0.f;
    for (int c = tid; c < C_; c += 256) p += emb[c] * gw[c];
    red[tid] = p; __syncthreads();
    for (int s = 128; s > 0; s >>= 1){
      if (tid < s) red[tid] += red[tid + s];
      __syncthreads();
    }
    if (tid == 0) logits[be] = red[0] + gate_b[e];
    __syncthreads();
  }
  if (tid == 0){
    for (int b = 0; b < B_; ++b){
      float z[E_], m = -3.4e38f;
      for (int e = 0; e < E_; ++e){
        float gmb = jax_gumbel(0u, 1u, (uint32_t)(b*E_ + e));
        z[e] = (logits[b*E_ + e] + gmb) * 0.5f;
        m = fmaxf(m, z[e]);
      }
      float y[E_], sum = 0.f;
      for (int e = 0; e < E_; ++e){ y[e] = expf(z[e] - m); sum += y[e]; }
      for (int e = 0; e < E_; ++e) y[e] = y[e] / sum;
      int best = 0; float bv = y[0];
      for (int e = 1; e < E_; ++e) if (y[e] > bv){ bv = y[e]; best = e; }
      lang_sel[b] = best;
      for (int e = 0; e < E_; ++e)
        langP[b*E_ + e] = ((e == best) ? 1.0f : 0.0f) - y[e] + y[e];
    }
    for (int e = 0; e < E_; ++e) counts[e] = 0;
  }
}

// ---------------- conversion kernels ----------------
__global__ __launch_bounds__(256) void conv_split(const float* __restrict__ s,
    _Float16* __restrict__ hi, _Float16* __restrict__ lo, long n4){
  long i = (long)blockIdx.x*256 + threadIdx.x;
  long stride = (long)gridDim.x*256;
  for (; i < n4; i += stride){
    float4 v = ((const float4*)s)[i];
    h4 h, L;
    h[0]=(_Float16)v.x; h[1]=(_Float16)v.y; h[2]=(_Float16)v.z; h[3]=(_Float16)v.w;
    L[0]=(_Float16)(v.x-(float)h[0]); L[1]=(_Float16)(v.y-(float)h[1]);
    L[2]=(_Float16)(v.z-(float)h[2]); L[3]=(_Float16)(v.w-(float)h[3]);
    ((h4*)hi)[i] = h; ((h4*)lo)[i] = L;
  }
}
__global__ __launch_bounds__(256) void conv_plain(const float* __restrict__ s,
    _Float16* __restrict__ d, long n4){
  long i = (long)blockIdx.x*256 + threadIdx.x;
  long stride = (long)gridDim.x*256;
  for (; i < n4; i += stride){
    float4 v = ((const float4*)s)[i];
    h4 h;
    h[0]=(_Float16)v.x; h[1]=(_Float16)v.y; h[2]=(_Float16)v.z; h[3]=(_Float16)v.w;
    ((h4*)d)[i] = h;
  }
}
// w2-style selected-expert split (layout unchanged [C][H])
__global__ __launch_bounds__(256) void conv_split_sel(const float* __restrict__ base,
    const int* __restrict__ sel, int slot,
    _Float16* __restrict__ hi, _Float16* __restrict__ lo, long n4){
  const float* s = base + (size_t)sel[slot]*PEsz;
  long i = (long)blockIdx.x*256 + threadIdx.x;
  long stride = (long)gridDim.x*256;
  for (; i < n4; i += stride){
    float4 v = ((const float4*)s)[i];
    h4 h, L;
    h[0]=(_Float16)v.x; h[1]=(_Float16)v.y; h[2]=(_Float16)v.z; h[3]=(_Float16)v.w;
    L[0]=(_Float16)(v.x-(float)h[0]); L[1]=(_Float16)(v.y-(float)h[1]);
    L[2]=(_Float16)(v.z-(float)h[2]); L[3]=(_Float16)(v.w-(float)h[3]);
    ((h4*)hi)[i] = h; ((h4*)lo)[i] = L;
  }
}
// W1/W3 -> interleaved W13 (16-row groups: [w1 h-rows 16 | w3 h-rows 16] per 32)
// SPLIT: lang (sel-indexed slots, hi+lo). !SPLIT: cap (all 4 experts, plain)
template<bool SPLIT>
__global__ __launch_bounds__(256) void conv_w13(
    const float* __restrict__ w1, const float* __restrict__ w3,
    const int* __restrict__ sel, int nslot,
    _Float16* __restrict__ hi, _Float16* __restrict__ lo)
{
  const int K8 = C_/8;
  long total = (long)nslot * (2*H_) * K8;
  for (long i = (long)blockIdx.x*256 + threadIdx.x; i < total; i += (long)gridDim.x*256){
    int kv = (int)(i & (K8-1));
    long rs = i >> 7;                 // K8 = 128
    int r  = (int)(rs % (2*H_));
    int slot = (int)(rs / (2*H_));
    int e = SPLIT ? sel[slot] : slot;
    int gg = r >> 5, o = r & 31;
    const float* src = ((o<16)? w1 : w3) + (size_t)e*PEsz + (size_t)(16*gg + (o&15))*C_ + kv*8;
    float4 v0 = *(const float4*)src, v1 = *(const float4*)(src+4);
    float vv[8] = {v0.x,v0.y,v0.z,v0.w,v1.x,v1.y,v1.z,v1.w};
    h8 hh, ll;
#pragma unroll
    for (int jj=0;jj<8;++jj){
      hh[jj] = (_Float16)vv[jj];
      if constexpr (SPLIT) ll[jj] = (_Float16)(vv[jj]-(float)hh[jj]);
    }
    size_t dof = (size_t)slot*2*PEsz + (size_t)r*C_ + kv*8;
    *(h8*)(hi + dof) = hh;
    if constexpr (SPLIT) *(h8*)(lo + dof) = ll;
  }
}

// ---------------- unified pipelined GEMM ----------------
// C[m][n'] = sum_seg Aseg * Bseg^T  (K-extension handles hi/lo split: segs A:[Ah,Al,Ah], B:[Bh,Bh,Bl])
// tile 128x128, BK=64, 256 thr / 4 waves (2x2, wave-tile 64x64), 2 LDS bufs (64KB),
// depth-1 prefetch with counted vmcnt(8) (never drains mid-loop), 2 phases/K-tile,
// XOR-swizzled staging (pre-swizzled global src) -> conflict-free ds_read_b128.
// EPI: 0 f32+bias, 1 f16 hi/lo (+opt bias), 2 scatter-add (O0/O1=F in, Cf32=out),
//      3 gate split (silu(s1)*s3 -> O0/O1 hi/lo), 4 gate plain (-> O0)
// EXPM: 0 none, 1 lang slot by m-block, 2 grouped rows + perm-gather A, 3 grouped rows + linear A
template<int EPI, int NSEG, int EXPM>
__global__ __launch_bounds__(256,2) void gemm8(
    const _Float16* __restrict__ A0, const _Float16* __restrict__ A1,
    const _Float16* __restrict__ B0, const _Float16* __restrict__ B1,
    const float* __restrict__ bias, float* __restrict__ Cf32,
    _Float16* __restrict__ O0, _Float16* __restrict__ O1,
    const int* __restrict__ bmap_e, const int* __restrict__ bmap_s,
    const int* __restrict__ offs, const int* __restrict__ perm,
    int M, int K, int Nw, size_t bstride_e)
{
  __shared__ __align__(16) char smem[65536];
  const int tid = threadIdx.x, w = tid>>6, l = tid&63;
  const int lm = l&15, g = l>>4;
  const int wm = w>>1, wn = w&1;
  int bx = blockIdx.x, by = blockIdx.y;
  xcd_swizzle(bx, by);
  const int n0 = bx<<7;
  int m0, valid = 128; size_t eoff = 0;
  if constexpr (EXPM>=2){
    int e = bmap_e[by]; if (e<0) return;
    m0 = bmap_s[by];
    int v = offs[e+1]-m0; valid = v>128?128:v;
    eoff = (size_t)e*bstride_e;
  } else {
    m0 = by<<7;
    if constexpr (EXPM==1) eoff = (m0>=T_) ? bstride_e : 0;
  }
  // per-thread staging bases (pre-swizzled source column)
  const int cAe = (((tid&7) ^ ((tid>>3)&7)) << 3);
  size_t rbA[4], rbB[4];
#pragma unroll
  for (int j=0;j<4;++j){
    int r = (j<<5) + (tid>>3);
    int ia = m0 + r;
    if constexpr (EXPM==2){ ia = perm[(ia < N_) ? ia : (N_-1)]; }
    else if constexpr (EXPM==3){ ia = (ia < N_) ? ia : (N_-1); }
    else { if (ia > M-1) ia = M-1; }
    rbA[j] = (size_t)ia*K + cAe;
    rbB[j] = eoff + (size_t)(n0+r)*K + cAe;
  }
  const int tps = K>>6, nt = NSEG*tps;

#define STAGE8(tt, cc) { \
    int sg = 0; \
    if constexpr (NSEG==3){ sg = ((tt)>=2*tps) ? 2 : (((tt)>=tps)?1:0); } \
    const _Float16* Asrc = (sg==1) ? A1 : A0; \
    const _Float16* Bsrc = (sg==2) ? B1 : B0; \
    int kk0 = ((tt) - sg*tps)<<6; \
    char* db = smem + (cc)*32768 + w*1024; \
    _Pragma("unroll") \
    for (int j=0;j<4;++j) gload16(Asrc + rbA[j] + kk0, db + j*4096); \
    _Pragma("unroll") \
    for (int j=0;j<4;++j) gload16(Bsrc + rbB[j] + kk0, db + 16384 + j*4096); \
  }

  // per-phase LDS byte offsets (swizzled)
  int aoff[2][4], boff[2][4];
#pragma unroll
  for (int kk=0;kk<2;++kk){
#pragma unroll
    for (int i=0;i<4;++i){
      int ra = wm*64 + i*16 + lm;
      aoff[kk][i] = (ra<<7) + (((kk<<6)+(g<<4)) ^ ((ra&7)<<4));
      int rb = wn*64 + i*16 + lm;
      boff[kk][i] = (rb<<7) + (((kk<<6)+(g<<4)) ^ ((rb&7)<<4));
    }
  }

  f4 acc[4][4] = {};
  STAGE8(0, 0)
  for (int t=0; t<nt; ++t){
    const int c = t&1;
    if (t+1 < nt){
      STAGE8(t+1, c^1)
      asm volatile("s_waitcnt vmcnt(8)" ::: "memory");
    } else {
      asm volatile("s_waitcnt vmcnt(0)" ::: "memory");
    }
    __builtin_amdgcn_s_barrier();
    const char* Ab = smem + c*32768;
    const char* Bb = Ab + 16384;
#pragma unroll
    for (int kk=0;kk<2;++kk){
      h8 af[4], bf[4];
#pragma unroll
      for (int i=0;i<4;++i){
        af[i] = *(const h8*)(Ab + aoff[kk][i]);
        bf[i] = *(const h8*)(Bb + boff[kk][i]);
      }
      __builtin_amdgcn_s_setprio(1);
#pragma unroll
      for (int mi=0;mi<4;++mi)
#pragma unroll
        for (int ni=0;ni<4;++ni)
          acc[mi][ni] = __builtin_amdgcn_mfma_f32_16x16x32_f16(af[mi], bf[ni], acc[mi][ni],0,0,0);
      __builtin_amdgcn_s_setprio(0);
      __builtin_amdgcn_s_barrier();
    }
  }

  // epilogue
#pragma unroll
  for (int mi=0;mi<4;++mi){
    const int rl0 = wm*64 + mi*16 + (g<<2);
    if constexpr (EPI==3 || EPI==4){
#pragma unroll
      for (int p=0;p<2;++p){
        int h = ((n0 + wn*64)>>1) + p*16 + lm;
#pragma unroll
        for (int j=0;j<4;++j){
          int rl = rl0 + j;
          if (rl >= valid) continue;
          float s1 = acc[mi][2*p][j], s3 = acc[mi][2*p+1][j];
          float hval = s1/(1.f+expf(-s1))*s3;
          size_t row = (size_t)(m0 + rl);
          if constexpr (EPI==3){
            _Float16 hh = (_Float16)hval;
            O0[row*H_ + h] = hh;
            O1[row*H_ + h] = (_Float16)(hval - (float)hh);
          } else {
            O0[row*H_ + h] = (_Float16)hval;
          }
        }
      }
    } else {
#pragma unroll
      for (int ni=0;ni<4;++ni){
        int col = n0 + wn*64 + ni*16 + lm;
#pragma unroll
        for (int j=0;j<4;++j){
          int rl = rl0 + j;
          float v = acc[mi][ni][j];
          if constexpr (EPI==0){
            int grow = m0 + rl;
            if (grow < M) Cf32[(size_t)grow*Nw + col] = v + bias[col];
          } else if constexpr (EPI==1){
            int grow = m0 + rl;
            if (grow < M){
              float vb = v + (bias ? bias[col] : 0.f);
              _Float16 hh = (_Float16)vb;
              O0[(size_t)grow*Nw + col] = hh;
              O1[(size_t)grow*Nw + col] = (_Float16)(vb - (float)hh);
            }
          } else {   // EPI==2 scatter-add
            if (rl < valid){
              int orig = perm[m0 + rl];
              size_t o = (size_t)orig*C_ + col;
              Cf32[o] = (float)O0[o] + (float)O1[o] + v;
            }
          }
        }
      }
    }
  }
#undef STAGE8
}

// ---------------- MFMA cross attention (unchanged from r3) ----------------
#define SP5 5
#define KSTR 136
#define VSTR 104
__global__ __launch_bounds__(256) void attn_mfma(
    const _Float16* __restrict__ Qh, const _Float16* __restrict__ Ql,
    const _Float16* __restrict__ KVh, const _Float16* __restrict__ KVl,
    _Float16* __restrict__ AOh, _Float16* __restrict__ AOl)
{
  __shared__ __align__(16) _Float16 Usm[2*128*VSTR];
  __shared__ __align__(16) _Float16 Psm[2*64*VSTR];
  _Float16* Kh_s = Usm;
  _Float16* Kl_s = Usm + 128*VSTR;
  _Float16* VTh  = Usm;
  _Float16* VTl  = Usm + 128*VSTR;
  _Float16* Ph   = Psm;
  _Float16* Pl   = Psm + 64*VSTR;

  const int tid = threadIdx.x;
  const int w = tid>>6, l = tid&63, lm = l&15, g = l>>4;
  const int b = blockIdx.z, h = blockIdx.y, q0 = blockIdx.x<<6;
  const float scale = 0.08838834764831845f;

  for (int i = tid; i < 64*VSTR; i += 256) ((uint32_t*)Psm)[i] = 0;
  {
    int oct = tid & 15, s0 = tid >> 4;
    for (int s = s0; s < 80; s += 16){
      h8 vh = {}, vl = {};
      if (s < S_){
        size_t ga = ((size_t)(b*S_ + s))*(2*C_) + h*HD_ + oct*8;
        vh = *(const h8*)(KVh + ga);
        vl = *(const h8*)(KVl + ga);
      }
      *(h8*)(Kh_s + s*KSTR + oct*8) = vh;
      *(h8*)(Kl_s + s*KSTR + oct*8) = vl;
    }
  }
  h8 qh[4], ql[4];
  {
    size_t qrow = (size_t)(b*T_ + q0 + w*16 + lm);
    const _Float16* qph = Qh + qrow*C_ + h*HD_ + g*8;
    const _Float16* qpl = Ql + qrow*C_ + h*HD_ + g*8;
#pragma unroll
    for (int ks=0; ks<4; ++ks){ qh[ks] = *(const h8*)(qph + ks*32); ql[ks] = *(const h8*)(qpl + ks*32); }
  }
  __syncthreads();

  f4 sc[SP5] = {};
#pragma unroll
  for (int ks=0; ks<4; ++ks){
#pragma unroll
    for (int nt=0; nt<SP5; ++nt){
      h8 kh = *(const h8*)(Kh_s + (nt*16+lm)*KSTR + ks*32 + g*8);
      h8 kl = *(const h8*)(Kl_s + (nt*16+lm)*KSTR + ks*32 + g*8);
      sc[nt] = __builtin_amdgcn_mfma_f32_16x16x32_f16(qh[ks], kh, sc[nt],0,0,0);
      sc[nt] = __builtin_amdgcn_mfma_f32_16x16x32_f16(ql[ks], kh, sc[nt],0,0,0);
      sc[nt] = __builtin_amdgcn_mfma_f32_16x16x32_f16(qh[ks], kl, sc[nt],0,0,0);
    }
  }

  float mx[4] = {-3e38f,-3e38f,-3e38f,-3e38f};
#pragma unroll
  for (int nt=0; nt<SP5; ++nt){
    bool valid = (nt*16+lm) < S_;
#pragma unroll
    for (int j=0;j<4;++j){
      float v = valid ? sc[nt][j]*scale : -3e38f;
      sc[nt][j] = v;
      mx[j] = fmaxf(mx[j], v);
    }
  }
#pragma unroll
  for (int off=1; off<16; off<<=1){
#pragma unroll
    for (int j=0;j<4;++j) mx[j] = fmaxf(mx[j], __shfl_xor(mx[j], off));
  }
  float sm[4] = {0,0,0,0};
#pragma unroll
  for (int nt=0; nt<SP5; ++nt){
    bool valid = (nt*16+lm) < S_;
#pragma unroll
    for (int j=0;j<4;++j){
      float p = valid ? expf(sc[nt][j]-mx[j]) : 0.f;
      sc[nt][j] = p; sm[j] += p;
    }
  }
#pragma unroll
  for (int off=1; off<16; off<<=1){
#pragma unroll
    for (int j=0;j<4;++j) sm[j] += __shfl_xor(sm[j], off);
  }
#pragma unroll
  for (int nt=0; nt<SP5; ++nt){
#pragma unroll
    for (int j=0;j<4;++j){
      int col = nt*16 + lm;
      if (col < S_){
        float p = sc[nt][j] / sm[j];
        int row = w*16 + g*4 + j;
        _Float16 ph = (_Float16)p;
        Ph[row*VSTR + col] = ph;
        Pl[row*VSTR + col] = (_Float16)(p - (float)ph);
      }
    }
  }
  __syncthreads();

  for (int i = tid; i < 128*VSTR; i += 256) ((uint32_t*)Usm)[i] = 0;
  __syncthreads();
  {
    int oct = tid & 15, s0 = tid >> 4;
    for (int s = s0; s < S_; s += 16){
      size_t ga = ((size_t)(b*S_ + s))*(2*C_) + C_ + h*HD_ + oct*8;
      h8 vh = *(const h8*)(KVh + ga);
      h8 vl = *(const h8*)(KVl + ga);
#pragma unroll
      for (int i2=0;i2<8;++i2){
        VTh[(oct*8+i2)*VSTR + s] = vh[i2];
        VTl[(oct*8+i2)*VSTR + s] = vl[i2];
      }
    }
  }
  __syncthreads();

  h8 pah[3], pal[3];
#pragma unroll
  for (int ks=0;ks<3;++ks){
    pah[ks] = *(const h8*)(Ph + (w*16+lm)*VSTR + ks*32 + g*8);
    pal[ks] = *(const h8*)(Pl + (w*16+lm)*VSTR + ks*32 + g*8);
  }
#pragma unroll
  for (int nt=0; nt<8; ++nt){
    f4 o = {};
#pragma unroll
    for (int ks=0;ks<3;++ks){
      h8 vh = *(const h8*)(VTh + (nt*16+lm)*VSTR + ks*32 + g*8);
      h8 vl = *(const h8*)(VTl + (nt*16+lm)*VSTR + ks*32 + g*8);
      o = __builtin_amdgcn_mfma_f32_16x16x32_f16(pah[ks], vh, o,0,0,0);
      o = __builtin_amdgcn_mfma_f32_16x16x32_f16(pal[ks], vh, o,0,0,0);
      o = __builtin_amdgcn_mfma_f32_16x16x32_f16(pah[ks], vl, o,0,0,0);
    }
#pragma unroll
    for (int j=0;j<4;++j){
      size_t orow = (size_t)(b*T_ + q0 + w*16 + g*4 + j);
      size_t oa = orow*C_ + h*HD_ + nt*16 + lm;
      _Float16 hh = (_Float16)o[j];
      AOh[oa] = hh;
      AOl[oa] = (_Float16)(o[j] - (float)hh);
    }
  }
}

// ---------------- caption gating ----------------
__global__ __launch_bounds__(256) void cap_gate(
    const float* __restrict__ CR, const float* __restrict__ gw, const float* __restrict__ gb,
    int* __restrict__ cap_sel, float* __restrict__ capP, int* __restrict__ counts)
{
  int tid = threadIdx.x, wave = tid >> 6, lane = tid & 63;
  for (int r = 0; r < 4; ++r){
    int row = (blockIdx.x << 4) + (wave << 2) + r;
    const float* xp = CR + (size_t)row * C_;
    float lg[E_];
#pragma unroll
    for (int e = 0; e < E_; ++e){
      const float* wv = gw + (size_t)e * C_;
      float p = 0.f;
      for (int c = lane; c < C_; c += 64) p += xp[c] * wv[c];
#pragma unroll
      for (int off = 32; off; off >>= 1) p += __shfl_xor(p, off);
      lg[e] = p + gb[e];
    }
    if (lane == 0){
      float z[E_], m = -3.4e38f;
      for (int e = 0; e < E_; ++e){
        float gmb = jax_gumbel(0u, 2u, (uint32_t)(row*E_ + e));
        z[e] = (lg[e] + gmb) * 0.5f;
        m = fmaxf(m, z[e]);
      }
      float y[E_], sum = 0.f;
      for (int e = 0; e < E_; ++e){ y[e] = expf(z[e] - m); sum += y[e]; }
      for (int e = 0; e < E_; ++e) y[e] = y[e] / sum;
      int best = 0; float bv = y[0];
      for (int e = 1; e < E_; ++e) if (y[e] > bv){ bv = y[e]; best = e; }
      cap_sel[row] = best;
      atomicAdd(&counts[best], 1);
      for (int e = 0; e < E_; ++e)
        capP[(size_t)row*E_ + e] = ((e == best) ? 1.0f : 0.0f) - y[e] + y[e];
    }
  }
}

// ---------------- expert grouping ----------------
__global__ void build_groups(const int* __restrict__ counts, int* __restrict__ offs,
                             int* __restrict__ cursor, int* __restrict__ bmap_e,
                             int* __restrict__ bmap_s)
{
  offs[0] = 0;
  for (int e = 0; e < E_; ++e){ offs[e+1] = offs[e] + counts[e]; cursor[e] = offs[e]; }
  int idx = 0;
  for (int e = 0; e < E_; ++e)
    for (int s = offs[e]; s < offs[e+1]; s += GTILE){ bmap_e[idx] = e; bmap_s[idx] = s; ++idx; }
  for (; idx < MAXGB; ++idx) bmap_e[idx] = -1;
}

__global__ __launch_bounds__(256) void scatter_perm(
    const int* __restrict__ cap_sel, int* __restrict__ cursor, int* __restrict__ perm)
{
  int row = blockIdx.x * 256 + threadIdx.x;
  int e = cap_sel[row];
  int pos = atomicAdd(&cursor[e], 1);
  perm[pos] = row;
}

// ---------------- loss ----------------
__global__ __launch_bounds__(256) void loss_kernel(
    const float* __restrict__ capP, const float* __restrict__ langP, float* __restrict__ out_loss)
{
  __shared__ float red[4][256];
  int tid = threadIdx.x;
  float p0=0.f, p1=0.f, p2=0.f, p3=0.f;
  for (int r = tid; r < N_; r += 256){
    const float* p = capP + (size_t)r*E_;
    p0 += p[0]; p1 += p[1]; p2 += p[2]; p3 += p[3];
  }
  red[0][tid]=p0; red[1][tid]=p1; red[2][tid]=p2; red[3][tid]=p3;
  __syncthreads();
  for (int s = 128; s > 0; s >>= 1){
    if (tid < s){
      red[0][tid]+=red[0][tid+s]; red[1][tid]+=red[1][tid+s];
      red[2][tid]+=red[2][tid+s]; red[3][tid]+=red[3][tid+s];
    }
    __syncthreads();
  }
  if (tid == 0){
    float loss = 0.f;
    for (int e = 0; e < E_; ++e){
      float ul = (langP[e] + langP[E_ + e]) * 0.5f;
      loss += ul * logf(ul + 1e-10f);
    }
    for (int e = 0; e < E_; ++e){
      float uc = red[e][0] * (1.0f / N_);
      loss += uc * logf(uc + 1e-10f);
    }
    out_loss[0] = loss;
  }
}

// ---------------- host launch ----------------
extern "C" void kernel_launch(void* const* d_in, const int* in_sizes, int n_in,
                              void* d_out, int out_size, void* d_ws, size_t ws_size,
                              hipStream_t stream)
{
  const float* x          = (const float*)d_in[0];
  const float* caption    = (const float*)d_in[2];
  const int*   language   = (const int*)  d_in[3];
  const float* lang_embed = (const float*)d_in[4];
  const float* lang_gw    = (const float*)d_in[5];
  const float* lang_gb    = (const float*)d_in[6];
  const float* lang_w1    = (const float*)d_in[7];
  const float* lang_w2    = (const float*)d_in[8];
  const float* lang_w3    = (const float*)d_in[9];
  const float* in_w       = (const float*)d_in[10];
  const float* in_b       = (const float*)d_in[11];
  const float* out_w      = (const float*)d_in[12];
  const float* out_b      = (const float*)d_in[13];
  const float* cap_gw     = (const float*)d_in[14];
  const float* cap_gb     = (const float*)d_in[15];
  const float* cap_w1     = (const float*)d_in[16];
  const float* cap_w2     = (const float*)d_in[17];
  const float* cap_w3     = (const float*)d_in[18];
  float* out = (float*)d_out;

  const size_t NC = (size_t)N_*C_;
  const size_t NHe = (size_t)N_*H_;
  const size_t KVel = (size_t)B_*S_*2*C_;
  const size_t CAPel = (size_t)B_*S_*C_;

  char* base = (char*)d_ws;
  size_t cur = 0;
  auto alloc = [&](size_t bytes)->char*{
    char* p = base + cur;
    cur += (bytes + 255) & ~(size_t)255;
    return p;
  };
  float* Qcross = (float*)alloc(NC*4);            // Qh/Ql f16, then cross f32
  _Float16* Qh = (_Float16*)Qcross;
  _Float16* Ql = Qh + NC;
  char* kvreg = alloc(KVel*4);
  _Float16* KVh = (_Float16*)kvreg;
  _Float16* KVl = KVh + KVel;
  float* capP   = (float*)alloc((size_t)N_*E_*4);
  float* langP  = (float*)alloc(64);
  int* lang_sel = (int*)alloc(64);
  int* cap_sel  = (int*)alloc(N_*4);
  int* counts   = (int*)alloc(64);
  int* offs     = (int*)alloc(64);
  int* cursor   = (int*)alloc(64);
  int* bmap_e   = (int*)alloc(MAXGB*4);
  int* bmap_s   = (int*)alloc(MAXGB*4);
  int* perm     = (int*)alloc(N_*4);
  _Float16* xAO_hi = (_Float16*)alloc(NC*2);      // x_hi, then AO_hi
  _Float16* xAO_lo = (_Float16*)alloc(NC*2);
  _Float16* cap_hi = (_Float16*)alloc(CAPel*2);
  _Float16* cap_lo = (_Float16*)alloc(CAPel*2);
  _Float16* Hb_hi  = (_Float16*)alloc(NHe*2);     // stage-1 hidden hi, then H2
  _Float16* Hb_lo  = (_Float16*)alloc(NHe*2);
  _Float16* F_hi   = (_Float16*)alloc(NC*2);
  _Float16* F_lo   = (_Float16*)alloc(NC*2);
  _Float16* Wreg = (_Float16*)alloc(2*( (size_t)3*C_*C_*2 + (size_t)C_*C_*2 + 3*4*PEsz ));
  // phase1 (lang): W13 interleaved split [2 slots][2H][C] + w2 split [2 slots][C][H]
  _Float16* w13hi = Wreg;                 // 4*PEsz
  _Float16* w13lo = Wreg + 4*PEsz;        // 4*PEsz
  _Float16* w2hi  = Wreg + 8*PEsz;        // 2*PEsz
  _Float16* w2lo  = Wreg + 10*PEsz;       // 2*PEsz
  // phase2: proj split + cap W13 interleaved plain + cap w2 plain
  _Float16* inw_hi  = Wreg;
  _Float16* inw_lo  = inw_hi + (size_t)3*C_*C_;
  _Float16* outw_hi = inw_lo + (size_t)3*C_*C_;
  _Float16* outw_lo = outw_hi + (size_t)C_*C_;
  _Float16* capw13f = outw_lo + (size_t)C_*C_;    // 8*PEsz (4 experts x 2H x C)
  _Float16* capw2f  = capw13f + 8*PEsz;           // 4*PEsz

  // ---- phase 0: gating setup + conversions ----
  setup_lang<<<1, 256, 0, stream>>>(lang_embed, lang_gw, lang_gb, language, langP, lang_sel, counts);
  conv_w13<true><<<2048, 256, 0, stream>>>(lang_w1, lang_w3, lang_sel, 2, w13hi, w13lo);
  conv_split_sel<<<1024, 256, 0, stream>>>(lang_w2, lang_sel, 0, w2hi, w2lo, (long)(PEsz/4));
  conv_split_sel<<<1024, 256, 0, stream>>>(lang_w2, lang_sel, 1, w2hi+PEsz, w2lo+PEsz, (long)(PEsz/4));
  conv_split<<<2048, 256, 0, stream>>>(x, xAO_hi, xAO_lo, (long)(NC/4));
  conv_split<<<256, 256, 0, stream>>>(caption, cap_hi, cap_lo, (long)(CAPel/4));

  // ---- stage-1 FFN (split via K-extension) ----
  gemm8<3,3,1><<<dim3((2*H_)/128, N_/128), 256, 0, stream>>>(
      xAO_hi, xAO_lo, w13hi, w13lo, nullptr, nullptr, Hb_hi, Hb_lo,
      nullptr, nullptr, nullptr, nullptr, N_, C_, H_, 2*PEsz);
  gemm8<1,3,1><<<dim3(C_/128, N_/128), 256, 0, stream>>>(
      Hb_hi, Hb_lo, w2hi, w2lo, nullptr, nullptr, F_hi, F_lo,
      nullptr, nullptr, nullptr, nullptr, N_, H_, C_, PEsz);

  // ---- phase-2 weight conversions (reuse Wreg) ----
  conv_split<<<2048, 256, 0, stream>>>(in_w, inw_hi, inw_lo, (long)((size_t)3*C_*C_/4));
  conv_split<<<1024, 256, 0, stream>>>(out_w, outw_hi, outw_lo, (long)((size_t)C_*C_/4));
  conv_w13<false><<<2048, 256, 0, stream>>>(cap_w1, cap_w3, nullptr, 4, capw13f, nullptr);
  conv_plain<<<2048, 256, 0, stream>>>(cap_w2, capw2f, (long)(4*PEsz/4));

  // ---- projections + attention ----
  gemm8<1,3,0><<<dim3(C_/128, N_/128), 256, 0, stream>>>(       // Q -> Qh/Ql
      F_hi, F_lo, inw_hi, inw_lo, in_b, nullptr, Qh, Ql,
      nullptr, nullptr, nullptr, nullptr, N_, C_, C_, 0);
  gemm8<1,3,0><<<dim3((2*C_)/128, 2), 256, 0, stream>>>(        // K|V -> KVh/KVl
      cap_hi, cap_lo, inw_hi + (size_t)C_*C_, inw_lo + (size_t)C_*C_, in_b + C_,
      nullptr, KVh, KVl,
      nullptr, nullptr, nullptr, nullptr, B_*S_, C_, 2*C_, 0);
  attn_mfma<<<dim3(T_/64, NH_, B_), 256, 0, stream>>>(Qh, Ql, KVh, KVl, xAO_hi, xAO_lo);
  gemm8<0,3,0><<<dim3(C_/128, N_/128), 256, 0, stream>>>(       // out-proj -> cross (f32)
      xAO_hi, xAO_lo, outw_hi, outw_lo, out_b, Qcross, nullptr, nullptr,
      nullptr, nullptr, nullptr, nullptr, N_, C_, C_, 0);

  // ---- caption gating + grouping ----
  cap_gate<<<N_/16, 256, 0, stream>>>(Qcross, cap_gw, cap_gb, cap_sel, capP, counts);
  build_groups<<<1, 1, 0, stream>>>(counts, offs, cursor, bmap_e, bmap_s);
  scatter_perm<<<N_/256, 256, 0, stream>>>(cap_sel, cursor, perm);

  // ---- stage-2 FFN (plain f16) ----
  _Float16* H2 = Hb_hi;
  gemm8<4,1,2><<<dim3((2*H_)/128, MAXGB), 256, 0, stream>>>(
      F_hi, nullptr, capw13f, nullptr, nullptr, nullptr, H2, nullptr,
      bmap_e, bmap_s, offs, perm, N_, C_, H_, 2*PEsz);
  gemm8<2,1,3><<<dim3(C_/128, MAXGB), 256, 0, stream>>>(
      H2, nullptr, capw2f, nullptr, nullptr, out, F_hi, F_lo,
      bmap_e, bmap_s, offs, perm, N_, H_, C_, PEsz);

  loss_kernel<<<1, 256, 0, stream>>>(capP, langP, out + NC);
}

// Round 5
// 779.835 us; speedup vs baseline: 3.4769x; 1.0279x over previous
//
#include <hip/hip_runtime.h>
#include <stdint.h>

// Problem constants
#define B_ 2
#define T_ 2048
#define S_ 77
#define C_ 1024
#define E_ 4
#define H_ 2816
#define NH_ 8
#define HD_ 128
#define N_ (B_*T_)            // 4096 tokens
#define MAXGB (N_/128 + E_)   // 36 row-tiles of 128 (ffn2_out)
#define MAXGB2 (N_/256 + E_)  // 20 row-tiles of 256 (ffn2_gate)
#define PEsz ((size_t)H_*C_)  // per-expert matrix elems (H*C)

typedef _Float16 h8 __attribute__((ext_vector_type(8)));
typedef _Float16 h4 __attribute__((ext_vector_type(4)));
typedef float f4 __attribute__((ext_vector_type(4)));

__device__ __forceinline__ void gload16(const void* g, void* l){
  __builtin_amdgcn_global_load_lds((const __attribute__((address_space(1))) void*)g,
                                   (__attribute__((address_space(3))) void*)l, 16, 0, 0);
}

// bijective XCD swizzle (m204)
__device__ __forceinline__ void xcd_swizzle(int& bx, int& by){
  int nx = gridDim.x, ny = gridDim.y;
  int nwg = nx*ny;
  int wg = by*nx + bx;
  int q = nwg >> 3, r = nwg & 7;
  int xcd = wg & 7, idx = wg >> 3;
  int s = (xcd < r ? xcd*(q+1) : r*(q+1) + (xcd-r)*q) + idx;
  bx = s % nx; by = s / nx;
}

// ---------------- Threefry-2x32 (JAX partitionable) ----------------
__device__ __forceinline__ uint32_t rotl32(uint32_t v, int r){ return (v<<r)|(v>>(32-r)); }
__device__ __forceinline__ void threefry2x32(uint32_t k0, uint32_t k1,
                                             uint32_t x, uint32_t y,
                                             uint32_t& o0, uint32_t& o1){
  uint32_t k2 = k0 ^ k1 ^ 0x1BD11BDAu;
  x += k0; y += k1;
#define TFR(r) { x += y; y = rotl32(y, r); y ^= x; }
  TFR(13) TFR(15) TFR(26) TFR(6)   x += k1; y += k2 + 1u;
  TFR(17) TFR(29) TFR(16) TFR(24)  x += k2; y += k0 + 2u;
  TFR(13) TFR(15) TFR(26) TFR(6)   x += k0; y += k1 + 3u;
  TFR(17) TFR(29) TFR(16) TFR(24)  x += k1; y += k2 + 4u;
  TFR(13) TFR(15) TFR(26) TFR(6)   x += k2; y += k0 + 5u;
#undef TFR
  o0 = x; o1 = y;
}
__device__ __forceinline__ float gumbel_from_bits(uint32_t bits){
  const float TINY = 1.17549435e-38f;
  float f = __uint_as_float((bits >> 9) | 0x3f800000u) - 1.0f;
  float u = fmaxf(TINY, f + TINY);
  return -logf(-logf(u));
}
__device__ __forceinline__ float jax_gumbel(uint32_t k0, uint32_t k1, uint32_t idx){
  uint32_t a, b;
  threefry2x32(k0, k1, 0u, idx, a, b);
  return gumbel_from_bits(a ^ b);
}

// ---------------- language gating ----------------
__global__ __launch_bounds__(256) void setup_lang(
    const float* __restrict__ lang_embed, const float* __restrict__ gate_w,
    const float* __restrict__ gate_b, const int* __restrict__ language,
    float* __restrict__ langP, int* __restrict__ lang_sel, int* __restrict__ counts)
{
  __shared__ float red[256];
  __shared__ float logits[8];
  int tid = threadIdx.x;
  for (int be = 0; be < 8; ++be){
    int b = be >> 2, e = be & 3;
    const float* emb = lang_embed + (size_t)language[b] * C_;
    const float* gw  = gate_w + (size_t)e * C_;
    float p = 0.f;
    for (int c = tid; c < C_; c += 256) p += emb[c] * gw[c];
    red[tid] = p; __syncthreads();
    for (int s = 128; s > 0; s >>= 1){
      if (tid < s) red[tid] += red[tid + s];
      __syncthreads();
    }
    if (tid == 0) logits[be] = red[0] + gate_b[e];
    __syncthreads();
  }
  if (tid == 0){
    for (int b = 0; b < B_; ++b){
      float z[E_], m = -3.4e38f;
      for (int e = 0; e < E_; ++e){
        float gmb = jax_gumbel(0u, 1u, (uint32_t)(b*E_ + e));
        z[e] = (logits[b*E_ + e] + gmb) * 0.5f;
        m = fmaxf(m, z[e]);
      }
      float y[E_], sum = 0.f;
      for (int e = 0; e < E_; ++e){ y[e] = expf(z[e] - m); sum += y[e]; }
      for (int e = 0; e < E_; ++e) y[e] = y[e] / sum;
      int best = 0; float bv = y[0];
      for (int e = 1; e < E_; ++e) if (y[e] > bv){ bv = y[e]; best = e; }
      lang_sel[b] = best;
      for (int e = 0; e < E_; ++e)
        langP[b*E_ + e] = ((e == best) ? 1.0f : 0.0f) - y[e] + y[e];
    }
    for (int e = 0; e < E_; ++e) counts[e] = 0;
  }
}

// ---------------- conversion kernels ----------------
__global__ __launch_bounds__(256) void conv_split(const float* __restrict__ s,
    _Float16* __restrict__ hi, _Float16* __restrict__ lo, long n4){
  long i = (long)blockIdx.x*256 + threadIdx.x;
  long stride = (long)gridDim.x*256;
  for (; i < n4; i += stride){
    float4 v = ((const float4*)s)[i];
    h4 h, L;
    h[0]=(_Float16)v.x; h[1]=(_Float16)v.y; h[2]=(_Float16)v.z; h[3]=(_Float16)v.w;
    L[0]=(_Float16)(v.x-(float)h[0]); L[1]=(_Float16)(v.y-(float)h[1]);
    L[2]=(_Float16)(v.z-(float)h[2]); L[3]=(_Float16)(v.w-(float)h[3]);
    ((h4*)hi)[i] = h; ((h4*)lo)[i] = L;
  }
}
__global__ __launch_bounds__(256) void conv_plain(const float* __restrict__ s,
    _Float16* __restrict__ d, long n4){
  long i = (long)blockIdx.x*256 + threadIdx.x;
  long stride = (long)gridDim.x*256;
  for (; i < n4; i += stride){
    float4 v = ((const float4*)s)[i];
    h4 h;
    h[0]=(_Float16)v.x; h[1]=(_Float16)v.y; h[2]=(_Float16)v.z; h[3]=(_Float16)v.w;
    ((h4*)d)[i] = h;
  }
}
// w2-style selected-expert split (layout unchanged [C][H])
__global__ __launch_bounds__(256) void conv_split_sel(const float* __restrict__ base,
    const int* __restrict__ sel, int slot,
    _Float16* __restrict__ hi, _Float16* __restrict__ lo, long n4){
  const float* s = base + (size_t)sel[slot]*PEsz;
  long i = (long)blockIdx.x*256 + threadIdx.x;
  long stride = (long)gridDim.x*256;
  for (; i < n4; i += stride){
    float4 v = ((const float4*)s)[i];
    h4 h, L;
    h[0]=(_Float16)v.x; h[1]=(_Float16)v.y; h[2]=(_Float16)v.z; h[3]=(_Float16)v.w;
    L[0]=(_Float16)(v.x-(float)h[0]); L[1]=(_Float16)(v.y-(float)h[1]);
    L[2]=(_Float16)(v.z-(float)h[2]); L[3]=(_Float16)(v.w-(float)h[3]);
    ((h4*)hi)[i] = h; ((h4*)lo)[i] = L;
  }
}
// W1/W3 -> interleaved W13 (16-row groups: [w1 16 | w3 16] per 32)
template<bool SPLIT>
__global__ __launch_bounds__(256) void conv_w13(
    const float* __restrict__ w1, const float* __restrict__ w3,
    const int* __restrict__ sel, int nslot,
    _Float16* __restrict__ hi, _Float16* __restrict__ lo)
{
  const int K8 = C_/8;
  long total = (long)nslot * (2*H_) * K8;
  for (long i = (long)blockIdx.x*256 + threadIdx.x; i < total; i += (long)gridDim.x*256){
    int kv = (int)(i & (K8-1));
    long rs = i >> 7;
    int r  = (int)(rs % (2*H_));
    int slot = (int)(rs / (2*H_));
    int e = SPLIT ? sel[slot] : slot;
    int gg = r >> 5, o = r & 31;
    const float* src = ((o<16)? w1 : w3) + (size_t)e*PEsz + (size_t)(16*gg + (o&15))*C_ + kv*8;
    float4 v0 = *(const float4*)src, v1 = *(const float4*)(src+4);
    float vv[8] = {v0.x,v0.y,v0.z,v0.w,v1.x,v1.y,v1.z,v1.w};
    h8 hh, ll;
#pragma unroll
    for (int jj=0;jj<8;++jj){
      hh[jj] = (_Float16)vv[jj];
      if constexpr (SPLIT) ll[jj] = (_Float16)(vv[jj]-(float)hh[jj]);
    }
    size_t dof = (size_t)slot*2*PEsz + (size_t)r*C_ + kv*8;
    *(h8*)(hi + dof) = hh;
    if constexpr (SPLIT) *(h8*)(lo + dof) = ll;
  }
}

// ============ deep-pipelined 256x128 split gate GEMM (ffn1_gate) ============
// H(hi/lo) = silu(X W1^T) * (X W3^T), split fp16 (3 terms), expert slot by m-block.
// BK=32, 512 thr / 8 waves (4M x 2N), wave-tile 64x64, 3-buffer LDS ring (144KB),
// depth-2 prefetch, counted vmcnt(12), hi/lo interleaved 128B LDS rows + XOR swizzle.
__global__ __launch_bounds__(512,2) void gemm_gate_split(
    const _Float16* __restrict__ Ahi, const _Float16* __restrict__ Alo,
    const _Float16* __restrict__ Bhi, const _Float16* __restrict__ Blo,
    _Float16* __restrict__ Hhi, _Float16* __restrict__ Hlo)
{
  __shared__ __align__(16) char smem[147456];   // 3 x (A 32KB + B 16KB)
  const int tid = threadIdx.x, w = tid>>6, l = tid&63;
  const int lm = l&15, g = l>>4;
  const int wm = w>>1, wn = w&1;
  int bx = blockIdx.x, by = blockIdx.y;
  xcd_swizzle(bx, by);
  const int n0 = bx<<7;          // 0..5631 (N'=2H)
  const int m0 = by<<8;          // 0..4095
  const size_t eoff = (m0 >= T_) ? (size_t)2*PEsz : 0;

  // staging sources: A chunks jj=0..3 (c=jj*512+tid), B chunks jj=0..1
  const _Float16* srcA[4]; const _Float16* srcB[2];
#pragma unroll
  for (int jj=0;jj<4;++jj){
    int c = jj*512 + tid, r = c>>3, s = c&7;
    int st = s ^ (r&7);
    srcA[jj] = (st<4 ? Ahi : Alo) + (size_t)(m0 + r)*C_ + ((st&3)<<3);
  }
#pragma unroll
  for (int jj=0;jj<2;++jj){
    int c = jj*512 + tid, r = c>>3, s = c&7;
    int st = s ^ (r&7);
    srcB[jj] = (st<4 ? Bhi : Blo) + eoff + (size_t)(n0 + r)*C_ + ((st&3)<<3);
  }

#define STG(ts, bi) { \
    int k0 = (ts)<<5; \
    char* db = smem + (bi)*49152; \
    _Pragma("unroll") \
    for (int jj=0;jj<4;++jj) gload16(srcA[jj]+k0, db + (jj*512 + w*64)*16); \
    _Pragma("unroll") \
    for (int jj=0;jj<2;++jj) gload16(srcB[jj]+k0, db + 32768 + (jj*512 + w*64)*16); \
  }

  const int shi = (g ^ (lm&7)) << 4;
  int aoff[4], boff[4];
#pragma unroll
  for (int i=0;i<4;++i){
    aoff[i] = ((wm*64 + i*16 + lm)<<7) + shi;
    boff[i] = 32768 + ((wn*64 + i*16 + lm)<<7) + shi;
  }

  f4 acc[4][4] = {};
  const int nt = C_/32;   // 32
  STG(0,0) STG(1,1)
  for (int t=0; t<nt; ++t){
    const int bi = t%3;
    const int ts = (t+2 < nt) ? t+2 : 0;
    STG(ts, (t+2)%3)
    asm volatile("s_waitcnt vmcnt(12)" ::: "memory");
    __builtin_amdgcn_s_barrier();
    asm volatile("" ::: "memory");
    const char* base = smem + bi*49152;
    // P1: hh
    h8 ah[4], bh[4];
#pragma unroll
    for (int i=0;i<4;++i){ ah[i] = *(const h8*)(base + aoff[i]); bh[i] = *(const h8*)(base + boff[i]); }
    __builtin_amdgcn_s_setprio(1);
#pragma unroll
    for (int mi=0;mi<4;++mi)
#pragma unroll
      for (int ni=0;ni<4;++ni)
        acc[mi][ni] = __builtin_amdgcn_mfma_f32_16x16x32_f16(ah[mi], bh[ni], acc[mi][ni],0,0,0);
    __builtin_amdgcn_s_setprio(0);
    // P2: ah x blo
    h8 bl[4];
#pragma unroll
    for (int i=0;i<4;++i) bl[i] = *(const h8*)(base + (boff[i]^64));
    __builtin_amdgcn_s_setprio(1);
#pragma unroll
    for (int mi=0;mi<4;++mi)
#pragma unroll
      for (int ni=0;ni<4;++ni)
        acc[mi][ni] = __builtin_amdgcn_mfma_f32_16x16x32_f16(ah[mi], bl[ni], acc[mi][ni],0,0,0);
    __builtin_amdgcn_s_setprio(0);
    // P3: alo x bh
    h8 al[4];
#pragma unroll
    for (int i=0;i<4;++i) al[i] = *(const h8*)(base + (aoff[i]^64));
    __builtin_amdgcn_s_setprio(1);
#pragma unroll
    for (int mi=0;mi<4;++mi)
#pragma unroll
      for (int ni=0;ni<4;++ni)
        acc[mi][ni] = __builtin_amdgcn_mfma_f32_16x16x32_f16(al[mi], bh[ni], acc[mi][ni],0,0,0);
    __builtin_amdgcn_s_setprio(0);
    asm volatile("" ::: "memory");
    __builtin_amdgcn_s_barrier();
  }
#undef STG

  // epilogue: silu pair (even 16-group = w1, odd = w3) -> hi/lo
#pragma unroll
  for (int mi=0;mi<4;++mi){
#pragma unroll
    for (int p=0;p<2;++p){
      int hc = ((n0 + wn*64)>>1) + p*16 + lm;
#pragma unroll
      for (int j=0;j<4;++j){
        int rl = wm*64 + mi*16 + (g<<2) + j;
        float s1 = acc[mi][2*p][j], s3 = acc[mi][2*p+1][j];
        float hval = s1/(1.f+expf(-s1))*s3;
        size_t row = (size_t)(m0 + rl);
        _Float16 hh = (_Float16)hval;
        Hhi[row*H_ + hc] = hh;
        Hlo[row*H_ + hc] = (_Float16)(hval - (float)hh);
      }
    }
  }
}

// ============ deep-pipelined 256x128 plain gate GEMM (ffn2_gate) ============
// BK=64, plain f16, grouped rows (256-tile bmap2) + perm gather, same ring schedule.
__global__ __launch_bounds__(512,2) void gemm_gate_plain(
    const _Float16* __restrict__ A, const _Float16* __restrict__ Bw,
    _Float16* __restrict__ Hout,
    const int* __restrict__ bmap_e, const int* __restrict__ bmap_s,
    const int* __restrict__ offs, const int* __restrict__ perm)
{
  __shared__ __align__(16) char smem[147456];
  const int tid = threadIdx.x, w = tid>>6, l = tid&63;
  const int lm = l&15, g = l>>4;
  const int wm = w>>1, wn = w&1;
  int bx = blockIdx.x, by = blockIdx.y;
  xcd_swizzle(bx, by);
  const int e = bmap_e[by]; if (e<0) return;
  const int m0 = bmap_s[by];
  int v = offs[e+1]-m0; const int valid = v>256?256:v;
  const size_t eoff = (size_t)e*2*PEsz;
  const int n0 = bx<<7;

  const _Float16* srcA[4]; const _Float16* srcB[2];
#pragma unroll
  for (int jj=0;jj<4;++jj){
    int c = jj*512 + tid, r = c>>3, s = c&7;
    int st = s ^ (r&7);
    int ia = m0 + r; ia = (ia<N_) ? ia : (N_-1);
    srcA[jj] = A + (size_t)perm[ia]*C_ + (st<<3);
  }
#pragma unroll
  for (int jj=0;jj<2;++jj){
    int c = jj*512 + tid, r = c>>3, s = c&7;
    int st = s ^ (r&7);
    srcB[jj] = Bw + eoff + (size_t)(n0 + r)*C_ + (st<<3);
  }

#define STG(ts, bi) { \
    int k0 = (ts)<<6; \
    char* db = smem + (bi)*49152; \
    _Pragma("unroll") \
    for (int jj=0;jj<4;++jj) gload16(srcA[jj]+k0, db + (jj*512 + w*64)*16); \
    _Pragma("unroll") \
    for (int jj=0;jj<2;++jj) gload16(srcB[jj]+k0, db + 32768 + (jj*512 + w*64)*16); \
  }

  const int shi = (g ^ (lm&7)) << 4;
  int aoff[4], boff[4];
#pragma unroll
  for (int i=0;i<4;++i){
    aoff[i] = ((wm*64 + i*16 + lm)<<7) + shi;
    boff[i] = 32768 + ((wn*64 + i*16 + lm)<<7) + shi;
  }

  f4 acc[4][4] = {};
  const int nt = C_/64;   // 16
  STG(0,0) STG(1,1)
  for (int t=0; t<nt; ++t){
    const int bi = t%3;
    const int ts = (t+2 < nt) ? t+2 : 0;
    STG(ts, (t+2)%3)
    asm volatile("s_waitcnt vmcnt(12)" ::: "memory");
    __builtin_amdgcn_s_barrier();
    asm volatile("" ::: "memory");
    const char* base = smem + bi*49152;
#pragma unroll
    for (int kk=0;kk<2;++kk){
      h8 af[4], bf[4];
      const int x = kk<<6;
#pragma unroll
      for (int i=0;i<4;++i){ af[i] = *(const h8*)(base + (aoff[i]^x)); bf[i] = *(const h8*)(base + (boff[i]^x)); }
      __builtin_amdgcn_s_setprio(1);
#pragma unroll
      for (int mi=0;mi<4;++mi)
#pragma unroll
        for (int ni=0;ni<4;++ni)
          acc[mi][ni] = __builtin_amdgcn_mfma_f32_16x16x32_f16(af[mi], bf[ni], acc[mi][ni],0,0,0);
      __builtin_amdgcn_s_setprio(0);
    }
    asm volatile("" ::: "memory");
    __builtin_amdgcn_s_barrier();
  }
#undef STG

#pragma unroll
  for (int mi=0;mi<4;++mi){
#pragma unroll
    for (int p=0;p<2;++p){
      int hc = ((n0 + wn*64)>>1) + p*16 + lm;
#pragma unroll
      for (int j=0;j<4;++j){
        int rl = wm*64 + mi*16 + (g<<2) + j;
        if (rl >= valid) continue;
        float s1 = acc[mi][2*p][j], s3 = acc[mi][2*p+1][j];
        Hout[(size_t)(m0 + rl)*H_ + hc] = (_Float16)(s1/(1.f+expf(-s1))*s3);
      }
    }
  }
}

// ---------------- unified pipelined GEMM (128x128, from r4) ----------------
// EPI: 0 f32+bias, 1 f16 hi/lo (+opt bias), 2 scatter-add
// EXPM: 0 none, 1 lang slot by m-block, 3 grouped rows + linear A
template<int EPI, int NSEG, int EXPM>
__global__ __launch_bounds__(256,2) void gemm8(
    const _Float16* __restrict__ A0, const _Float16* __restrict__ A1,
    const _Float16* __restrict__ B0, const _Float16* __restrict__ B1,
    const float* __restrict__ bias, float* __restrict__ Cf32,
    _Float16* __restrict__ O0, _Float16* __restrict__ O1,
    const int* __restrict__ bmap_e, const int* __restrict__ bmap_s,
    const int* __restrict__ offs, const int* __restrict__ perm,
    int M, int K, int Nw, size_t bstride_e)
{
  __shared__ __align__(16) char smem[65536];
  const int tid = threadIdx.x, w = tid>>6, l = tid&63;
  const int lm = l&15, g = l>>4;
  const int wm = w>>1, wn = w&1;
  int bx = blockIdx.x, by = blockIdx.y;
  xcd_swizzle(bx, by);
  const int n0 = bx<<7;
  int m0, valid = 128; size_t eoff = 0;
  if constexpr (EXPM==3){
    int e = bmap_e[by]; if (e<0) return;
    m0 = bmap_s[by];
    int v = offs[e+1]-m0; valid = v>128?128:v;
    eoff = (size_t)e*bstride_e;
  } else {
    m0 = by<<7;
    if constexpr (EXPM==1) eoff = (m0>=T_) ? bstride_e : 0;
  }
  const int cAe = (((tid&7) ^ ((tid>>3)&7)) << 3);
  size_t rbA[4], rbB[4];
#pragma unroll
  for (int j=0;j<4;++j){
    int r = (j<<5) + (tid>>3);
    int ia = m0 + r;
    if constexpr (EXPM==3){ ia = (ia < N_) ? ia : (N_-1); }
    else { if (ia > M-1) ia = M-1; }
    rbA[j] = (size_t)ia*K + cAe;
    rbB[j] = eoff + (size_t)(n0+r)*K + cAe;
  }
  const int tps = K>>6, nt = NSEG*tps;

#define STAGE8(tt, cc) { \
    int sg = 0; \
    if constexpr (NSEG==3){ sg = ((tt)>=2*tps) ? 2 : (((tt)>=tps)?1:0); } \
    const _Float16* Asrc = (sg==1) ? A1 : A0; \
    const _Float16* Bsrc = (sg==2) ? B1 : B0; \
    int kk0 = ((tt) - sg*tps)<<6; \
    char* db = smem + (cc)*32768 + w*1024; \
    _Pragma("unroll") \
    for (int j=0;j<4;++j) gload16(Asrc + rbA[j] + kk0, db + j*4096); \
    _Pragma("unroll") \
    for (int j=0;j<4;++j) gload16(Bsrc + rbB[j] + kk0, db + 16384 + j*4096); \
  }

  int aoff[2][4], boff[2][4];
#pragma unroll
  for (int kk=0;kk<2;++kk){
#pragma unroll
    for (int i=0;i<4;++i){
      int ra = wm*64 + i*16 + lm;
      aoff[kk][i] = (ra<<7) + (((kk<<6)+(g<<4)) ^ ((ra&7)<<4));
      int rb = wn*64 + i*16 + lm;
      boff[kk][i] = (rb<<7) + (((kk<<6)+(g<<4)) ^ ((rb&7)<<4));
    }
  }

  f4 acc[4][4] = {};
  STAGE8(0, 0)
  for (int t=0; t<nt; ++t){
    const int c = t&1;
    if (t+1 < nt){
      STAGE8(t+1, c^1)
      asm volatile("s_waitcnt vmcnt(8)" ::: "memory");
    } else {
      asm volatile("s_waitcnt vmcnt(0)" ::: "memory");
    }
    __builtin_amdgcn_s_barrier();
    const char* Ab = smem + c*32768;
    const char* Bb = Ab + 16384;
#pragma unroll
    for (int kk=0;kk<2;++kk){
      h8 af[4], bf[4];
#pragma unroll
      for (int i=0;i<4;++i){
        af[i] = *(const h8*)(Ab + aoff[kk][i]);
        bf[i] = *(const h8*)(Bb + boff[kk][i]);
      }
      __builtin_amdgcn_s_setprio(1);
#pragma unroll
      for (int mi=0;mi<4;++mi)
#pragma unroll
        for (int ni=0;ni<4;++ni)
          acc[mi][ni] = __builtin_amdgcn_mfma_f32_16x16x32_f16(af[mi], bf[ni], acc[mi][ni],0,0,0);
      __builtin_amdgcn_s_setprio(0);
      __builtin_amdgcn_s_barrier();
    }
  }

#pragma unroll
  for (int mi=0;mi<4;++mi){
    const int rl0 = wm*64 + mi*16 + (g<<2);
#pragma unroll
    for (int ni=0;ni<4;++ni){
      int col = n0 + wn*64 + ni*16 + lm;
#pragma unroll
      for (int j=0;j<4;++j){
        int rl = rl0 + j;
        float vv = acc[mi][ni][j];
        if constexpr (EPI==0){
          int grow = m0 + rl;
          if (grow < M) Cf32[(size_t)grow*Nw + col] = vv + bias[col];
        } else if constexpr (EPI==1){
          int grow = m0 + rl;
          if (grow < M){
            float vb = vv + (bias ? bias[col] : 0.f);
            _Float16 hh = (_Float16)vb;
            O0[(size_t)grow*Nw + col] = hh;
            O1[(size_t)grow*Nw + col] = (_Float16)(vb - (float)hh);
          }
        } else {
          if (rl < valid){
            int orig = perm[m0 + rl];
            size_t o = (size_t)orig*C_ + col;
            Cf32[o] = (float)O0[o] + (float)O1[o] + vv;
          }
        }
      }
    }
  }
#undef STAGE8
}

// ---------------- MFMA cross attention (unchanged) ----------------
#define SP5 5
#define KSTR 136
#define VSTR 104
__global__ __launch_bounds__(256) void attn_mfma(
    const _Float16* __restrict__ Qh, const _Float16* __restrict__ Ql,
    const _Float16* __restrict__ KVh, const _Float16* __restrict__ KVl,
    _Float16* __restrict__ AOh, _Float16* __restrict__ AOl)
{
  __shared__ __align__(16) _Float16 Usm[2*128*VSTR];
  __shared__ __align__(16) _Float16 Psm[2*64*VSTR];
  _Float16* Kh_s = Usm;
  _Float16* Kl_s = Usm + 128*VSTR;
  _Float16* VTh  = Usm;
  _Float16* VTl  = Usm + 128*VSTR;
  _Float16* Ph   = Psm;
  _Float16* Pl   = Psm + 64*VSTR;

  const int tid = threadIdx.x;
  const int w = tid>>6, l = tid&63, lm = l&15, g = l>>4;
  const int b = blockIdx.z, h = blockIdx.y, q0 = blockIdx.x<<6;
  const float scale = 0.08838834764831845f;

  for (int i = tid; i < 64*VSTR; i += 256) ((uint32_t*)Psm)[i] = 0;
  {
    int oct = tid & 15, s0 = tid >> 4;
    for (int s = s0; s < 80; s += 16){
      h8 vh = {}, vl = {};
      if (s < S_){
        size_t ga = ((size_t)(b*S_ + s))*(2*C_) + h*HD_ + oct*8;
        vh = *(const h8*)(KVh + ga);
        vl = *(const h8*)(KVl + ga);
      }
      *(h8*)(Kh_s + s*KSTR + oct*8) = vh;
      *(h8*)(Kl_s + s*KSTR + oct*8) = vl;
    }
  }
  h8 qh[4], ql[4];
  {
    size_t qrow = (size_t)(b*T_ + q0 + w*16 + lm);
    const _Float16* qph = Qh + qrow*C_ + h*HD_ + g*8;
    const _Float16* qpl = Ql + qrow*C_ + h*HD_ + g*8;
#pragma unroll
    for (int ks=0; ks<4; ++ks){ qh[ks] = *(const h8*)(qph + ks*32); ql[ks] = *(const h8*)(qpl + ks*32); }
  }
  __syncthreads();

  f4 sc[SP5] = {};
#pragma unroll
  for (int ks=0; ks<4; ++ks){
#pragma unroll
    for (int nt=0; nt<SP5; ++nt){
      h8 kh = *(const h8*)(Kh_s + (nt*16+lm)*KSTR + ks*32 + g*8);
      h8 kl = *(const h8*)(Kl_s + (nt*16+lm)*KSTR + ks*32 + g*8);
      sc[nt] = __builtin_amdgcn_mfma_f32_16x16x32_f16(qh[ks], kh, sc[nt],0,0,0);
      sc[nt] = __builtin_amdgcn_mfma_f32_16x16x32_f16(ql[ks], kh, sc[nt],0,0,0);
      sc[nt] = __builtin_amdgcn_mfma_f32_16x16x32_f16(qh[ks], kl, sc[nt],0,0,0);
    }
  }

  float mx[4] = {-3e38f,-3e38f,-3e38f,-3e38f};
#pragma unroll
  for (int nt=0; nt<SP5; ++nt){
    bool valid = (nt*16+lm) < S_;
#pragma unroll
    for (int j=0;j<4;++j){
      float v = valid ? sc[nt][j]*scale : -3e38f;
      sc[nt][j] = v;
      mx[j] = fmaxf(mx[j], v);
    }
  }
#pragma unroll
  for (int off=1; off<16; off<<=1){
#pragma unroll
    for (int j=0;j<4;++j) mx[j] = fmaxf(mx[j], __shfl_xor(mx[j], off));
  }
  float sm[4] = {0,0,0,0};
#pragma unroll
  for (int nt=0; nt<SP5; ++nt){
    bool valid = (nt*16+lm) < S_;
#pragma unroll
    for (int j=0;j<4;++j){
      float p = valid ? expf(sc[nt][j]-mx[j]) : 0.f;
      sc[nt][j] = p; sm[j] += p;
    }
  }
#pragma unroll
  for (int off=1; off<16; off<<=1){
#pragma unroll
    for (int j=0;j<4;++j) sm[j] += __shfl_xor(sm[j], off);
  }
#pragma unroll
  for (int nt=0; nt<SP5; ++nt){
#pragma unroll
    for (int j=0;j<4;++j){
      int col = nt*16 + lm;
      if (col < S_){
        float p = sc[nt][j] / sm[j];
        int row = w*16 + g*4 + j;
        _Float16 ph = (_Float16)p;
        Ph[row*VSTR + col] = ph;
        Pl[row*VSTR + col] = (_Float16)(p - (float)ph);
      }
    }
  }
  __syncthreads();

  for (int i = tid; i < 128*VSTR; i += 256) ((uint32_t*)Usm)[i] = 0;
  __syncthreads();
  {
    int oct = tid & 15, s0 = tid >> 4;
    for (int s = s0; s < S_; s += 16){
      size_t ga = ((size_t)(b*S_ + s))*(2*C_) + C_ + h*HD_ + oct*8;
      h8 vh = *(const h8*)(KVh + ga);
      h8 vl = *(const h8*)(KVl + ga);
#pragma unroll
      for (int i2=0;i2<8;++i2){
        VTh[(oct*8+i2)*VSTR + s] = vh[i2];
        VTl[(oct*8+i2)*VSTR + s] = vl[i2];
      }
    }
  }
  __syncthreads();

  h8 pah[3], pal[3];
#pragma unroll
  for (int ks=0;ks<3;++ks){
    pah[ks] = *(const h8*)(Ph + (w*16+lm)*VSTR + ks*32 + g*8);
    pal[ks] = *(const h8*)(Pl + (w*16+lm)*VSTR + ks*32 + g*8);
  }
#pragma unroll
  for (int nt=0; nt<8; ++nt){
    f4 o = {};
#pragma unroll
    for (int ks=0;ks<3;++ks){
      h8 vh = *(const h8*)(VTh + (nt*16+lm)*VSTR + ks*32 + g*8);
      h8 vl = *(const h8*)(VTl + (nt*16+lm)*VSTR + ks*32 + g*8);
      o = __builtin_amdgcn_mfma_f32_16x16x32_f16(pah[ks], vh, o,0,0,0);
      o = __builtin_amdgcn_mfma_f32_16x16x32_f16(pal[ks], vh, o,0,0,0);
      o = __builtin_amdgcn_mfma_f32_16x16x32_f16(pah[ks], vl, o,0,0,0);
    }
#pragma unroll
    for (int j=0;j<4;++j){
      size_t orow = (size_t)(b*T_ + q0 + w*16 + g*4 + j);
      size_t oa = orow*C_ + h*HD_ + nt*16 + lm;
      _Float16 hh = (_Float16)o[j];
      AOh[oa] = hh;
      AOl[oa] = (_Float16)(o[j] - (float)hh);
    }
  }
}

// ---------------- caption gating ----------------
__global__ __launch_bounds__(256) void cap_gate(
    const float* __restrict__ CR, const float* __restrict__ gw, const float* __restrict__ gb,
    int* __restrict__ cap_sel, float* __restrict__ capP, int* __restrict__ counts)
{
  int tid = threadIdx.x, wave = tid >> 6, lane = tid & 63;
  for (int r = 0; r < 4; ++r){
    int row = (blockIdx.x << 4) + (wave << 2) + r;
    const float* xp = CR + (size_t)row * C_;
    float lg[E_];
#pragma unroll
    for (int e = 0; e < E_; ++e){
      const float* wv = gw + (size_t)e * C_;
      float p = 0.f;
      for (int c = lane; c < C_; c += 64) p += xp[c] * wv[c];
#pragma unroll
      for (int off = 32; off; off >>= 1) p += __shfl_xor(p, off);
      lg[e] = p + gb[e];
    }
    if (lane == 0){
      float z[E_], m = -3.4e38f;
      for (int e = 0; e < E_; ++e){
        float gmb = jax_gumbel(0u, 2u, (uint32_t)(row*E_ + e));
        z[e] = (lg[e] + gmb) * 0.5f;
        m = fmaxf(m, z[e]);
      }
      float y[E_], sum = 0.f;
      for (int e = 0; e < E_; ++e){ y[e] = expf(z[e] - m); sum += y[e]; }
      for (int e = 0; e < E_; ++e) y[e] = y[e] / sum;
      int best = 0; float bv = y[0];
      for (int e = 1; e < E_; ++e) if (y[e] > bv){ bv = y[e]; best = e; }
      cap_sel[row] = best;
      atomicAdd(&counts[best], 1);
      for (int e = 0; e < E_; ++e)
        capP[(size_t)row*E_ + e] = ((e == best) ? 1.0f : 0.0f) - y[e] + y[e];
    }
  }
}

// ---------------- expert grouping (dual maps: 256-tiles + 128-tiles) ----------------
__global__ void build_groups(const int* __restrict__ counts, int* __restrict__ offs,
                             int* __restrict__ cursor,
                             int* __restrict__ bmap_e, int* __restrict__ bmap_s,
                             int* __restrict__ bmap_e2, int* __restrict__ bmap_s2)
{
  offs[0] = 0;
  for (int e = 0; e < E_; ++e){ offs[e+1] = offs[e] + counts[e]; cursor[e] = offs[e]; }
  int idx = 0;
  for (int e = 0; e < E_; ++e)
    for (int s = offs[e]; s < offs[e+1]; s += 128){ bmap_e[idx] = e; bmap_s[idx] = s; ++idx; }
  for (; idx < MAXGB; ++idx) bmap_e[idx] = -1;
  int idx2 = 0;
  for (int e = 0; e < E_; ++e)
    for (int s = offs[e]; s < offs[e+1]; s += 256){ bmap_e2[idx2] = e; bmap_s2[idx2] = s; ++idx2; }
  for (; idx2 < MAXGB2; ++idx2) bmap_e2[idx2] = -1;
}

__global__ __launch_bounds__(256) void scatter_perm(
    const int* __restrict__ cap_sel, int* __restrict__ cursor, int* __restrict__ perm)
{
  int row = blockIdx.x * 256 + threadIdx.x;
  int e = cap_sel[row];
  int pos = atomicAdd(&cursor[e], 1);
  perm[pos] = row;
}

// ---------------- loss ----------------
__global__ __launch_bounds__(256) void loss_kernel(
    const float* __restrict__ capP, const float* __restrict__ langP, float* __restrict__ out_loss)
{
  __shared__ float red[4][256];
  int tid = threadIdx.x;
  float p0=0.f, p1=0.f, p2=0.f, p3=0.f;
  for (int r = tid; r < N_; r += 256){
    const float* p = capP + (size_t)r*E_;
    p0 += p[0]; p1 += p[1]; p2 += p[2]; p3 += p[3];
  }
  red[0][tid]=p0; red[1][tid]=p1; red[2][tid]=p2; red[3][tid]=p3;
  __syncthreads();
  for (int s = 128; s > 0; s >>= 1){
    if (tid < s){
      red[0][tid]+=red[0][tid+s]; red[1][tid]+=red[1][tid+s];
      red[2][tid]+=red[2][tid+s]; red[3][tid]+=red[3][tid+s];
    }
    __syncthreads();
  }
  if (tid == 0){
    float loss = 0.f;
    for (int e = 0; e < E_; ++e){
      float ul = (langP[e] + langP[E_ + e]) * 0.5f;
      loss += ul * logf(ul + 1e-10f);
    }
    for (int e = 0; e < E_; ++e){
      float uc = red[e][0] * (1.0f / N_);
      loss += uc * logf(uc + 1e-10f);
    }
    out_loss[0] = loss;
  }
}

// ---------------- host launch ----------------
extern "C" void kernel_launch(void* const* d_in, const int* in_sizes, int n_in,
                              void* d_out, int out_size, void* d_ws, size_t ws_size,
                              hipStream_t stream)
{
  const float* x          = (const float*)d_in[0];
  const float* caption    = (const float*)d_in[2];
  const int*   language   = (const int*)  d_in[3];
  const float* lang_embed = (const float*)d_in[4];
  const float* lang_gw    = (const float*)d_in[5];
  const float* lang_gb    = (const float*)d_in[6];
  const float* lang_w1    = (const float*)d_in[7];
  const float* lang_w2    = (const float*)d_in[8];
  const float* lang_w3    = (const float*)d_in[9];
  const float* in_w       = (const float*)d_in[10];
  const float* in_b       = (const float*)d_in[11];
  const float* out_w      = (const float*)d_in[12];
  const float* out_b      = (const float*)d_in[13];
  const float* cap_gw     = (const float*)d_in[14];
  const float* cap_gb     = (const float*)d_in[15];
  const float* cap_w1     = (const float*)d_in[16];
  const float* cap_w2     = (const float*)d_in[17];
  const float* cap_w3     = (const float*)d_in[18];
  float* out = (float*)d_out;

  const size_t NC = (size_t)N_*C_;
  const size_t NHe = (size_t)N_*H_;
  const size_t KVel = (size_t)B_*S_*2*C_;
  const size_t CAPel = (size_t)B_*S_*C_;

  char* base = (char*)d_ws;
  size_t cur = 0;
  auto alloc = [&](size_t bytes)->char*{
    char* p = base + cur;
    cur += (bytes + 255) & ~(size_t)255;
    return p;
  };
  float* Qcross = (float*)alloc(NC*4);
  _Float16* Qh = (_Float16*)Qcross;
  _Float16* Ql = Qh + NC;
  char* kvreg = alloc(KVel*4);
  _Float16* KVh = (_Float16*)kvreg;
  _Float16* KVl = KVh + KVel;
  float* capP   = (float*)alloc((size_t)N_*E_*4);
  float* langP  = (float*)alloc(64);
  int* lang_sel = (int*)alloc(64);
  int* cap_sel  = (int*)alloc(N_*4);
  int* counts   = (int*)alloc(64);
  int* offs     = (int*)alloc(64);
  int* cursor   = (int*)alloc(64);
  int* bmap_e   = (int*)alloc(MAXGB*4);
  int* bmap_s   = (int*)alloc(MAXGB*4);
  int* bmap_e2  = (int*)alloc(MAXGB2*4);
  int* bmap_s2  = (int*)alloc(MAXGB2*4);
  int* perm     = (int*)alloc(N_*4);
  _Float16* xAO_hi = (_Float16*)alloc(NC*2);
  _Float16* xAO_lo = (_Float16*)alloc(NC*2);
  _Float16* cap_hi = (_Float16*)alloc(CAPel*2);
  _Float16* cap_lo = (_Float16*)alloc(CAPel*2);
  _Float16* Hb_hi  = (_Float16*)alloc(NHe*2);
  _Float16* Hb_lo  = (_Float16*)alloc(NHe*2);
  _Float16* F_hi   = (_Float16*)alloc(NC*2);
  _Float16* F_lo   = (_Float16*)alloc(NC*2);
  _Float16* Wreg = (_Float16*)alloc(2*( (size_t)3*C_*C_*2 + (size_t)C_*C_*2 + 3*4*PEsz ));
  _Float16* w13hi = Wreg;
  _Float16* w13lo = Wreg + 4*PEsz;
  _Float16* w2hi  = Wreg + 8*PEsz;
  _Float16* w2lo  = Wreg + 10*PEsz;
  _Float16* inw_hi  = Wreg;
  _Float16* inw_lo  = inw_hi + (size_t)3*C_*C_;
  _Float16* outw_hi = inw_lo + (size_t)3*C_*C_;
  _Float16* outw_lo = outw_hi + (size_t)C_*C_;
  _Float16* capw13f = outw_lo + (size_t)C_*C_;
  _Float16* capw2f  = capw13f + 8*PEsz;

  // ---- phase 0 ----
  setup_lang<<<1, 256, 0, stream>>>(lang_embed, lang_gw, lang_gb, language, langP, lang_sel, counts);
  conv_w13<true><<<2048, 256, 0, stream>>>(lang_w1, lang_w3, lang_sel, 2, w13hi, w13lo);
  conv_split_sel<<<1024, 256, 0, stream>>>(lang_w2, lang_sel, 0, w2hi, w2lo, (long)(PEsz/4));
  conv_split_sel<<<1024, 256, 0, stream>>>(lang_w2, lang_sel, 1, w2hi+PEsz, w2lo+PEsz, (long)(PEsz/4));
  conv_split<<<2048, 256, 0, stream>>>(x, xAO_hi, xAO_lo, (long)(NC/4));
  conv_split<<<256, 256, 0, stream>>>(caption, cap_hi, cap_lo, (long)(CAPel/4));

  // ---- stage-1 FFN ----
  gemm_gate_split<<<dim3((2*H_)/128, N_/256), 512, 0, stream>>>(
      xAO_hi, xAO_lo, w13hi, w13lo, Hb_hi, Hb_lo);
  gemm8<1,3,1><<<dim3(C_/128, N_/128), 256, 0, stream>>>(
      Hb_hi, Hb_lo, w2hi, w2lo, nullptr, nullptr, F_hi, F_lo,
      nullptr, nullptr, nullptr, nullptr, N_, H_, C_, PEsz);

  // ---- phase-2 weight conversions ----
  conv_split<<<2048, 256, 0, stream>>>(in_w, inw_hi, inw_lo, (long)((size_t)3*C_*C_/4));
  conv_split<<<1024, 256, 0, stream>>>(out_w, outw_hi, outw_lo, (long)((size_t)C_*C_/4));
  conv_w13<false><<<2048, 256, 0, stream>>>(cap_w1, cap_w3, nullptr, 4, capw13f, nullptr);
  conv_plain<<<2048, 256, 0, stream>>>(cap_w2, capw2f, (long)(4*PEsz/4));

  // ---- projections + attention ----
  gemm8<1,3,0><<<dim3(C_/128, N_/128), 256, 0, stream>>>(
      F_hi, F_lo, inw_hi, inw_lo, in_b, nullptr, Qh, Ql,
      nullptr, nullptr, nullptr, nullptr, N_, C_, C_, 0);
  gemm8<1,3,0><<<dim3((2*C_)/128, 2), 256, 0, stream>>>(
      cap_hi, cap_lo, inw_hi + (size_t)C_*C_, inw_lo + (size_t)C_*C_, in_b + C_,
      nullptr, KVh, KVl,
      nullptr, nullptr, nullptr, nullptr, B_*S_, C_, 2*C_, 0);
  attn_mfma<<<dim3(T_/64, NH_, B_), 256, 0, stream>>>(Qh, Ql, KVh, KVl, xAO_hi, xAO_lo);
  gemm8<0,3,0><<<dim3(C_/128, N_/128), 256, 0, stream>>>(
      xAO_hi, xAO_lo, outw_hi, outw_lo, out_b, Qcross, nullptr, nullptr,
      nullptr, nullptr, nullptr, nullptr, N_, C_, C_, 0);

  // ---- caption gating + grouping ----
  cap_gate<<<N_/16, 256, 0, stream>>>(Qcross, cap_gw, cap_gb, cap_sel, capP, counts);
  build_groups<<<1, 1, 0, stream>>>(counts, offs, cursor, bmap_e, bmap_s, bmap_e2, bmap_s2);
  scatter_perm<<<N_/256, 256, 0, stream>>>(cap_sel, cursor, perm);

  // ---- stage-2 FFN ----
  _Float16* H2 = Hb_hi;
  gemm_gate_plain<<<dim3((2*H_)/128, MAXGB2), 512, 0, stream>>>(
      F_hi, capw13f, H2, bmap_e2, bmap_s2, offs, perm);
  gemm8<2,1,3><<<dim3(C_/128, MAXGB), 256, 0, stream>>>(
      H2, nullptr, capw2f, nullptr, nullptr, out, F_hi, F_lo,
      bmap_e, bmap_s, offs, perm, N_, H_, C_, PEsz);

  loss_kernel<<<1, 256, 0, stream>>>(capP, langP, out + NC);
}

// Round 7
// 690.634 us; speedup vs baseline: 3.9260x; 1.1292x over previous
//
#include <hip/hip_runtime.h>
#include <stdint.h>

// Problem constants
#define B_ 2
#define T_ 2048
#define S_ 77
#define C_ 1024
#define E_ 4
#define H_ 2816
#define NH_ 8
#define HD_ 128
#define N_ (B_*T_)            // 4096 tokens
#define MAXGB (N_/128 + E_)   // 36 row-tiles of 128 (ffn2_out)
#define MAXGB2 (N_/256 + E_)  // 20 row-tiles of 256 (ffn2_gate)
#define PEsz ((size_t)H_*C_)  // per-expert matrix elems (H*C)
#define CC_ ((size_t)C_*C_)

typedef _Float16 h8 __attribute__((ext_vector_type(8)));
typedef _Float16 h4 __attribute__((ext_vector_type(4)));
typedef float f4 __attribute__((ext_vector_type(4)));

__device__ __forceinline__ void gload16(const void* g, void* l){
  __builtin_amdgcn_global_load_lds((const __attribute__((address_space(1))) void*)g,
                                   (__attribute__((address_space(3))) void*)l, 16, 0, 0);
}

// bijective XCD swizzle (m204)
__device__ __forceinline__ void xcd_swizzle(int& bx, int& by){
  int nx = gridDim.x, ny = gridDim.y;
  int nwg = nx*ny;
  int wg = by*nx + bx;
  int q = nwg >> 3, r = nwg & 7;
  int xcd = wg & 7, idx = wg >> 3;
  int s = (xcd < r ? xcd*(q+1) : r*(q+1) + (xcd-r)*q) + idx;
  bx = s % nx; by = s / nx;
}

// ---------------- Threefry-2x32 (JAX partitionable) ----------------
__device__ __forceinline__ uint32_t rotl32(uint32_t v, int r){ return (v<<r)|(v>>(32-r)); }
__device__ __forceinline__ void threefry2x32(uint32_t k0, uint32_t k1,
                                             uint32_t x, uint32_t y,
                                             uint32_t& o0, uint32_t& o1){
  uint32_t k2 = k0 ^ k1 ^ 0x1BD11BDAu;
  x += k0; y += k1;
#define TFR(r) { x += y; y = rotl32(y, r); y ^= x; }
  TFR(13) TFR(15) TFR(26) TFR(6)   x += k1; y += k2 + 1u;
  TFR(17) TFR(29) TFR(16) TFR(24)  x += k2; y += k0 + 2u;
  TFR(13) TFR(15) TFR(26) TFR(6)   x += k0; y += k1 + 3u;
  TFR(17) TFR(29) TFR(16) TFR(24)  x += k1; y += k2 + 4u;
  TFR(13) TFR(15) TFR(26) TFR(6)   x += k2; y += k0 + 5u;
#undef TFR
  o0 = x; o1 = y;
}
__device__ __forceinline__ float gumbel_from_bits(uint32_t bits){
  const float TINY = 1.17549435e-38f;
  float f = __uint_as_float((bits >> 9) | 0x3f800000u) - 1.0f;
  float u = fmaxf(TINY, f + TINY);
  return -logf(-logf(u));
}
__device__ __forceinline__ float jax_gumbel(uint32_t k0, uint32_t k1, uint32_t idx){
  uint32_t a, b;
  threefry2x32(k0, k1, 0u, idx, a, b);
  return gumbel_from_bits(a ^ b);
}

// ---------------- conversion job helpers (grid-stride over nb blocks) ----------------
__device__ __forceinline__ void job_split(const float* __restrict__ s,
    _Float16* __restrict__ hi, _Float16* __restrict__ lo, long n4, int b0, int nb){
  for (long i = (long)b0*256 + threadIdx.x; i < n4; i += (long)nb*256){
    float4 v = ((const float4*)s)[i];
    h4 h, L;
    h[0]=(_Float16)v.x; h[1]=(_Float16)v.y; h[2]=(_Float16)v.z; h[3]=(_Float16)v.w;
    L[0]=(_Float16)(v.x-(float)h[0]); L[1]=(_Float16)(v.y-(float)h[1]);
    L[2]=(_Float16)(v.z-(float)h[2]); L[3]=(_Float16)(v.w-(float)h[3]);
    ((h4*)hi)[i] = h; ((h4*)lo)[i] = L;
  }
}
__device__ __forceinline__ void job_plain(const float* __restrict__ s,
    _Float16* __restrict__ d, long n4, int b0, int nb){
  for (long i = (long)b0*256 + threadIdx.x; i < n4; i += (long)nb*256){
    float4 v = ((const float4*)s)[i];
    h4 h;
    h[0]=(_Float16)v.x; h[1]=(_Float16)v.y; h[2]=(_Float16)v.z; h[3]=(_Float16)v.w;
    ((h4*)d)[i] = h;
  }
}
// W1/W3 -> interleaved W13 (16-row groups: [w1 16 | w3 16] per 32), plain, slots=experts
__device__ __forceinline__ void job_w13_plain(const float* __restrict__ w1,
    const float* __restrict__ w3, _Float16* __restrict__ dst, int nslot, int b0, int nb){
  const int K8 = C_/8;
  long total = (long)nslot * (2*H_) * K8;
  for (long i = (long)b0*256 + threadIdx.x; i < total; i += (long)nb*256){
    int kv = (int)(i & (K8-1));
    long rs = i >> 7;
    int r  = (int)(rs % (2*H_));
    int slot = (int)(rs / (2*H_));
    int gg = r >> 5, o = r & 31;
    const float* src = ((o<16)? w1 : w3) + (size_t)slot*PEsz + (size_t)(16*gg + (o&15))*C_ + kv*8;
    float4 v0 = *(const float4*)src, v1 = *(const float4*)(src+4);
    float vv[8] = {v0.x,v0.y,v0.z,v0.w,v1.x,v1.y,v1.z,v1.w};
    h8 hh;
#pragma unroll
    for (int jj=0;jj<8;++jj) hh[jj] = (_Float16)vv[jj];
    *(h8*)(dst + (size_t)slot*2*PEsz + (size_t)r*C_ + kv*8) = hh;
  }
}
// split variant with selected experts (2 slots)
__device__ __forceinline__ void job_w13_split_sel(const float* __restrict__ w1,
    const float* __restrict__ w3, int sel0, int sel1,
    _Float16* __restrict__ hi, _Float16* __restrict__ lo, int b0, int nb){
  const int K8 = C_/8;
  long total = 2L * (2*H_) * K8;
  for (long i = (long)b0*256 + threadIdx.x; i < total; i += (long)nb*256){
    int kv = (int)(i & (K8-1));
    long rs = i >> 7;
    int r  = (int)(rs % (2*H_));
    int slot = (int)(rs / (2*H_));
    int e = slot ? sel1 : sel0;
    int gg = r >> 5, o = r & 31;
    const float* src = ((o<16)? w1 : w3) + (size_t)e*PEsz + (size_t)(16*gg + (o&15))*C_ + kv*8;
    float4 v0 = *(const float4*)src, v1 = *(const float4*)(src+4);
    float vv[8] = {v0.x,v0.y,v0.z,v0.w,v1.x,v1.y,v1.z,v1.w};
    h8 hh, ll;
#pragma unroll
    for (int jj=0;jj<8;++jj){
      hh[jj] = (_Float16)vv[jj];
      ll[jj] = (_Float16)(vv[jj]-(float)hh[jj]);
    }
    size_t dof = (size_t)slot*2*PEsz + (size_t)r*C_ + kv*8;
    *(h8*)(hi + dof) = hh;
    *(h8*)(lo + dof) = ll;
  }
}
__device__ __forceinline__ void job_w2_split_sel(const float* __restrict__ w2,
    int sel0, int sel1, _Float16* __restrict__ hi, _Float16* __restrict__ lo, int b0, int nb){
  long per = (long)(PEsz/4);
  for (long i = (long)b0*256 + threadIdx.x; i < 2*per; i += (long)nb*256){
    int slot = (i >= per) ? 1 : 0;
    long ii = i - (long)slot*per;
    float4 v = ((const float4*)(w2 + (size_t)(slot?sel1:sel0)*PEsz))[ii];
    h4 h, L;
    h[0]=(_Float16)v.x; h[1]=(_Float16)v.y; h[2]=(_Float16)v.z; h[3]=(_Float16)v.w;
    L[0]=(_Float16)(v.x-(float)h[0]); L[1]=(_Float16)(v.y-(float)h[1]);
    L[2]=(_Float16)(v.z-(float)h[2]); L[3]=(_Float16)(v.w-(float)h[3]);
    ((h4*)(hi + (size_t)slot*PEsz))[ii] = h;
    ((h4*)(lo + (size_t)slot*PEsz))[ii] = L;
  }
}

// ---------------- convA: lang gating (inline, redundant per block) + phase-0 conversions ----------------
#define CVA_W13 1024
#define CVA_W2  512
#define CVA_X   256
#define CVA_TOT (CVA_W13+CVA_W2+CVA_X)
__global__ __launch_bounds__(256) void convA(
    const float* __restrict__ lang_embed, const float* __restrict__ gate_w,
    const float* __restrict__ gate_b, const int* __restrict__ language,
    const float* __restrict__ w1, const float* __restrict__ w3, const float* __restrict__ w2,
    const float* __restrict__ x,
    _Float16* __restrict__ w13hi, _Float16* __restrict__ w13lo,
    _Float16* __restrict__ w2hi, _Float16* __restrict__ w2lo,
    _Float16* __restrict__ xhi, _Float16* __restrict__ xlo,
    float* __restrict__ langP, int* __restrict__ counts)
{
  __shared__ float lds8[8];
  const int tid = threadIdx.x, w = tid>>6, l = tid&63;
  // 8 gate logits: wave w computes pairs 2w, 2w+1
  for (int p = 2*w; p < 2*w+2; ++p){
    int b = p>>2, e = p&3;
    const float* emb = lang_embed + (size_t)language[b]*C_;
    const float* gw  = gate_w + (size_t)e*C_;
    float acc = 0.f;
    for (int c = l; c < C_; c += 64) acc += emb[c]*gw[c];
#pragma unroll
    for (int off = 32; off; off >>= 1) acc += __shfl_xor(acc, off);
    if (l == 0) lds8[p] = acc + gate_b[e];
  }
  __syncthreads();
  // per-thread redundant gumbel-softmax argmax (identical fp ops to reference path)
  int sel[2];
  for (int b = 0; b < 2; ++b){
    float z[4], m = -3.4e38f;
    for (int e = 0; e < 4; ++e){
      float g = jax_gumbel(0u, 1u, (uint32_t)(b*4 + e));
      z[e] = (lds8[b*4 + e] + g) * 0.5f;
      m = fmaxf(m, z[e]);
    }
    float y[4], sum = 0.f;
    for (int e = 0; e < 4; ++e){ y[e] = expf(z[e]-m); sum += y[e]; }
    for (int e = 0; e < 4; ++e) y[e] = y[e] / sum;
    int best = 0; float bv = y[0];
    for (int e = 1; e < 4; ++e) if (y[e] > bv){ bv = y[e]; best = e; }
    sel[b] = best;
    if (blockIdx.x == 0 && tid == 0){
      for (int e = 0; e < 4; ++e)
        langP[b*4 + e] = ((e == best) ? 1.0f : 0.0f) - y[e] + y[e];
    }
  }
  if (blockIdx.x == 0 && tid == 0){
    for (int e = 0; e < 4; ++e) counts[e] = 0;
  }
  int bid = blockIdx.x;
  if (bid < CVA_W13)                 job_w13_split_sel(w1, w3, sel[0], sel[1], w13hi, w13lo, bid, CVA_W13);
  else if (bid < CVA_W13+CVA_W2)     job_w2_split_sel(w2, sel[0], sel[1], w2hi, w2lo, bid-CVA_W13, CVA_W2);
  else                               job_split(x, xhi, xlo, (long)((size_t)N_*C_/4), bid-CVA_W13-CVA_W2, CVA_X);
}

// ============ deep-pipelined 256x128 split gate GEMM (ffn1_gate) ============
__global__ __launch_bounds__(512,2) void gemm_gate_split(
    const _Float16* __restrict__ Ahi, const _Float16* __restrict__ Alo,
    const _Float16* __restrict__ Bhi, const _Float16* __restrict__ Blo,
    _Float16* __restrict__ Hhi, _Float16* __restrict__ Hlo)
{
  __shared__ __align__(16) char smem[147456];
  const int tid = threadIdx.x, w = tid>>6, l = tid&63;
  const int lm = l&15, g = l>>4;
  const int wm = w>>1, wn = w&1;
  int bx = blockIdx.x, by = blockIdx.y;
  xcd_swizzle(bx, by);
  const int n0 = bx<<7;
  const int m0 = by<<8;
  const size_t eoff = (m0 >= T_) ? (size_t)2*PEsz : 0;

  const _Float16* srcA[4]; const _Float16* srcB[2];
#pragma unroll
  for (int jj=0;jj<4;++jj){
    int c = jj*512 + tid, r = c>>3, s = c&7;
    int st = s ^ (r&7);
    srcA[jj] = (st<4 ? Ahi : Alo) + (size_t)(m0 + r)*C_ + ((st&3)<<3);
  }
#pragma unroll
  for (int jj=0;jj<2;++jj){
    int c = jj*512 + tid, r = c>>3, s = c&7;
    int st = s ^ (r&7);
    srcB[jj] = (st<4 ? Bhi : Blo) + eoff + (size_t)(n0 + r)*C_ + ((st&3)<<3);
  }

#define STG(ts, bi) { \
    int k0 = (ts)<<5; \
    char* db = smem + (bi)*49152; \
    _Pragma("unroll") \
    for (int jj=0;jj<4;++jj) gload16(srcA[jj]+k0, db + (jj*512 + w*64)*16); \
    _Pragma("unroll") \
    for (int jj=0;jj<2;++jj) gload16(srcB[jj]+k0, db + 32768 + (jj*512 + w*64)*16); \
  }

  const int shi = (g ^ (lm&7)) << 4;
  int aoff[4], boff[4];
#pragma unroll
  for (int i=0;i<4;++i){
    aoff[i] = ((wm*64 + i*16 + lm)<<7) + shi;
    boff[i] = 32768 + ((wn*64 + i*16 + lm)<<7) + shi;
  }

  f4 acc[4][4] = {};
  const int nt = C_/32;
  STG(0,0) STG(1,1)
  for (int t=0; t<nt; ++t){
    const int bi = t%3;
    const int ts = (t+2 < nt) ? t+2 : 0;
    STG(ts, (t+2)%3)
    asm volatile("s_waitcnt vmcnt(12)" ::: "memory");
    __builtin_amdgcn_s_barrier();
    asm volatile("" ::: "memory");
    const char* base = smem + bi*49152;
    h8 ah[4], bh[4];
#pragma unroll
    for (int i=0;i<4;++i){ ah[i] = *(const h8*)(base + aoff[i]); bh[i] = *(const h8*)(base + boff[i]); }
    __builtin_amdgcn_s_setprio(1);
#pragma unroll
    for (int mi=0;mi<4;++mi)
#pragma unroll
      for (int ni=0;ni<4;++ni)
        acc[mi][ni] = __builtin_amdgcn_mfma_f32_16x16x32_f16(ah[mi], bh[ni], acc[mi][ni],0,0,0);
    __builtin_amdgcn_s_setprio(0);
    h8 bl[4];
#pragma unroll
    for (int i=0;i<4;++i) bl[i] = *(const h8*)(base + (boff[i]^64));
    __builtin_amdgcn_s_setprio(1);
#pragma unroll
    for (int mi=0;mi<4;++mi)
#pragma unroll
      for (int ni=0;ni<4;++ni)
        acc[mi][ni] = __builtin_amdgcn_mfma_f32_16x16x32_f16(ah[mi], bl[ni], acc[mi][ni],0,0,0);
    __builtin_amdgcn_s_setprio(0);
    h8 al[4];
#pragma unroll
    for (int i=0;i<4;++i) al[i] = *(const h8*)(base + (aoff[i]^64));
    __builtin_amdgcn_s_setprio(1);
#pragma unroll
    for (int mi=0;mi<4;++mi)
#pragma unroll
      for (int ni=0;ni<4;++ni)
        acc[mi][ni] = __builtin_amdgcn_mfma_f32_16x16x32_f16(al[mi], bh[ni], acc[mi][ni],0,0,0);
    __builtin_amdgcn_s_setprio(0);
    asm volatile("" ::: "memory");
    __builtin_amdgcn_s_barrier();
  }
#undef STG

#pragma unroll
  for (int mi=0;mi<4;++mi){
#pragma unroll
    for (int p=0;p<2;++p){
      int hc = ((n0 + wn*64)>>1) + p*16 + lm;
#pragma unroll
      for (int j=0;j<4;++j){
        int rl = wm*64 + mi*16 + (g<<2) + j;
        float s1 = acc[mi][2*p][j], s3 = acc[mi][2*p+1][j];
        float hval = s1/(1.f+expf(-s1))*s3;
        size_t row = (size_t)(m0 + rl);
        _Float16 hh = (_Float16)hval;
        Hhi[row*H_ + hc] = hh;
        Hlo[row*H_ + hc] = (_Float16)(hval - (float)hh);
      }
    }
  }
}

// ============ deep-pipelined 256x128 plain gate GEMM (ffn2_gate) ============
__global__ __launch_bounds__(512,2) void gemm_gate_plain(
    const _Float16* __restrict__ A, const _Float16* __restrict__ Bw,
    _Float16* __restrict__ Hout,
    const int* __restrict__ bmap_e, const int* __restrict__ bmap_s,
    const int* __restrict__ offs, const int* __restrict__ perm)
{
  __shared__ __align__(16) char smem[147456];
  const int tid = threadIdx.x, w = tid>>6, l = tid&63;
  const int lm = l&15, g = l>>4;
  const int wm = w>>1, wn = w&1;
  int bx = blockIdx.x, by = blockIdx.y;
  xcd_swizzle(bx, by);
  const int e = bmap_e[by]; if (e<0) return;
  const int m0 = bmap_s[by];
  int v = offs[e+1]-m0; const int valid = v>256?256:v;
  const size_t eoff = (size_t)e*2*PEsz;
  const int n0 = bx<<7;

  const _Float16* srcA[4]; const _Float16* srcB[2];
#pragma unroll
  for (int jj=0;jj<4;++jj){
    int c = jj*512 + tid, r = c>>3, s = c&7;
    int st = s ^ (r&7);
    int ia = m0 + r; ia = (ia<N_) ? ia : (N_-1);
    srcA[jj] = A + (size_t)perm[ia]*C_ + (st<<3);
  }
#pragma unroll
  for (int jj=0;jj<2;++jj){
    int c = jj*512 + tid, r = c>>3, s = c&7;
    int st = s ^ (r&7);
    srcB[jj] = Bw + eoff + (size_t)(n0 + r)*C_ + (st<<3);
  }

#define STG(ts, bi) { \
    int k0 = (ts)<<6; \
    char* db = smem + (bi)*49152; \
    _Pragma("unroll") \
    for (int jj=0;jj<4;++jj) gload16(srcA[jj]+k0, db + (jj*512 + w*64)*16); \
    _Pragma("unroll") \
    for (int jj=0;jj<2;++jj) gload16(srcB[jj]+k0, db + 32768 + (jj*512 + w*64)*16); \
  }

  const int shi = (g ^ (lm&7)) << 4;
  int aoff[4], boff[4];
#pragma unroll
  for (int i=0;i<4;++i){
    aoff[i] = ((wm*64 + i*16 + lm)<<7) + shi;
    boff[i] = 32768 + ((wn*64 + i*16 + lm)<<7) + shi;
  }

  f4 acc[4][4] = {};
  const int nt = C_/64;
  STG(0,0) STG(1,1)
  for (int t=0; t<nt; ++t){
    const int bi = t%3;
    const int ts = (t+2 < nt) ? t+2 : 0;
    STG(ts, (t+2)%3)
    asm volatile("s_waitcnt vmcnt(12)" ::: "memory");
    __builtin_amdgcn_s_barrier();
    asm volatile("" ::: "memory");
    const char* base = smem + bi*49152;
#pragma unroll
    for (int kk=0;kk<2;++kk){
      h8 af[4], bf[4];
      const int x = kk<<6;
#pragma unroll
      for (int i=0;i<4;++i){ af[i] = *(const h8*)(base + (aoff[i]^x)); bf[i] = *(const h8*)(base + (boff[i]^x)); }
      __builtin_amdgcn_s_setprio(1);
#pragma unroll
      for (int mi=0;mi<4;++mi)
#pragma unroll
        for (int ni=0;ni<4;++ni)
          acc[mi][ni] = __builtin_amdgcn_mfma_f32_16x16x32_f16(af[mi], bf[ni], acc[mi][ni],0,0,0);
      __builtin_amdgcn_s_setprio(0);
    }
    asm volatile("" ::: "memory");
    __builtin_amdgcn_s_barrier();
  }
#undef STG

#pragma unroll
  for (int mi=0;mi<4;++mi){
#pragma unroll
    for (int p=0;p<2;++p){
      int hc = ((n0 + wn*64)>>1) + p*16 + lm;
#pragma unroll
      for (int j=0;j<4;++j){
        int rl = wm*64 + mi*16 + (g<<2) + j;
        if (rl >= valid) continue;
        float s1 = acc[mi][2*p][j], s3 = acc[mi][2*p+1][j];
        Hout[(size_t)(m0 + rl)*H_ + hc] = (_Float16)(s1/(1.f+expf(-s1))*s3);
      }
    }
  }
}

// ---------------- unified pipelined GEMM body (128x128) ----------------
// EPI: 0 f32+bias, 1 f16 hi/lo (+opt bias), 2 scatter-add
// EXPM: 0 none, 1 lang slot by m-block, 3 grouped rows + linear A
template<int EPI, int NSEG, int EXPM>
__device__ __forceinline__ void gemm8_body(
    char* smem,
    const _Float16* __restrict__ A0, const _Float16* __restrict__ A1,
    const _Float16* __restrict__ B0, const _Float16* __restrict__ B1,
    const float* __restrict__ bias, float* __restrict__ Cf32,
    _Float16* __restrict__ O0, _Float16* __restrict__ O1,
    const int* __restrict__ bmap_e, const int* __restrict__ bmap_s,
    const int* __restrict__ offs, const int* __restrict__ perm,
    int M, int K, int Nw, size_t bstride_e, int bx, int by)
{
  const int tid = threadIdx.x, w = tid>>6, l = tid&63;
  const int lm = l&15, g = l>>4;
  const int wm = w>>1, wn = w&1;
  const int n0 = bx<<7;
  int m0, valid = 128; size_t eoff = 0;
  if constexpr (EXPM==3){
    int e = bmap_e[by]; if (e<0) return;
    m0 = bmap_s[by];
    int v = offs[e+1]-m0; valid = v>128?128:v;
    eoff = (size_t)e*bstride_e;
  } else {
    m0 = by<<7;
    if constexpr (EXPM==1) eoff = (m0>=T_) ? bstride_e : 0;
  }
  const int cAe = (((tid&7) ^ ((tid>>3)&7)) << 3);
  size_t rbA[4], rbB[4];
#pragma unroll
  for (int j=0;j<4;++j){
    int r = (j<<5) + (tid>>3);
    int ia = m0 + r;
    if constexpr (EXPM==3){ ia = (ia < N_) ? ia : (N_-1); }
    else { if (ia > M-1) ia = M-1; }
    rbA[j] = (size_t)ia*K + cAe;
    rbB[j] = eoff + (size_t)(n0+r)*K + cAe;
  }
  const int tps = K>>6, nt = NSEG*tps;

#define STAGE8(tt, cc) { \
    int sg = 0; \
    if constexpr (NSEG==3){ sg = ((tt)>=2*tps) ? 2 : (((tt)>=tps)?1:0); } \
    const _Float16* Asrc = (sg==1) ? A1 : A0; \
    const _Float16* Bsrc = (sg==2) ? B1 : B0; \
    int kk0 = ((tt) - sg*tps)<<6; \
    char* db = smem + (cc)*32768 + w*1024; \
    _Pragma("unroll") \
    for (int j=0;j<4;++j) gload16(Asrc + rbA[j] + kk0, db + j*4096); \
    _Pragma("unroll") \
    for (int j=0;j<4;++j) gload16(Bsrc + rbB[j] + kk0, db + 16384 + j*4096); \
  }

  int aoff[2][4], boff[2][4];
#pragma unroll
  for (int kk=0;kk<2;++kk){
#pragma unroll
    for (int i=0;i<4;++i){
      int ra = wm*64 + i*16 + lm;
      aoff[kk][i] = (ra<<7) + (((kk<<6)+(g<<4)) ^ ((ra&7)<<4));
      int rb = wn*64 + i*16 + lm;
      boff[kk][i] = (rb<<7) + (((kk<<6)+(g<<4)) ^ ((rb&7)<<4));
    }
  }

  f4 acc[4][4] = {};
  STAGE8(0, 0)
  for (int t=0; t<nt; ++t){
    const int c = t&1;
    if (t+1 < nt){
      STAGE8(t+1, c^1)
      asm volatile("s_waitcnt vmcnt(8)" ::: "memory");
    } else {
      asm volatile("s_waitcnt vmcnt(0)" ::: "memory");
    }
    __builtin_amdgcn_s_barrier();
    const char* Ab = smem + c*32768;
    const char* Bb = Ab + 16384;
#pragma unroll
    for (int kk=0;kk<2;++kk){
      h8 af[4], bf[4];
#pragma unroll
      for (int i=0;i<4;++i){
        af[i] = *(const h8*)(Ab + aoff[kk][i]);
        bf[i] = *(const h8*)(Bb + boff[kk][i]);
      }
      __builtin_amdgcn_s_setprio(1);
#pragma unroll
      for (int mi=0;mi<4;++mi)
#pragma unroll
        for (int ni=0;ni<4;++ni)
          acc[mi][ni] = __builtin_amdgcn_mfma_f32_16x16x32_f16(af[mi], bf[ni], acc[mi][ni],0,0,0);
      __builtin_amdgcn_s_setprio(0);
      __builtin_amdgcn_s_barrier();
    }
  }

#pragma unroll
  for (int mi=0;mi<4;++mi){
    const int rl0 = wm*64 + mi*16 + (g<<2);
#pragma unroll
    for (int ni=0;ni<4;++ni){
      int col = n0 + wn*64 + ni*16 + lm;
#pragma unroll
      for (int j=0;j<4;++j){
        int rl = rl0 + j;
        float vv = acc[mi][ni][j];
        if constexpr (EPI==0){
          int grow = m0 + rl;
          if (grow < M) Cf32[(size_t)grow*Nw + col] = vv + bias[col];
        } else if constexpr (EPI==1){
          int grow = m0 + rl;
          if (grow < M){
            float vb = vv + (bias ? bias[col] : 0.f);
            _Float16 hh = (_Float16)vb;
            O0[(size_t)grow*Nw + col] = hh;
            O1[(size_t)grow*Nw + col] = (_Float16)(vb - (float)hh);
          }
        } else {
          if (rl < valid){
            int orig = perm[m0 + rl];
            size_t o = (size_t)orig*C_ + col;
            Cf32[o] = (float)O0[o] + (float)O1[o] + vv;
          }
        }
      }
    }
  }
#undef STAGE8
}

template<int EPI, int NSEG, int EXPM>
__global__ __launch_bounds__(256,2) void gemm8(
    const _Float16* __restrict__ A0, const _Float16* __restrict__ A1,
    const _Float16* __restrict__ B0, const _Float16* __restrict__ B1,
    const float* __restrict__ bias, float* __restrict__ Cf32,
    _Float16* __restrict__ O0, _Float16* __restrict__ O1,
    const int* __restrict__ bmap_e, const int* __restrict__ bmap_s,
    const int* __restrict__ offs, const int* __restrict__ perm,
    int M, int K, int Nw, size_t bstride_e)
{
  __shared__ __align__(16) char smem[65536];
  int bx = blockIdx.x, by = blockIdx.y;
  xcd_swizzle(bx, by);
  gemm8_body<EPI,NSEG,EXPM>(smem, A0,A1,B0,B1,bias,Cf32,O0,O1,
                            bmap_e,bmap_s,offs,perm,M,K,Nw,bstride_e,bx,by);
}

// ---------------- ffn1_out (gemm8<1,3,1>) fused with phase-2 weight conversions ----------------
__global__ __launch_bounds__(256,2) void ffn1_out_fused(
    const _Float16* __restrict__ Hbh, const _Float16* __restrict__ Hbl,
    const _Float16* __restrict__ w2hi, const _Float16* __restrict__ w2lo,
    _Float16* __restrict__ Fh, _Float16* __restrict__ Fl,
    const float* __restrict__ in_w, const float* __restrict__ out_w,
    const float* __restrict__ cap_w1, const float* __restrict__ cap_w3,
    const float* __restrict__ caption,
    _Float16* __restrict__ inwh, _Float16* __restrict__ inwl,
    _Float16* __restrict__ outwh, _Float16* __restrict__ outwl,
    _Float16* __restrict__ capw13,
    _Float16* __restrict__ caph, _Float16* __restrict__ capl)
{
  __shared__ __align__(16) char smem[65536];
  int id = blockIdx.x;
  if (id < 256){
    int s = (id&7)*32 + (id>>3);          // XCD swizzle over 256 GEMM blocks
    gemm8_body<1,3,1>(smem, Hbh, Hbl, w2hi, w2lo, nullptr, nullptr, Fh, Fl,
                      nullptr,nullptr,nullptr,nullptr, N_, H_, C_, PEsz, s&7, s>>3);
  } else {
    int cid = id - 256;                    // 512 conversion blocks
    if (cid < 320)      job_w13_plain(cap_w1, cap_w3, capw13, 4, cid, 320);
    else if (cid < 448) job_split(in_w, inwh, inwl, (long)(3*CC_/4), cid-320, 128);
    else if (cid < 496) job_split(out_w, outwh, outwl, (long)(CC_/4), cid-448, 48);
    else                job_split(caption, caph, capl, (long)((size_t)B_*S_*C_/4), cid-496, 16);
  }
}

// ---------------- Q + KV projections in one dispatch, + cap_w2 conversion ----------------
__global__ __launch_bounds__(256,2) void gemm_qkv(
    const _Float16* __restrict__ Fh, const _Float16* __restrict__ Fl,
    const _Float16* __restrict__ caph, const _Float16* __restrict__ capl,
    const _Float16* __restrict__ inwh, const _Float16* __restrict__ inwl,
    const float* __restrict__ in_b,
    _Float16* __restrict__ Qh, _Float16* __restrict__ Ql,
    _Float16* __restrict__ KVh, _Float16* __restrict__ KVl,
    const float* __restrict__ cap_w2, _Float16* __restrict__ capw2f)
{
  __shared__ __align__(16) char smem[65536];
  int id = blockIdx.x;
  if (id < 256){
    int s = (id&7)*32 + (id>>3);
    gemm8_body<1,3,0>(smem, Fh, Fl, inwh, inwl, in_b, nullptr, Qh, Ql,
                      nullptr,nullptr,nullptr,nullptr, N_, C_, C_, 0, s&7, s>>3);
  } else if (id < 288){
    int cid = id - 256;                    // KV: grid (16,2)
    gemm8_body<1,3,0>(smem, caph, capl, inwh + CC_, inwl + CC_, in_b + C_,
                      nullptr, KVh, KVl, nullptr,nullptr,nullptr,nullptr,
                      B_*S_, C_, 2*C_, 0, cid & 15, cid >> 4);
  } else {
    job_plain(cap_w2, capw2f, (long)(4*PEsz/4), id-288, 96);
  }
}

// ---------------- MFMA cross attention ----------------
#define SP5 5
#define KSTR 136
#define VSTR 104
__global__ __launch_bounds__(256) void attn_mfma(
    const _Float16* __restrict__ Qh, const _Float16* __restrict__ Ql,
    const _Float16* __restrict__ KVh, const _Float16* __restrict__ KVl,
    _Float16* __restrict__ AOh, _Float16* __restrict__ AOl)
{
  __shared__ __align__(16) _Float16 Usm[2*128*VSTR];
  __shared__ __align__(16) _Float16 Psm[2*64*VSTR];
  _Float16* Kh_s = Usm;
  _Float16* Kl_s = Usm + 128*VSTR;
  _Float16* VTh  = Usm;
  _Float16* VTl  = Usm + 128*VSTR;
  _Float16* Ph   = Psm;
  _Float16* Pl   = Psm + 64*VSTR;

  const int tid = threadIdx.x;
  const int w = tid>>6, l = tid&63, lm = l&15, g = l>>4;
  const int b = blockIdx.z, h = blockIdx.y, q0 = blockIdx.x<<6;
  const float scale = 0.08838834764831845f;

  for (int i = tid; i < 64*VSTR; i += 256) ((uint32_t*)Psm)[i] = 0;
  {
    int oct = tid & 15, s0 = tid >> 4;
    for (int s = s0; s < 80; s += 16){
      h8 vh = {}, vl = {};
      if (s < S_){
        size_t ga = ((size_t)(b*S_ + s))*(2*C_) + h*HD_ + oct*8;
        vh = *(const h8*)(KVh + ga);
        vl = *(const h8*)(KVl + ga);
      }
      *(h8*)(Kh_s + s*KSTR + oct*8) = vh;
      *(h8*)(Kl_s + s*KSTR + oct*8) = vl;
    }
  }
  h8 qh[4], ql[4];
  {
    size_t qrow = (size_t)(b*T_ + q0 + w*16 + lm);
    const _Float16* qph = Qh + qrow*C_ + h*HD_ + g*8;
    const _Float16* qpl = Ql + qrow*C_ + h*HD_ + g*8;
#pragma unroll
    for (int ks=0; ks<4; ++ks){ qh[ks] = *(const h8*)(qph + ks*32); ql[ks] = *(const h8*)(qpl + ks*32); }
  }
  __syncthreads();

  f4 sc[SP5] = {};
#pragma unroll
  for (int ks=0; ks<4; ++ks){
#pragma unroll
    for (int nt=0; nt<SP5; ++nt){
      h8 kh = *(const h8*)(Kh_s + (nt*16+lm)*KSTR + ks*32 + g*8);
      h8 kl = *(const h8*)(Kl_s + (nt*16+lm)*KSTR + ks*32 + g*8);
      sc[nt] = __builtin_amdgcn_mfma_f32_16x16x32_f16(qh[ks], kh, sc[nt],0,0,0);
      sc[nt] = __builtin_amdgcn_mfma_f32_16x16x32_f16(ql[ks], kh, sc[nt],0,0,0);
      sc[nt] = __builtin_amdgcn_mfma_f32_16x16x32_f16(qh[ks], kl, sc[nt],0,0,0);
    }
  }

  float mx[4] = {-3e38f,-3e38f,-3e38f,-3e38f};
#pragma unroll
  for (int nt=0; nt<SP5; ++nt){
    bool valid = (nt*16+lm) < S_;
#pragma unroll
    for (int j=0;j<4;++j){
      float v = valid ? sc[nt][j]*scale : -3e38f;
      sc[nt][j] = v;
      mx[j] = fmaxf(mx[j], v);
    }
  }
#pragma unroll
  for (int off=1; off<16; off<<=1){
#pragma unroll
    for (int j=0;j<4;++j) mx[j] = fmaxf(mx[j], __shfl_xor(mx[j], off));
  }
  float sm[4] = {0,0,0,0};
#pragma unroll
  for (int nt=0; nt<SP5; ++nt){
    bool valid = (nt*16+lm) < S_;
#pragma unroll
    for (int j=0;j<4;++j){
      float p = valid ? expf(sc[nt][j]-mx[j]) : 0.f;
      sc[nt][j] = p; sm[j] += p;
    }
  }
#pragma unroll
  for (int off=1; off<16; off<<=1){
#pragma unroll
    for (int j=0;j<4;++j) sm[j] += __shfl_xor(sm[j], off);
  }
#pragma unroll
  for (int nt=0; nt<SP5; ++nt){
#pragma unroll
    for (int j=0;j<4;++j){
      int col = nt*16 + lm;
      if (col < S_){
        float p = sc[nt][j] / sm[j];
        int row = w*16 + g*4 + j;
        _Float16 ph = (_Float16)p;
        Ph[row*VSTR + col] = ph;
        Pl[row*VSTR + col] = (_Float16)(p - (float)ph);
      }
    }
  }
  __syncthreads();

  for (int i = tid; i < 128*VSTR; i += 256) ((uint32_t*)Usm)[i] = 0;
  __syncthreads();
  {
    int oct = tid & 15, s0 = tid >> 4;
    for (int s = s0; s < S_; s += 16){
      size_t ga = ((size_t)(b*S_ + s))*(2*C_) + C_ + h*HD_ + oct*8;
      h8 vh = *(const h8*)(KVh + ga);
      h8 vl = *(const h8*)(KVl + ga);
#pragma unroll
      for (int i2=0;i2<8;++i2){
        VTh[(oct*8+i2)*VSTR + s] = vh[i2];
        VTl[(oct*8+i2)*VSTR + s] = vl[i2];
      }
    }
  }
  __syncthreads();

  h8 pah[3], pal[3];
#pragma unroll
  for (int ks=0;ks<3;++ks){
    pah[ks] = *(const h8*)(Ph + (w*16+lm)*VSTR + ks*32 + g*8);
    pal[ks] = *(const h8*)(Pl + (w*16+lm)*VSTR + ks*32 + g*8);
  }
#pragma unroll
  for (int nt=0; nt<8; ++nt){
    f4 o = {};
#pragma unroll
    for (int ks=0;ks<3;++ks){
      h8 vh = *(const h8*)(VTh + (nt*16+lm)*VSTR + ks*32 + g*8);
      h8 vl = *(const h8*)(VTl + (nt*16+lm)*VSTR + ks*32 + g*8);
      o = __builtin_amdgcn_mfma_f32_16x16x32_f16(pah[ks], vh, o,0,0,0);
      o = __builtin_amdgcn_mfma_f32_16x16x32_f16(pal[ks], vh, o,0,0,0);
      o = __builtin_amdgcn_mfma_f32_16x16x32_f16(pah[ks], vl, o,0,0,0);
    }
#pragma unroll
    for (int j=0;j<4;++j){
      size_t orow = (size_t)(b*T_ + q0 + w*16 + g*4 + j);
      size_t oa = orow*C_ + h*HD_ + nt*16 + lm;
      _Float16 hh = (_Float16)o[j];
      AOh[oa] = hh;
      AOl[oa] = (_Float16)(o[j] - (float)hh);
    }
  }
}

// ---------------- caption gating (512 blocks, 8 rows each) ----------------
__global__ __launch_bounds__(256) void cap_gate(
    const float* __restrict__ CR, const float* __restrict__ gw, const float* __restrict__ gb,
    int* __restrict__ cap_sel, float* __restrict__ capP, int* __restrict__ counts)
{
  int tid = threadIdx.x, wave = tid >> 6, lane = tid & 63;
  for (int r = 0; r < 2; ++r){
    int row = (blockIdx.x << 3) + (wave << 1) + r;
    const float* xp = CR + (size_t)row * C_;
    float lg[E_];
#pragma unroll
    for (int e = 0; e < E_; ++e){
      const float* wv = gw + (size_t)e * C_;
      float p = 0.f;
      for (int c = lane; c < C_; c += 64) p += xp[c] * wv[c];
#pragma unroll
      for (int off = 32; off; off >>= 1) p += __shfl_xor(p, off);
      lg[e] = p + gb[e];
    }
    if (lane == 0){
      float z[E_], m = -3.4e38f;
      for (int e = 0; e < E_; ++e){
        float gmb = jax_gumbel(0u, 2u, (uint32_t)(row*E_ + e));
        z[e] = (lg[e] + gmb) * 0.5f;
        m = fmaxf(m, z[e]);
      }
      float y[E_], sum = 0.f;
      for (int e = 0; e < E_; ++e){ y[e] = expf(z[e] - m); sum += y[e]; }
      for (int e = 0; e < E_; ++e) y[e] = y[e] / sum;
      int best = 0; float bv = y[0];
      for (int e = 1; e < E_; ++e) if (y[e] > bv){ bv = y[e]; best = e; }
      cap_sel[row] = best;
      atomicAdd(&counts[best], 1);
      for (int e = 0; e < E_; ++e)
        capP[(size_t)row*E_ + e] = ((e == best) ? 1.0f : 0.0f) - y[e] + y[e];
    }
  }
}

// ---------------- finalize: groups + perm scatter (block 0) + loss (block 1) ----------------
__global__ __launch_bounds__(256) void finalize(
    const int* __restrict__ counts, const int* __restrict__ cap_sel,
    int* __restrict__ offs,
    int* __restrict__ bmap_e, int* __restrict__ bmap_s,
    int* __restrict__ bmap_e2, int* __restrict__ bmap_s2,
    int* __restrict__ perm,
    const float* __restrict__ capP, const float* __restrict__ langP,
    float* __restrict__ out_loss)
{
  __shared__ int loffs[5];
  __shared__ int lcur[4];
  __shared__ float red[4][256];
  int tid = threadIdx.x;
  if (blockIdx.x == 0){
    if (tid == 0){
      loffs[0] = 0;
      for (int e = 0; e < E_; ++e){ loffs[e+1] = loffs[e] + counts[e]; lcur[e] = loffs[e]; }
      for (int e = 0; e < E_+1; ++e) offs[e] = loffs[e];
      int idx = 0;
      for (int e = 0; e < E_; ++e)
        for (int s = loffs[e]; s < loffs[e+1]; s += 128){ bmap_e[idx] = e; bmap_s[idx] = s; ++idx; }
      for (; idx < MAXGB; ++idx) bmap_e[idx] = -1;
      int idx2 = 0;
      for (int e = 0; e < E_; ++e)
        for (int s = loffs[e]; s < loffs[e+1]; s += 256){ bmap_e2[idx2] = e; bmap_s2[idx2] = s; ++idx2; }
      for (; idx2 < MAXGB2; ++idx2) bmap_e2[idx2] = -1;
    }
    __syncthreads();
    for (int row = tid; row < N_; row += 256){
      int e = cap_sel[row];
      int pos = atomicAdd(&lcur[e], 1);
      perm[pos] = row;
    }
  } else {
    float p0=0.f, p1=0.f, p2=0.f, p3=0.f;
    for (int r = tid; r < N_; r += 256){
      const float* p = capP + (size_t)r*E_;
      p0 += p[0]; p1 += p[1]; p2 += p[2]; p3 += p[3];
    }
    red[0][tid]=p0; red[1][tid]=p1; red[2][tid]=p2; red[3][tid]=p3;
    __syncthreads();
    for (int s = 128; s > 0; s >>= 1){
      if (tid < s){
        red[0][tid]+=red[0][tid+s]; red[1][tid]+=red[1][tid+s];
        red[2][tid]+=red[2][tid+s]; red[3][tid]+=red[3][tid+s];
      }
      __syncthreads();
    }
    if (tid == 0){
      float loss = 0.f;
      for (int e = 0; e < E_; ++e){
        float ul = (langP[e] + langP[E_ + e]) * 0.5f;
        loss += ul * logf(ul + 1e-10f);
      }
      for (int e = 0; e < E_; ++e){
        float uc = red[e][0] * (1.0f / N_);
        loss += uc * logf(uc + 1e-10f);
      }
      out_loss[0] = loss;
    }
  }
}

// ---------------- host launch ----------------
extern "C" void kernel_launch(void* const* d_in, const int* in_sizes, int n_in,
                              void* d_out, int out_size, void* d_ws, size_t ws_size,
                              hipStream_t stream)
{
  const float* x          = (const float*)d_in[0];
  const float* caption    = (const float*)d_in[2];
  const int*   language   = (const int*)  d_in[3];
  const float* lang_embed = (const float*)d_in[4];
  const float* lang_gw    = (const float*)d_in[5];
  const float* lang_gb    = (const float*)d_in[6];
  const float* lang_w1    = (const float*)d_in[7];
  const float* lang_w2    = (const float*)d_in[8];
  const float* lang_w3    = (const float*)d_in[9];
  const float* in_w       = (const float*)d_in[10];
  const float* in_b       = (const float*)d_in[11];
  const float* out_w      = (const float*)d_in[12];
  const float* out_b      = (const float*)d_in[13];
  const float* cap_gw     = (const float*)d_in[14];
  const float* cap_gb     = (const float*)d_in[15];
  const float* cap_w1     = (const float*)d_in[16];
  const float* cap_w2     = (const float*)d_in[17];
  const float* cap_w3     = (const float*)d_in[18];
  float* out = (float*)d_out;

  const size_t NC = (size_t)N_*C_;
  const size_t NHe = (size_t)N_*H_;
  const size_t KVel = (size_t)B_*S_*2*C_;
  const size_t CAPel = (size_t)B_*S_*C_;

  char* base = (char*)d_ws;
  size_t cur = 0;
  auto alloc = [&](size_t bytes)->char*{
    char* p = base + cur;
    cur += (bytes + 255) & ~(size_t)255;
    return p;
  };
  float* Qcross = (float*)alloc(NC*4);            // Qh/Ql f16, then cross f32
  _Float16* Qh = (_Float16*)Qcross;
  _Float16* Ql = Qh + NC;
  char* kvreg = alloc(KVel*4);
  _Float16* KVh = (_Float16*)kvreg;
  _Float16* KVl = KVh + KVel;
  float* capP   = (float*)alloc((size_t)N_*E_*4);
  float* langP  = (float*)alloc(64);
  int* lang_sel = (int*)alloc(64);
  int* cap_sel  = (int*)alloc(N_*4);
  int* counts   = (int*)alloc(64);
  int* offs     = (int*)alloc(64);
  int* cursor   = (int*)alloc(64);
  int* bmap_e   = (int*)alloc(MAXGB*4);
  int* bmap_s   = (int*)alloc(MAXGB*4);
  int* bmap_e2  = (int*)alloc(MAXGB2*4);
  int* bmap_s2  = (int*)alloc(MAXGB2*4);
  int* perm     = (int*)alloc(N_*4);
  _Float16* xAO_hi = (_Float16*)alloc(NC*2);      // x_hi, then AO_hi
  _Float16* xAO_lo = (_Float16*)alloc(NC*2);
  _Float16* cap_hi = (_Float16*)alloc(CAPel*2);
  _Float16* cap_lo = (_Float16*)alloc(CAPel*2);
  _Float16* Hb_hi  = (_Float16*)alloc(NHe*2);     // stage-1 hidden hi, then H2
  _Float16* Hb_lo  = (_Float16*)alloc(NHe*2);
  _Float16* F_hi   = (_Float16*)alloc(NC*2);
  _Float16* F_lo   = (_Float16*)alloc(NC*2);
  _Float16* Wreg = (_Float16*)alloc(2*( (size_t)3*CC_*2 + CC_*2 + 3*4*PEsz ));
  // phase-1 (lang): w13 split [0,8PEsz), w2 split [8PEsz,12PEsz)
  _Float16* w13hi = Wreg;
  _Float16* w13lo = Wreg + 4*PEsz;
  _Float16* w2hi  = Wreg + 8*PEsz;
  _Float16* w2lo  = Wreg + 10*PEsz;
  // phase-2 layout chosen for lifetime safety under fusion:
  //  capw13f [0,8PEsz)      — written in ffn1_out_fused (w13 dead by then)
  //  capw2f  [8PEsz,12PEsz) — written in gemm_qkv (w2 dead by then)
  //  inw/outw [12PEsz, ...) — Wreg tail, never overlaps live data
  _Float16* capw13f = Wreg;
  _Float16* capw2f  = Wreg + 8*PEsz;
  _Float16* inw_hi  = Wreg + 12*PEsz;
  _Float16* inw_lo  = inw_hi + 3*CC_;
  _Float16* outw_hi = inw_lo + 3*CC_;
  _Float16* outw_lo = outw_hi + CC_;
  (void)lang_sel; (void)cursor;

  // 1) phase-0 conversions (+ inline language gating, langP, counts=0)
  convA<<<CVA_TOT, 256, 0, stream>>>(
      lang_embed, lang_gw, lang_gb, language,
      lang_w1, lang_w3, lang_w2, x,
      w13hi, w13lo, w2hi, w2lo, xAO_hi, xAO_lo, langP, counts);

  // 2) ffn1 gate
  gemm_gate_split<<<dim3((2*H_)/128, N_/256), 512, 0, stream>>>(
      xAO_hi, xAO_lo, w13hi, w13lo, Hb_hi, Hb_lo);

  // 3) ffn1 out + phase-2 conversions (co-resident)
  ffn1_out_fused<<<768, 256, 0, stream>>>(
      Hb_hi, Hb_lo, w2hi, w2lo, F_hi, F_lo,
      in_w, out_w, cap_w1, cap_w3, caption,
      inw_hi, inw_lo, outw_hi, outw_lo, capw13f, cap_hi, cap_lo);

  // 4) Q + KV projections + cap_w2 conversion
  gemm_qkv<<<384, 256, 0, stream>>>(
      F_hi, F_lo, cap_hi, cap_lo, inw_hi, inw_lo, in_b,
      Qh, Ql, KVh, KVl, cap_w2, capw2f);

  // 5) attention
  attn_mfma<<<dim3(T_/64, NH_, B_), 256, 0, stream>>>(Qh, Ql, KVh, KVl, xAO_hi, xAO_lo);

  // 6) out projection -> cross (f32)
  gemm8<0,3,0><<<dim3(C_/128, N_/128), 256, 0, stream>>>(
      xAO_hi, xAO_lo, outw_hi, outw_lo, out_b, Qcross, nullptr, nullptr,
      nullptr, nullptr, nullptr, nullptr, N_, C_, C_, 0);

  // 7) caption gating
  cap_gate<<<N_/8, 256, 0, stream>>>(Qcross, cap_gw, cap_gb, cap_sel, capP, counts);

  // 8) groups + perm + loss
  finalize<<<2, 256, 0, stream>>>(counts, cap_sel, offs, bmap_e, bmap_s,
                                  bmap_e2, bmap_s2, perm, capP, langP, out + NC);

  // 9) ffn2 gate
  _Float16* H2 = Hb_hi;
  gemm_gate_plain<<<dim3((2*H_)/128, MAXGB2), 512, 0, stream>>>(
      F_hi, capw13f, H2, bmap_e2, bmap_s2, offs, perm);

  // 10) ffn2 out + final sum scatter
  gemm8<2,1,3><<<dim3(C_/128, MAXGB), 256, 0, stream>>>(
      H2, nullptr, capw2f, nullptr, nullptr, out, F_hi, F_lo,
      bmap_e, bmap_s, offs, perm, N_, H_, C_, PEsz);
}

// Round 8
// 660.106 us; speedup vs baseline: 4.1076x; 1.0462x over previous
//
#include <hip/hip_runtime.h>
#include <stdint.h>

// Problem constants
#define B_ 2
#define T_ 2048
#define S_ 77
#define C_ 1024
#define E_ 4
#define H_ 2816
#define NH_ 8
#define HD_ 128
#define N_ (B_*T_)            // 4096 tokens
#define MAXGB (N_/128 + E_)   // 36 row-tiles of 128 (ffn2_out)
#define MAXGB2 (N_/256 + E_)  // 20 row-tiles of 256 (ffn2_gate)
#define PEsz ((size_t)H_*C_)  // per-expert matrix elems (H*C)
#define CC_ ((size_t)C_*C_)

typedef _Float16 h8 __attribute__((ext_vector_type(8)));
typedef _Float16 h4 __attribute__((ext_vector_type(4)));
typedef float f4 __attribute__((ext_vector_type(4)));

__device__ __forceinline__ void gload16(const void* g, void* l){
  __builtin_amdgcn_global_load_lds((const __attribute__((address_space(1))) void*)g,
                                   (__attribute__((address_space(3))) void*)l, 16, 0, 0);
}

// bijective XCD chunking, COLUMN-major decode: each XCD owns a contiguous bx-range
// (weight panel slice per XCD fits L2; activations re-read from L3). [T1 variant]
__device__ __forceinline__ void xcd_swizzle_cm(int& bx, int& by){
  int nx = gridDim.x, ny = gridDim.y;
  int nwg = nx*ny;
  int wg = by*nx + bx;                 // hardware dispatch index
  int q = nwg >> 3, r = nwg & 7;
  int xcd = wg & 7, idx = wg >> 3;
  int s = (xcd < r ? xcd*(q+1) : r*(q+1) + (xcd-r)*q) + idx;
  bx = s / ny; by = s % ny;            // column-major: consecutive s = same bx
}

// ---------------- Threefry-2x32 (JAX partitionable) ----------------
__device__ __forceinline__ uint32_t rotl32(uint32_t v, int r){ return (v<<r)|(v>>(32-r)); }
__device__ __forceinline__ void threefry2x32(uint32_t k0, uint32_t k1,
                                             uint32_t x, uint32_t y,
                                             uint32_t& o0, uint32_t& o1){
  uint32_t k2 = k0 ^ k1 ^ 0x1BD11BDAu;
  x += k0; y += k1;
#define TFR(r) { x += y; y = rotl32(y, r); y ^= x; }
  TFR(13) TFR(15) TFR(26) TFR(6)   x += k1; y += k2 + 1u;
  TFR(17) TFR(29) TFR(16) TFR(24)  x += k2; y += k0 + 2u;
  TFR(13) TFR(15) TFR(26) TFR(6)   x += k0; y += k1 + 3u;
  TFR(17) TFR(29) TFR(16) TFR(24)  x += k1; y += k2 + 4u;
  TFR(13) TFR(15) TFR(26) TFR(6)   x += k2; y += k0 + 5u;
#undef TFR
  o0 = x; o1 = y;
}
__device__ __forceinline__ float gumbel_from_bits(uint32_t bits){
  const float TINY = 1.17549435e-38f;
  float f = __uint_as_float((bits >> 9) | 0x3f800000u) - 1.0f;
  float u = fmaxf(TINY, f + TINY);
  return -logf(-logf(u));
}
__device__ __forceinline__ float jax_gumbel(uint32_t k0, uint32_t k1, uint32_t idx){
  uint32_t a, b;
  threefry2x32(k0, k1, 0u, idx, a, b);
  return gumbel_from_bits(a ^ b);
}

// ---------------- conversion job helpers (grid-stride over nb blocks) ----------------
__device__ __forceinline__ void job_split(const float* __restrict__ s,
    _Float16* __restrict__ hi, _Float16* __restrict__ lo, long n4, int b0, int nb){
  for (long i = (long)b0*256 + threadIdx.x; i < n4; i += (long)nb*256){
    float4 v = ((const float4*)s)[i];
    h4 h, L;
    h[0]=(_Float16)v.x; h[1]=(_Float16)v.y; h[2]=(_Float16)v.z; h[3]=(_Float16)v.w;
    L[0]=(_Float16)(v.x-(float)h[0]); L[1]=(_Float16)(v.y-(float)h[1]);
    L[2]=(_Float16)(v.z-(float)h[2]); L[3]=(_Float16)(v.w-(float)h[3]);
    ((h4*)hi)[i] = h; ((h4*)lo)[i] = L;
  }
}
__device__ __forceinline__ void job_plain(const float* __restrict__ s,
    _Float16* __restrict__ d, long n4, int b0, int nb){
  for (long i = (long)b0*256 + threadIdx.x; i < n4; i += (long)nb*256){
    float4 v = ((const float4*)s)[i];
    h4 h;
    h[0]=(_Float16)v.x; h[1]=(_Float16)v.y; h[2]=(_Float16)v.z; h[3]=(_Float16)v.w;
    ((h4*)d)[i] = h;
  }
}
// W1/W3 -> interleaved W13 (16-row groups: [w1 16 | w3 16] per 32), plain, slots=experts
__device__ __forceinline__ void job_w13_plain(const float* __restrict__ w1,
    const float* __restrict__ w3, _Float16* __restrict__ dst, int nslot, int b0, int nb){
  const int K8 = C_/8;
  long total = (long)nslot * (2*H_) * K8;
  for (long i = (long)b0*256 + threadIdx.x; i < total; i += (long)nb*256){
    int kv = (int)(i & (K8-1));
    long rs = i >> 7;
    int r  = (int)(rs % (2*H_));
    int slot = (int)(rs / (2*H_));
    int gg = r >> 5, o = r & 31;
    const float* src = ((o<16)? w1 : w3) + (size_t)slot*PEsz + (size_t)(16*gg + (o&15))*C_ + kv*8;
    float4 v0 = *(const float4*)src, v1 = *(const float4*)(src+4);
    float vv[8] = {v0.x,v0.y,v0.z,v0.w,v1.x,v1.y,v1.z,v1.w};
    h8 hh;
#pragma unroll
    for (int jj=0;jj<8;++jj) hh[jj] = (_Float16)vv[jj];
    *(h8*)(dst + (size_t)slot*2*PEsz + (size_t)r*C_ + kv*8) = hh;
  }
}
// split variant with selected experts (2 slots)
__device__ __forceinline__ void job_w13_split_sel(const float* __restrict__ w1,
    const float* __restrict__ w3, int sel0, int sel1,
    _Float16* __restrict__ hi, _Float16* __restrict__ lo, int b0, int nb){
  const int K8 = C_/8;
  long total = 2L * (2*H_) * K8;
  for (long i = (long)b0*256 + threadIdx.x; i < total; i += (long)nb*256){
    int kv = (int)(i & (K8-1));
    long rs = i >> 7;
    int r  = (int)(rs % (2*H_));
    int slot = (int)(rs / (2*H_));
    int e = slot ? sel1 : sel0;
    int gg = r >> 5, o = r & 31;
    const float* src = ((o<16)? w1 : w3) + (size_t)e*PEsz + (size_t)(16*gg + (o&15))*C_ + kv*8;
    float4 v0 = *(const float4*)src, v1 = *(const float4*)(src+4);
    float vv[8] = {v0.x,v0.y,v0.z,v0.w,v1.x,v1.y,v1.z,v1.w};
    h8 hh, ll;
#pragma unroll
    for (int jj=0;jj<8;++jj){
      hh[jj] = (_Float16)vv[jj];
      ll[jj] = (_Float16)(vv[jj]-(float)hh[jj]);
    }
    size_t dof = (size_t)slot*2*PEsz + (size_t)r*C_ + kv*8;
    *(h8*)(hi + dof) = hh;
    *(h8*)(lo + dof) = ll;
  }
}
__device__ __forceinline__ void job_w2_split_sel(const float* __restrict__ w2,
    int sel0, int sel1, _Float16* __restrict__ hi, _Float16* __restrict__ lo, int b0, int nb){
  long per = (long)(PEsz/4);
  for (long i = (long)b0*256 + threadIdx.x; i < 2*per; i += (long)nb*256){
    int slot = (i >= per) ? 1 : 0;
    long ii = i - (long)slot*per;
    float4 v = ((const float4*)(w2 + (size_t)(slot?sel1:sel0)*PEsz))[ii];
    h4 h, L;
    h[0]=(_Float16)v.x; h[1]=(_Float16)v.y; h[2]=(_Float16)v.z; h[3]=(_Float16)v.w;
    L[0]=(_Float16)(v.x-(float)h[0]); L[1]=(_Float16)(v.y-(float)h[1]);
    L[2]=(_Float16)(v.z-(float)h[2]); L[3]=(_Float16)(v.w-(float)h[3]);
    ((h4*)(hi + (size_t)slot*PEsz))[ii] = h;
    ((h4*)(lo + (size_t)slot*PEsz))[ii] = L;
  }
}
// fold_w: Wp[e][k] = sum_c capgw[e][c]*outw[c][k]; bp[e] = sum_c outb[c]*capgw[e][c]
__device__ __forceinline__ void job_foldw(const float* __restrict__ outw,
    const float* __restrict__ capgw, const float* __restrict__ outb,
    float* __restrict__ Wp, float* __restrict__ bp, int b0){
  int e = b0 >> 2;
  int k = ((b0 & 3) << 8) + threadIdx.x;
  const float* cg = capgw + e*C_;
  float acc = 0.f;
  for (int c = 0; c < C_; ++c) acc += cg[c] * outw[(size_t)c*C_ + k];
  Wp[e*C_ + k] = acc;
  if ((b0 & 3) == 0){
    // bp[e'] for e' = wave index (4 waves); lane-strided reduce
    int wv = threadIdx.x >> 6, l = threadIdx.x & 63;
    const float* cg2 = capgw + wv*C_;
    float a2 = 0.f;
    for (int c = l; c < C_; c += 64) a2 += outb[c] * cg2[c];
#pragma unroll
    for (int off = 32; off; off >>= 1) a2 += __shfl_xor(a2, off);
    if (l == 0 && e == 0) bp[wv] = a2;
  }
}

// ---------------- convA: lang gating (inline, redundant per block) + phase-0 conversions ----------------
#define CVA_W13 1024
#define CVA_W2  512
#define CVA_X   256
#define CVA_TOT (CVA_W13+CVA_W2+CVA_X)
__global__ __launch_bounds__(256) void convA(
    const float* __restrict__ lang_embed, const float* __restrict__ gate_w,
    const float* __restrict__ gate_b, const int* __restrict__ language,
    const float* __restrict__ w1, const float* __restrict__ w3, const float* __restrict__ w2,
    const float* __restrict__ x,
    _Float16* __restrict__ w13hi, _Float16* __restrict__ w13lo,
    _Float16* __restrict__ w2hi, _Float16* __restrict__ w2lo,
    _Float16* __restrict__ xhi, _Float16* __restrict__ xlo,
    float* __restrict__ langP, int* __restrict__ counts)
{
  __shared__ float lds8[8];
  const int tid = threadIdx.x, w = tid>>6, l = tid&63;
  for (int p = 2*w; p < 2*w+2; ++p){
    int b = p>>2, e = p&3;
    const float* emb = lang_embed + (size_t)language[b]*C_;
    const float* gw  = gate_w + (size_t)e*C_;
    float acc = 0.f;
    for (int c = l; c < C_; c += 64) acc += emb[c]*gw[c];
#pragma unroll
    for (int off = 32; off; off >>= 1) acc += __shfl_xor(acc, off);
    if (l == 0) lds8[p] = acc + gate_b[e];
  }
  __syncthreads();
  int sel[2];
  for (int b = 0; b < 2; ++b){
    float z[4], m = -3.4e38f;
    for (int e = 0; e < 4; ++e){
      float g = jax_gumbel(0u, 1u, (uint32_t)(b*4 + e));
      z[e] = (lds8[b*4 + e] + g) * 0.5f;
      m = fmaxf(m, z[e]);
    }
    float y[4], sum = 0.f;
    for (int e = 0; e < 4; ++e){ y[e] = expf(z[e]-m); sum += y[e]; }
    for (int e = 0; e < 4; ++e) y[e] = y[e] / sum;
    int best = 0; float bv = y[0];
    for (int e = 1; e < 4; ++e) if (y[e] > bv){ bv = y[e]; best = e; }
    sel[b] = best;
    if (blockIdx.x == 0 && tid == 0){
      for (int e = 0; e < 4; ++e)
        langP[b*4 + e] = ((e == best) ? 1.0f : 0.0f) - y[e] + y[e];
    }
  }
  if (blockIdx.x == 0 && tid == 0){
    for (int e = 0; e < 4; ++e) counts[e] = 0;
  }
  int bid = blockIdx.x;
  if (bid < CVA_W13)                 job_w13_split_sel(w1, w3, sel[0], sel[1], w13hi, w13lo, bid, CVA_W13);
  else if (bid < CVA_W13+CVA_W2)     job_w2_split_sel(w2, sel[0], sel[1], w2hi, w2lo, bid-CVA_W13, CVA_W2);
  else                               job_split(x, xhi, xlo, (long)((size_t)N_*C_/4), bid-CVA_W13-CVA_W2, CVA_X);
}

// ============ deep-pipelined 256x128 split gate GEMM (ffn1_gate) ============
__global__ __launch_bounds__(512,2) void gemm_gate_split(
    const _Float16* __restrict__ Ahi, const _Float16* __restrict__ Alo,
    const _Float16* __restrict__ Bhi, const _Float16* __restrict__ Blo,
    _Float16* __restrict__ Hhi, _Float16* __restrict__ Hlo)
{
  __shared__ __align__(16) char smem[147456];
  const int tid = threadIdx.x, w = tid>>6, l = tid&63;
  const int lm = l&15, g = l>>4;
  const int wm = w>>1, wn = w&1;
  int bx = blockIdx.x, by = blockIdx.y;
  xcd_swizzle_cm(bx, by);
  const int n0 = bx<<7;
  const int m0 = by<<8;
  const size_t eoff = (m0 >= T_) ? (size_t)2*PEsz : 0;

  const _Float16* srcA[4]; const _Float16* srcB[2];
#pragma unroll
  for (int jj=0;jj<4;++jj){
    int c = jj*512 + tid, r = c>>3, s = c&7;
    int st = s ^ (r&7);
    srcA[jj] = (st<4 ? Ahi : Alo) + (size_t)(m0 + r)*C_ + ((st&3)<<3);
  }
#pragma unroll
  for (int jj=0;jj<2;++jj){
    int c = jj*512 + tid, r = c>>3, s = c&7;
    int st = s ^ (r&7);
    srcB[jj] = (st<4 ? Bhi : Blo) + eoff + (size_t)(n0 + r)*C_ + ((st&3)<<3);
  }

#define STG(ts, bi) { \
    int k0 = (ts)<<5; \
    char* db = smem + (bi)*49152; \
    _Pragma("unroll") \
    for (int jj=0;jj<4;++jj) gload16(srcA[jj]+k0, db + (jj*512 + w*64)*16); \
    _Pragma("unroll") \
    for (int jj=0;jj<2;++jj) gload16(srcB[jj]+k0, db + 32768 + (jj*512 + w*64)*16); \
  }

  const int shi = (g ^ (lm&7)) << 4;
  int aoff[4], boff[4];
#pragma unroll
  for (int i=0;i<4;++i){
    aoff[i] = ((wm*64 + i*16 + lm)<<7) + shi;
    boff[i] = 32768 + ((wn*64 + i*16 + lm)<<7) + shi;
  }

  f4 acc[4][4] = {};
  const int nt = C_/32;
  STG(0,0) STG(1,1)
  for (int t=0; t<nt; ++t){
    const int bi = t%3;
    const int ts = (t+2 < nt) ? t+2 : 0;
    STG(ts, (t+2)%3)
    asm volatile("s_waitcnt vmcnt(12)" ::: "memory");
    __builtin_amdgcn_s_barrier();
    asm volatile("" ::: "memory");
    const char* base = smem + bi*49152;
    h8 ah[4], bh[4];
#pragma unroll
    for (int i=0;i<4;++i){ ah[i] = *(const h8*)(base + aoff[i]); bh[i] = *(const h8*)(base + boff[i]); }
    __builtin_amdgcn_s_setprio(1);
#pragma unroll
    for (int mi=0;mi<4;++mi)
#pragma unroll
      for (int ni=0;ni<4;++ni)
        acc[mi][ni] = __builtin_amdgcn_mfma_f32_16x16x32_f16(ah[mi], bh[ni], acc[mi][ni],0,0,0);
    __builtin_amdgcn_s_setprio(0);
    h8 bl[4];
#pragma unroll
    for (int i=0;i<4;++i) bl[i] = *(const h8*)(base + (boff[i]^64));
    __builtin_amdgcn_s_setprio(1);
#pragma unroll
    for (int mi=0;mi<4;++mi)
#pragma unroll
      for (int ni=0;ni<4;++ni)
        acc[mi][ni] = __builtin_amdgcn_mfma_f32_16x16x32_f16(ah[mi], bl[ni], acc[mi][ni],0,0,0);
    __builtin_amdgcn_s_setprio(0);
    h8 al[4];
#pragma unroll
    for (int i=0;i<4;++i) al[i] = *(const h8*)(base + (aoff[i]^64));
    __builtin_amdgcn_s_setprio(1);
#pragma unroll
    for (int mi=0;mi<4;++mi)
#pragma unroll
      for (int ni=0;ni<4;++ni)
        acc[mi][ni] = __builtin_amdgcn_mfma_f32_16x16x32_f16(al[mi], bh[ni], acc[mi][ni],0,0,0);
    __builtin_amdgcn_s_setprio(0);
    asm volatile("" ::: "memory");
    __builtin_amdgcn_s_barrier();
  }
#undef STG

#pragma unroll
  for (int mi=0;mi<4;++mi){
#pragma unroll
    for (int p=0;p<2;++p){
      int hc = ((n0 + wn*64)>>1) + p*16 + lm;
#pragma unroll
      for (int j=0;j<4;++j){
        int rl = wm*64 + mi*16 + (g<<2) + j;
        float s1 = acc[mi][2*p][j], s3 = acc[mi][2*p+1][j];
        float hval = s1/(1.f+expf(-s1))*s3;
        size_t row = (size_t)(m0 + rl);
        _Float16 hh = (_Float16)hval;
        Hhi[row*H_ + hc] = hh;
        Hlo[row*H_ + hc] = (_Float16)(hval - (float)hh);
      }
    }
  }
}

// ============ deep-pipelined 256x128 plain gate GEMM (ffn2_gate) ============
__global__ __launch_bounds__(512,2) void gemm_gate_plain(
    const _Float16* __restrict__ A, const _Float16* __restrict__ Bw,
    _Float16* __restrict__ Hout,
    const int* __restrict__ bmap_e, const int* __restrict__ bmap_s,
    const int* __restrict__ offs, const int* __restrict__ perm)
{
  __shared__ __align__(16) char smem[147456];
  const int tid = threadIdx.x, w = tid>>6, l = tid&63;
  const int lm = l&15, g = l>>4;
  const int wm = w>>1, wn = w&1;
  int bx = blockIdx.x, by = blockIdx.y;
  xcd_swizzle_cm(bx, by);
  const int e = bmap_e[by]; if (e<0) return;
  const int m0 = bmap_s[by];
  int v = offs[e+1]-m0; const int valid = v>256?256:v;
  const size_t eoff = (size_t)e*2*PEsz;
  const int n0 = bx<<7;

  const _Float16* srcA[4]; const _Float16* srcB[2];
#pragma unroll
  for (int jj=0;jj<4;++jj){
    int c = jj*512 + tid, r = c>>3, s = c&7;
    int st = s ^ (r&7);
    int ia = m0 + r; ia = (ia<N_) ? ia : (N_-1);
    srcA[jj] = A + (size_t)perm[ia]*C_ + (st<<3);
  }
#pragma unroll
  for (int jj=0;jj<2;++jj){
    int c = jj*512 + tid, r = c>>3, s = c&7;
    int st = s ^ (r&7);
    srcB[jj] = Bw + eoff + (size_t)(n0 + r)*C_ + (st<<3);
  }

#define STG(ts, bi) { \
    int k0 = (ts)<<6; \
    char* db = smem + (bi)*49152; \
    _Pragma("unroll") \
    for (int jj=0;jj<4;++jj) gload16(srcA[jj]+k0, db + (jj*512 + w*64)*16); \
    _Pragma("unroll") \
    for (int jj=0;jj<2;++jj) gload16(srcB[jj]+k0, db + 32768 + (jj*512 + w*64)*16); \
  }

  const int shi = (g ^ (lm&7)) << 4;
  int aoff[4], boff[4];
#pragma unroll
  for (int i=0;i<4;++i){
    aoff[i] = ((wm*64 + i*16 + lm)<<7) + shi;
    boff[i] = 32768 + ((wn*64 + i*16 + lm)<<7) + shi;
  }

  f4 acc[4][4] = {};
  const int nt = C_/64;
  STG(0,0) STG(1,1)
  for (int t=0; t<nt; ++t){
    const int bi = t%3;
    const int ts = (t+2 < nt) ? t+2 : 0;
    STG(ts, (t+2)%3)
    asm volatile("s_waitcnt vmcnt(12)" ::: "memory");
    __builtin_amdgcn_s_barrier();
    asm volatile("" ::: "memory");
    const char* base = smem + bi*49152;
#pragma unroll
    for (int kk=0;kk<2;++kk){
      h8 af[4], bf[4];
      const int x = kk<<6;
#pragma unroll
      for (int i=0;i<4;++i){ af[i] = *(const h8*)(base + (aoff[i]^x)); bf[i] = *(const h8*)(base + (boff[i]^x)); }
      __builtin_amdgcn_s_setprio(1);
#pragma unroll
      for (int mi=0;mi<4;++mi)
#pragma unroll
        for (int ni=0;ni<4;++ni)
          acc[mi][ni] = __builtin_amdgcn_mfma_f32_16x16x32_f16(af[mi], bf[ni], acc[mi][ni],0,0,0);
      __builtin_amdgcn_s_setprio(0);
    }
    asm volatile("" ::: "memory");
    __builtin_amdgcn_s_barrier();
  }
#undef STG

#pragma unroll
  for (int mi=0;mi<4;++mi){
#pragma unroll
    for (int p=0;p<2;++p){
      int hc = ((n0 + wn*64)>>1) + p*16 + lm;
#pragma unroll
      for (int j=0;j<4;++j){
        int rl = wm*64 + mi*16 + (g<<2) + j;
        if (rl >= valid) continue;
        float s1 = acc[mi][2*p][j], s3 = acc[mi][2*p+1][j];
        Hout[(size_t)(m0 + rl)*H_ + hc] = (_Float16)(s1/(1.f+expf(-s1))*s3);
      }
    }
  }
}

// ---------------- unified pipelined GEMM body (128x128) ----------------
// EPI: 1 f16 hi/lo (+opt bias), 2 scatter-add
// EXPM: 0 none, 1 lang slot by m-block, 3 grouped rows + linear A
template<int EPI, int NSEG, int EXPM>
__device__ __forceinline__ void gemm8_body(
    char* smem,
    const _Float16* __restrict__ A0, const _Float16* __restrict__ A1,
    const _Float16* __restrict__ B0, const _Float16* __restrict__ B1,
    const float* __restrict__ bias, float* __restrict__ Cf32,
    _Float16* __restrict__ O0, _Float16* __restrict__ O1,
    const int* __restrict__ bmap_e, const int* __restrict__ bmap_s,
    const int* __restrict__ offs, const int* __restrict__ perm,
    int M, int K, int Nw, size_t bstride_e, int bx, int by)
{
  const int tid = threadIdx.x, w = tid>>6, l = tid&63;
  const int lm = l&15, g = l>>4;
  const int wm = w>>1, wn = w&1;
  const int n0 = bx<<7;
  int m0, valid = 128; size_t eoff = 0;
  if constexpr (EXPM==3){
    int e = bmap_e[by]; if (e<0) return;
    m0 = bmap_s[by];
    int v = offs[e+1]-m0; valid = v>128?128:v;
    eoff = (size_t)e*bstride_e;
  } else {
    m0 = by<<7;
    if constexpr (EXPM==1) eoff = (m0>=T_) ? bstride_e : 0;
  }
  const int cAe = (((tid&7) ^ ((tid>>3)&7)) << 3);
  size_t rbA[4], rbB[4];
#pragma unroll
  for (int j=0;j<4;++j){
    int r = (j<<5) + (tid>>3);
    int ia = m0 + r;
    if constexpr (EXPM==3){ ia = (ia < N_) ? ia : (N_-1); }
    else { if (ia > M-1) ia = M-1; }
    rbA[j] = (size_t)ia*K + cAe;
    rbB[j] = eoff + (size_t)(n0+r)*K + cAe;
  }
  const int tps = K>>6, nt = NSEG*tps;

#define STAGE8(tt, cc) { \
    int sg = 0; \
    if constexpr (NSEG==3){ sg = ((tt)>=2*tps) ? 2 : (((tt)>=tps)?1:0); } \
    const _Float16* Asrc = (sg==1) ? A1 : A0; \
    const _Float16* Bsrc = (sg==2) ? B1 : B0; \
    int kk0 = ((tt) - sg*tps)<<6; \
    char* db = smem + (cc)*32768 + w*1024; \
    _Pragma("unroll") \
    for (int j=0;j<4;++j) gload16(Asrc + rbA[j] + kk0, db + j*4096); \
    _Pragma("unroll") \
    for (int j=0;j<4;++j) gload16(Bsrc + rbB[j] + kk0, db + 16384 + j*4096); \
  }

  int aoff[2][4], boff[2][4];
#pragma unroll
  for (int kk=0;kk<2;++kk){
#pragma unroll
    for (int i=0;i<4;++i){
      int ra = wm*64 + i*16 + lm;
      aoff[kk][i] = (ra<<7) + (((kk<<6)+(g<<4)) ^ ((ra&7)<<4));
      int rb = wn*64 + i*16 + lm;
      boff[kk][i] = (rb<<7) + (((kk<<6)+(g<<4)) ^ ((rb&7)<<4));
    }
  }

  f4 acc[4][4] = {};
  STAGE8(0, 0)
  for (int t=0; t<nt; ++t){
    const int c = t&1;
    if (t+1 < nt){
      STAGE8(t+1, c^1)
      asm volatile("s_waitcnt vmcnt(8)" ::: "memory");
    } else {
      asm volatile("s_waitcnt vmcnt(0)" ::: "memory");
    }
    __builtin_amdgcn_s_barrier();
    const char* Ab = smem + c*32768;
    const char* Bb = Ab + 16384;
#pragma unroll
    for (int kk=0;kk<2;++kk){
      h8 af[4], bf[4];
#pragma unroll
      for (int i=0;i<4;++i){
        af[i] = *(const h8*)(Ab + aoff[kk][i]);
        bf[i] = *(const h8*)(Bb + boff[kk][i]);
      }
      __builtin_amdgcn_s_setprio(1);
#pragma unroll
      for (int mi=0;mi<4;++mi)
#pragma unroll
        for (int ni=0;ni<4;++ni)
          acc[mi][ni] = __builtin_amdgcn_mfma_f32_16x16x32_f16(af[mi], bf[ni], acc[mi][ni],0,0,0);
      __builtin_amdgcn_s_setprio(0);
      __builtin_amdgcn_s_barrier();
    }
  }

#pragma unroll
  for (int mi=0;mi<4;++mi){
    const int rl0 = wm*64 + mi*16 + (g<<2);
#pragma unroll
    for (int ni=0;ni<4;++ni){
      int col = n0 + wn*64 + ni*16 + lm;
#pragma unroll
      for (int j=0;j<4;++j){
        int rl = rl0 + j;
        float vv = acc[mi][ni][j];
        if constexpr (EPI==1){
          int grow = m0 + rl;
          if (grow < M){
            float vb = vv + (bias ? bias[col] : 0.f);
            _Float16 hh = (_Float16)vb;
            O0[(size_t)grow*Nw + col] = hh;
            O1[(size_t)grow*Nw + col] = (_Float16)(vb - (float)hh);
          }
        } else {
          if (rl < valid){
            int orig = perm[m0 + rl];
            size_t o = (size_t)orig*C_ + col;
            Cf32[o] = (float)O0[o] + (float)O1[o] + vv;
          }
        }
      }
    }
  }
#undef STAGE8
}

template<int EPI, int NSEG, int EXPM>
__global__ __launch_bounds__(256,2) void gemm8(
    const _Float16* __restrict__ A0, const _Float16* __restrict__ A1,
    const _Float16* __restrict__ B0, const _Float16* __restrict__ B1,
    const float* __restrict__ bias, float* __restrict__ Cf32,
    _Float16* __restrict__ O0, _Float16* __restrict__ O1,
    const int* __restrict__ bmap_e, const int* __restrict__ bmap_s,
    const int* __restrict__ offs, const int* __restrict__ perm,
    int M, int K, int Nw, size_t bstride_e)
{
  __shared__ __align__(16) char smem[65536];
  int bx = blockIdx.x, by = blockIdx.y;
  xcd_swizzle_cm(bx, by);
  gemm8_body<EPI,NSEG,EXPM>(smem, A0,A1,B0,B1,bias,Cf32,O0,O1,
                            bmap_e,bmap_s,offs,perm,M,K,Nw,bstride_e,bx,by);
}

// ---------------- ffn1_out (gemm8<1,3,1>) fused with phase-2 weight conversions ----------------
__global__ __launch_bounds__(256,2) void ffn1_out_fused(
    const _Float16* __restrict__ Hbh, const _Float16* __restrict__ Hbl,
    const _Float16* __restrict__ w2hi, const _Float16* __restrict__ w2lo,
    _Float16* __restrict__ Fh, _Float16* __restrict__ Fl,
    const float* __restrict__ in_w,
    const float* __restrict__ cap_w1, const float* __restrict__ cap_w3,
    const float* __restrict__ caption,
    _Float16* __restrict__ inwh, _Float16* __restrict__ inwl,
    _Float16* __restrict__ capw13,
    _Float16* __restrict__ caph, _Float16* __restrict__ capl)
{
  __shared__ __align__(16) char smem[65536];
  int id = blockIdx.x;
  if (id < 256){
    // column-per-XCD: bx = id%8 (each XCD owns one w2 column slice, L2-resident)
    gemm8_body<1,3,1>(smem, Hbh, Hbl, w2hi, w2lo, nullptr, nullptr, Fh, Fl,
                      nullptr,nullptr,nullptr,nullptr, N_, H_, C_, PEsz, id&7, id>>3);
  } else {
    int cid = id - 256;                    // 512 conversion blocks
    if (cid < 352)      job_w13_plain(cap_w1, cap_w3, capw13, 4, cid, 352);
    else if (cid < 496) job_split(in_w, inwh, inwl, (long)(3*CC_/4), cid-352, 144);
    else                job_split(caption, caph, capl, (long)((size_t)B_*S_*C_/4), cid-496, 16);
  }
}

// ---------------- Q + KV projections + fold_w in one dispatch ----------------
__global__ __launch_bounds__(256,2) void gemm_qkv(
    const _Float16* __restrict__ Fh, const _Float16* __restrict__ Fl,
    const _Float16* __restrict__ caph, const _Float16* __restrict__ capl,
    const _Float16* __restrict__ inwh, const _Float16* __restrict__ inwl,
    const float* __restrict__ in_b,
    _Float16* __restrict__ Qh, _Float16* __restrict__ Ql,
    _Float16* __restrict__ KVh, _Float16* __restrict__ KVl,
    const float* __restrict__ out_w, const float* __restrict__ cap_gw,
    const float* __restrict__ out_b, float* __restrict__ Wp, float* __restrict__ bp)
{
  __shared__ __align__(16) char smem[65536];
  int id = blockIdx.x;
  if (id < 256){
    gemm8_body<1,3,0>(smem, Fh, Fl, inwh, inwl, in_b, nullptr, Qh, Ql,
                      nullptr,nullptr,nullptr,nullptr, N_, C_, C_, 0, id&7, id>>3);
  } else if (id < 288){
    int cid = id - 256;                    // KV: grid (16,2)
    gemm8_body<1,3,0>(smem, caph, capl, inwh + CC_, inwl + CC_, in_b + C_,
                      nullptr, KVh, KVl, nullptr,nullptr,nullptr,nullptr,
                      B_*S_, C_, 2*C_, 0, cid & 15, cid >> 4);
  } else {
    job_foldw(out_w, cap_gw, out_b, Wp, bp, id-288);   // 16 blocks
  }
}

// ---------------- MFMA cross attention (flattened grid) + capw2 conversion ----------------
#define SP5 5
#define KSTR 136
#define VSTR 104
__global__ __launch_bounds__(256) void attn_fused(
    const _Float16* __restrict__ Qh, const _Float16* __restrict__ Ql,
    const _Float16* __restrict__ KVh, const _Float16* __restrict__ KVl,
    _Float16* __restrict__ AOh, _Float16* __restrict__ AOl,
    const float* __restrict__ cap_w2, _Float16* __restrict__ capw2f)
{
  __shared__ __align__(16) _Float16 Usm[2*128*VSTR];
  __shared__ __align__(16) _Float16 Psm[2*64*VSTR];
  int id = blockIdx.x;
  if (id >= 512){ job_plain(cap_w2, capw2f, (long)(4*PEsz/4), id-512, 128); return; }
  _Float16* Kh_s = Usm;
  _Float16* Kl_s = Usm + 128*VSTR;
  _Float16* VTh  = Usm;
  _Float16* VTl  = Usm + 128*VSTR;
  _Float16* Ph   = Psm;
  _Float16* Pl   = Psm + 64*VSTR;

  const int tid = threadIdx.x;
  const int w = tid>>6, l = tid&63, lm = l&15, g = l>>4;
  const int b = id >> 8, h = (id >> 5) & 7, q0 = (id & 31) << 6;
  const float scale = 0.08838834764831845f;

  for (int i = tid; i < 64*VSTR; i += 256) ((uint32_t*)Psm)[i] = 0;
  {
    int oct = tid & 15, s0 = tid >> 4;
    for (int s = s0; s < 80; s += 16){
      h8 vh = {}, vl = {};
      if (s < S_){
        size_t ga = ((size_t)(b*S_ + s))*(2*C_) + h*HD_ + oct*8;
        vh = *(const h8*)(KVh + ga);
        vl = *(const h8*)(KVl + ga);
      }
      *(h8*)(Kh_s + s*KSTR + oct*8) = vh;
      *(h8*)(Kl_s + s*KSTR + oct*8) = vl;
    }
  }
  h8 qh[4], ql[4];
  {
    size_t qrow = (size_t)(b*T_ + q0 + w*16 + lm);
    const _Float16* qph = Qh + qrow*C_ + h*HD_ + g*8;
    const _Float16* qpl = Ql + qrow*C_ + h*HD_ + g*8;
#pragma unroll
    for (int ks=0; ks<4; ++ks){ qh[ks] = *(const h8*)(qph + ks*32); ql[ks] = *(const h8*)(qpl + ks*32); }
  }
  __syncthreads();

  f4 sc[SP5] = {};
#pragma unroll
  for (int ks=0; ks<4; ++ks){
#pragma unroll
    for (int nt=0; nt<SP5; ++nt){
      h8 kh = *(const h8*)(Kh_s + (nt*16+lm)*KSTR + ks*32 + g*8);
      h8 kl = *(const h8*)(Kl_s + (nt*16+lm)*KSTR + ks*32 + g*8);
      sc[nt] = __builtin_amdgcn_mfma_f32_16x16x32_f16(qh[ks], kh, sc[nt],0,0,0);
      sc[nt] = __builtin_amdgcn_mfma_f32_16x16x32_f16(ql[ks], kh, sc[nt],0,0,0);
      sc[nt] = __builtin_amdgcn_mfma_f32_16x16x32_f16(qh[ks], kl, sc[nt],0,0,0);
    }
  }

  float mx[4] = {-3e38f,-3e38f,-3e38f,-3e38f};
#pragma unroll
  for (int nt=0; nt<SP5; ++nt){
    bool valid = (nt*16+lm) < S_;
#pragma unroll
    for (int j=0;j<4;++j){
      float v = valid ? sc[nt][j]*scale : -3e38f;
      sc[nt][j] = v;
      mx[j] = fmaxf(mx[j], v);
    }
  }
#pragma unroll
  for (int off=1; off<16; off<<=1){
#pragma unroll
    for (int j=0;j<4;++j) mx[j] = fmaxf(mx[j], __shfl_xor(mx[j], off));
  }
  float sm[4] = {0,0,0,0};
#pragma unroll
  for (int nt=0; nt<SP5; ++nt){
    bool valid = (nt*16+lm) < S_;
#pragma unroll
    for (int j=0;j<4;++j){
      float p = valid ? expf(sc[nt][j]-mx[j]) : 0.f;
      sc[nt][j] = p; sm[j] += p;
    }
  }
#pragma unroll
  for (int off=1; off<16; off<<=1){
#pragma unroll
    for (int j=0;j<4;++j) sm[j] += __shfl_xor(sm[j], off);
  }
#pragma unroll
  for (int nt=0; nt<SP5; ++nt){
#pragma unroll
    for (int j=0;j<4;++j){
      int col = nt*16 + lm;
      if (col < S_){
        float p = sc[nt][j] / sm[j];
        int row = w*16 + g*4 + j;
        _Float16 ph = (_Float16)p;
        Ph[row*VSTR + col] = ph;
        Pl[row*VSTR + col] = (_Float16)(p - (float)ph);
      }
    }
  }
  __syncthreads();

  for (int i = tid; i < 128*VSTR; i += 256) ((uint32_t*)Usm)[i] = 0;
  __syncthreads();
  {
    int oct = tid & 15, s0 = tid >> 4;
    for (int s = s0; s < S_; s += 16){
      size_t ga = ((size_t)(b*S_ + s))*(2*C_) + C_ + h*HD_ + oct*8;
      h8 vh = *(const h8*)(KVh + ga);
      h8 vl = *(const h8*)(KVl + ga);
#pragma unroll
      for (int i2=0;i2<8;++i2){
        VTh[(oct*8+i2)*VSTR + s] = vh[i2];
        VTl[(oct*8+i2)*VSTR + s] = vl[i2];
      }
    }
  }
  __syncthreads();

  h8 pah[3], pal[3];
#pragma unroll
  for (int ks=0;ks<3;++ks){
    pah[ks] = *(const h8*)(Ph + (w*16+lm)*VSTR + ks*32 + g*8);
    pal[ks] = *(const h8*)(Pl + (w*16+lm)*VSTR + ks*32 + g*8);
  }
#pragma unroll
  for (int nt=0; nt<8; ++nt){
    f4 o = {};
#pragma unroll
    for (int ks=0;ks<3;++ks){
      h8 vh = *(const h8*)(VTh + (nt*16+lm)*VSTR + ks*32 + g*8);
      h8 vl = *(const h8*)(VTl + (nt*16+lm)*VSTR + ks*32 + g*8);
      o = __builtin_amdgcn_mfma_f32_16x16x32_f16(pah[ks], vh, o,0,0,0);
      o = __builtin_amdgcn_mfma_f32_16x16x32_f16(pal[ks], vh, o,0,0,0);
      o = __builtin_amdgcn_mfma_f32_16x16x32_f16(pah[ks], vl, o,0,0,0);
    }
#pragma unroll
    for (int j=0;j<4;++j){
      size_t orow = (size_t)(b*T_ + q0 + w*16 + g*4 + j);
      size_t oa = orow*C_ + h*HD_ + nt*16 + lm;
      _Float16 hh = (_Float16)o[j];
      AOh[oa] = hh;
      AOl[oa] = (_Float16)(o[j] - (float)hh);
    }
  }
}

// ---------------- caption gating from AO (hi/lo) via folded W' ----------------
__global__ __launch_bounds__(256) void cap_gate(
    const _Float16* __restrict__ AOh, const _Float16* __restrict__ AOl,
    const float* __restrict__ Wp, const float* __restrict__ bp,
    const float* __restrict__ gb,
    int* __restrict__ cap_sel, float* __restrict__ capP, int* __restrict__ counts)
{
  int tid = threadIdx.x, wave = tid >> 6, lane = tid & 63;
  for (int r = 0; r < 2; ++r){
    int row = (blockIdx.x << 3) + (wave << 1) + r;
    // load AO row once: lane-strided 16 elements
    float av[16];
#pragma unroll
    for (int i = 0; i < 16; ++i){
      int c = lane + (i << 6);
      av[i] = (float)AOh[(size_t)row*C_ + c] + (float)AOl[(size_t)row*C_ + c];
    }
    float lg[E_];
#pragma unroll
    for (int e = 0; e < E_; ++e){
      const float* wv = Wp + (size_t)e * C_;
      float p = 0.f;
#pragma unroll
      for (int i = 0; i < 16; ++i) p += av[i] * wv[lane + (i << 6)];
#pragma unroll
      for (int off = 32; off; off >>= 1) p += __shfl_xor(p, off);
      lg[e] = p + bp[e] + gb[e];
    }
    if (lane == 0){
      float z[E_], m = -3.4e38f;
      for (int e = 0; e < E_; ++e){
        float gmb = jax_gumbel(0u, 2u, (uint32_t)(row*E_ + e));
        z[e] = (lg[e] + gmb) * 0.5f;
        m = fmaxf(m, z[e]);
      }
      float y[E_], sum = 0.f;
      for (int e = 0; e < E_; ++e){ y[e] = expf(z[e] - m); sum += y[e]; }
      for (int e = 0; e < E_; ++e) y[e] = y[e] / sum;
      int best = 0; float bv = y[0];
      for (int e = 1; e < E_; ++e) if (y[e] > bv){ bv = y[e]; best = e; }
      cap_sel[row] = best;
      atomicAdd(&counts[best], 1);
      for (int e = 0; e < E_; ++e)
        capP[(size_t)row*E_ + e] = ((e == best) ? 1.0f : 0.0f) - y[e] + y[e];
    }
  }
}

// ---------------- finalize: groups + perm scatter (block 0) + loss (block 1) ----------------
__global__ __launch_bounds__(256) void finalize(
    const int* __restrict__ counts, const int* __restrict__ cap_sel,
    int* __restrict__ offs,
    int* __restrict__ bmap_e, int* __restrict__ bmap_s,
    int* __restrict__ bmap_e2, int* __restrict__ bmap_s2,
    int* __restrict__ perm,
    const float* __restrict__ capP, const float* __restrict__ langP,
    float* __restrict__ out_loss)
{
  __shared__ int loffs[5];
  __shared__ int lcur[4];
  __shared__ float red[4][256];
  int tid = threadIdx.x;
  if (blockIdx.x == 0){
    if (tid == 0){
      loffs[0] = 0;
      for (int e = 0; e < E_; ++e){ loffs[e+1] = loffs[e] + counts[e]; lcur[e] = loffs[e]; }
      for (int e = 0; e < E_+1; ++e) offs[e] = loffs[e];
      int idx = 0;
      for (int e = 0; e < E_; ++e)
        for (int s = loffs[e]; s < loffs[e+1]; s += 128){ bmap_e[idx] = e; bmap_s[idx] = s; ++idx; }
      for (; idx < MAXGB; ++idx) bmap_e[idx] = -1;
      int idx2 = 0;
      for (int e = 0; e < E_; ++e)
        for (int s = loffs[e]; s < loffs[e+1]; s += 256){ bmap_e2[idx2] = e; bmap_s2[idx2] = s; ++idx2; }
      for (; idx2 < MAXGB2; ++idx2) bmap_e2[idx2] = -1;
    }
    __syncthreads();
    for (int row = tid; row < N_; row += 256){
      int e = cap_sel[row];
      int pos = atomicAdd(&lcur[e], 1);
      perm[pos] = row;
    }
  } else {
    float p0=0.f, p1=0.f, p2=0.f, p3=0.f;
    for (int r = tid; r < N_; r += 256){
      const float* p = capP + (size_t)r*E_;
      p0 += p[0]; p1 += p[1]; p2 += p[2]; p3 += p[3];
    }
    red[0][tid]=p0; red[1][tid]=p1; red[2][tid]=p2; red[3][tid]=p3;
    __syncthreads();
    for (int s = 128; s > 0; s >>= 1){
      if (tid < s){
        red[0][tid]+=red[0][tid+s]; red[1][tid]+=red[1][tid+s];
        red[2][tid]+=red[2][tid+s]; red[3][tid]+=red[3][tid+s];
      }
      __syncthreads();
    }
    if (tid == 0){
      float loss = 0.f;
      for (int e = 0; e < E_; ++e){
        float ul = (langP[e] + langP[E_ + e]) * 0.5f;
        loss += ul * logf(ul + 1e-10f);
      }
      for (int e = 0; e < E_; ++e){
        float uc = red[e][0] * (1.0f / N_);
        loss += uc * logf(uc + 1e-10f);
      }
      out_loss[0] = loss;
    }
  }
}

// ---------------- host launch ----------------
extern "C" void kernel_launch(void* const* d_in, const int* in_sizes, int n_in,
                              void* d_out, int out_size, void* d_ws, size_t ws_size,
                              hipStream_t stream)
{
  const float* x          = (const float*)d_in[0];
  const float* caption    = (const float*)d_in[2];
  const int*   language   = (const int*)  d_in[3];
  const float* lang_embed = (const float*)d_in[4];
  const float* lang_gw    = (const float*)d_in[5];
  const float* lang_gb    = (const float*)d_in[6];
  const float* lang_w1    = (const float*)d_in[7];
  const float* lang_w2    = (const float*)d_in[8];
  const float* lang_w3    = (const float*)d_in[9];
  const float* in_w       = (const float*)d_in[10];
  const float* in_b       = (const float*)d_in[11];
  const float* out_w      = (const float*)d_in[12];
  const float* out_b      = (const float*)d_in[13];
  const float* cap_gw     = (const float*)d_in[14];
  const float* cap_gb     = (const float*)d_in[15];
  const float* cap_w1     = (const float*)d_in[16];
  const float* cap_w2     = (const float*)d_in[17];
  const float* cap_w3     = (const float*)d_in[18];
  float* out = (float*)d_out;

  const size_t NC = (size_t)N_*C_;
  const size_t NHe = (size_t)N_*H_;
  const size_t KVel = (size_t)B_*S_*2*C_;
  const size_t CAPel = (size_t)B_*S_*C_;

  char* base = (char*)d_ws;
  size_t cur = 0;
  auto alloc = [&](size_t bytes)->char*{
    char* p = base + cur;
    cur += (bytes + 255) & ~(size_t)255;
    return p;
  };
  _Float16* Qh = (_Float16*)alloc(NC*2);
  _Float16* Ql = (_Float16*)alloc(NC*2);
  char* kvreg = alloc(KVel*4);
  _Float16* KVh = (_Float16*)kvreg;
  _Float16* KVl = KVh + KVel;
  float* capP   = (float*)alloc((size_t)N_*E_*4);
  float* langP  = (float*)alloc(64);
  float* Wp     = (float*)alloc(E_*C_*4);
  float* bp     = (float*)alloc(64);
  int* cap_sel  = (int*)alloc(N_*4);
  int* counts   = (int*)alloc(64);
  int* offs     = (int*)alloc(64);
  int* bmap_e   = (int*)alloc(MAXGB*4);
  int* bmap_s   = (int*)alloc(MAXGB*4);
  int* bmap_e2  = (int*)alloc(MAXGB2*4);
  int* bmap_s2  = (int*)alloc(MAXGB2*4);
  int* perm     = (int*)alloc(N_*4);
  _Float16* xAO_hi = (_Float16*)alloc(NC*2);      // x_hi, then AO_hi
  _Float16* xAO_lo = (_Float16*)alloc(NC*2);
  _Float16* cap_hi = (_Float16*)alloc(CAPel*2);
  _Float16* cap_lo = (_Float16*)alloc(CAPel*2);
  _Float16* Hb_hi  = (_Float16*)alloc(NHe*2);     // stage-1 hidden hi, then H2
  _Float16* Hb_lo  = (_Float16*)alloc(NHe*2);
  _Float16* F_hi   = (_Float16*)alloc(NC*2);
  _Float16* F_lo   = (_Float16*)alloc(NC*2);
  _Float16* Wreg = (_Float16*)alloc(2*( (size_t)3*CC_*2 + CC_*2 + 3*4*PEsz ));
  // phase-1 (lang): w13 split [0,8PEsz), w2 split [8PEsz,12PEsz)
  _Float16* w13hi = Wreg;
  _Float16* w13lo = Wreg + 4*PEsz;
  _Float16* w2hi  = Wreg + 8*PEsz;
  _Float16* w2lo  = Wreg + 10*PEsz;
  // phase-2: capw13f overlays dead w13; capw2f overlays dead w2; inw in tail
  _Float16* capw13f = Wreg;
  _Float16* capw2f  = Wreg + 8*PEsz;
  _Float16* inw_hi  = Wreg + 12*PEsz;
  _Float16* inw_lo  = inw_hi + 3*CC_;

  // 1) phase-0 conversions (+ inline language gating, langP, counts=0)
  convA<<<CVA_TOT, 256, 0, stream>>>(
      lang_embed, lang_gw, lang_gb, language,
      lang_w1, lang_w3, lang_w2, x,
      w13hi, w13lo, w2hi, w2lo, xAO_hi, xAO_lo, langP, counts);

  // 2) ffn1 gate
  gemm_gate_split<<<dim3((2*H_)/128, N_/256), 512, 0, stream>>>(
      xAO_hi, xAO_lo, w13hi, w13lo, Hb_hi, Hb_lo);

  // 3) ffn1 out + phase-2 conversions (co-resident)
  ffn1_out_fused<<<768, 256, 0, stream>>>(
      Hb_hi, Hb_lo, w2hi, w2lo, F_hi, F_lo,
      in_w, cap_w1, cap_w3, caption,
      inw_hi, inw_lo, capw13f, cap_hi, cap_lo);

  // 4) Q + KV projections + fold_w (W' = cap_gw . out_w)
  gemm_qkv<<<304, 256, 0, stream>>>(
      F_hi, F_lo, cap_hi, cap_lo, inw_hi, inw_lo, in_b,
      Qh, Ql, KVh, KVl, out_w, cap_gw, out_b, Wp, bp);

  // 5) attention + capw2 conversion (w2 region dead after step 3)
  attn_fused<<<640, 256, 0, stream>>>(Qh, Ql, KVh, KVl, xAO_hi, xAO_lo, cap_w2, capw2f);

  // 6) caption gating directly from AO via W'
  cap_gate<<<N_/8, 256, 0, stream>>>(xAO_hi, xAO_lo, Wp, bp, cap_gb, cap_sel, capP, counts);

  // 7) groups + perm + loss
  finalize<<<2, 256, 0, stream>>>(counts, cap_sel, offs, bmap_e, bmap_s,
                                  bmap_e2, bmap_s2, perm, capP, langP, out + NC);

  // 8) ffn2 gate
  _Float16* H2 = Hb_hi;
  gemm_gate_plain<<<dim3((2*H_)/128, MAXGB2), 512, 0, stream>>>(
      F_hi, capw13f, H2, bmap_e2, bmap_s2, offs, perm);

  // 9) ffn2 out + final sum scatter
  gemm8<2,1,3><<<dim3(C_/128, MAXGB), 256, 0, stream>>>(
      H2, nullptr, capw2f, nullptr, nullptr, out, F_hi, F_lo,
      bmap_e, bmap_s, offs, perm, N_, H_, C_, PEsz);
}

// Round 9
// 639.966 us; speedup vs baseline: 4.2368x; 1.0315x over previous
//
#include <hip/hip_runtime.h>
#include <stdint.h>

// Problem constants
#define B_ 2
#define T_ 2048
#define S_ 77
#define C_ 1024
#define E_ 4
#define H_ 2816
#define NH_ 8
#define HD_ 128
#define N_ (B_*T_)            // 4096 tokens
#define MAXGB (N_/128 + E_)   // 36 row-tiles of 128 (ffn2_out)
#define MAXGB2 (N_/256 + E_)  // 20 row-tiles of 256 (ffn2_gate)
#define PEsz ((size_t)H_*C_)  // per-expert matrix elems (H*C)
#define CC_ ((size_t)C_*C_)

typedef _Float16 h8 __attribute__((ext_vector_type(8)));
typedef _Float16 h4 __attribute__((ext_vector_type(4)));
typedef float f4 __attribute__((ext_vector_type(4)));

__device__ __forceinline__ void gload16(const void* g, void* l){
  __builtin_amdgcn_global_load_lds((const __attribute__((address_space(1))) void*)g,
                                   (__attribute__((address_space(3))) void*)l, 16, 0, 0);
}

// bijective XCD chunking, COLUMN-major decode (r7/r8; cm vs row measured within noise)
__device__ __forceinline__ void xcd_swizzle_cm(int& bx, int& by){
  int nx = gridDim.x, ny = gridDim.y;
  int nwg = nx*ny;
  int wg = by*nx + bx;
  int q = nwg >> 3, r = nwg & 7;
  int xcd = wg & 7, idx = wg >> 3;
  int s = (xcd < r ? xcd*(q+1) : r*(q+1) + (xcd-r)*q) + idx;
  bx = s / ny; by = s % ny;
}

// ---------------- Threefry-2x32 (JAX partitionable) ----------------
__device__ __forceinline__ uint32_t rotl32(uint32_t v, int r){ return (v<<r)|(v>>(32-r)); }
__device__ __forceinline__ void threefry2x32(uint32_t k0, uint32_t k1,
                                             uint32_t x, uint32_t y,
                                             uint32_t& o0, uint32_t& o1){
  uint32_t k2 = k0 ^ k1 ^ 0x1BD11BDAu;
  x += k0; y += k1;
#define TFR(r) { x += y; y = rotl32(y, r); y ^= x; }
  TFR(13) TFR(15) TFR(26) TFR(6)   x += k1; y += k2 + 1u;
  TFR(17) TFR(29) TFR(16) TFR(24)  x += k2; y += k0 + 2u;
  TFR(13) TFR(15) TFR(26) TFR(6)   x += k0; y += k1 + 3u;
  TFR(17) TFR(29) TFR(16) TFR(24)  x += k1; y += k2 + 4u;
  TFR(13) TFR(15) TFR(26) TFR(6)   x += k2; y += k0 + 5u;
#undef TFR
  o0 = x; o1 = y;
}
__device__ __forceinline__ float gumbel_from_bits(uint32_t bits){
  const float TINY = 1.17549435e-38f;
  float f = __uint_as_float((bits >> 9) | 0x3f800000u) - 1.0f;
  float u = fmaxf(TINY, f + TINY);
  return -logf(-logf(u));
}
__device__ __forceinline__ float jax_gumbel(uint32_t k0, uint32_t k1, uint32_t idx){
  uint32_t a, b;
  threefry2x32(k0, k1, 0u, idx, a, b);
  return gumbel_from_bits(a ^ b);
}

// ---------------- conversion job helpers (grid-stride over nb blocks) ----------------
__device__ __forceinline__ void job_split(const float* __restrict__ s,
    _Float16* __restrict__ hi, _Float16* __restrict__ lo, long n4, int b0, int nb){
  for (long i = (long)b0*256 + threadIdx.x; i < n4; i += (long)nb*256){
    float4 v = ((const float4*)s)[i];
    h4 h, L;
    h[0]=(_Float16)v.x; h[1]=(_Float16)v.y; h[2]=(_Float16)v.z; h[3]=(_Float16)v.w;
    L[0]=(_Float16)(v.x-(float)h[0]); L[1]=(_Float16)(v.y-(float)h[1]);
    L[2]=(_Float16)(v.z-(float)h[2]); L[3]=(_Float16)(v.w-(float)h[3]);
    ((h4*)hi)[i] = h; ((h4*)lo)[i] = L;
  }
}
__device__ __forceinline__ void job_plain(const float* __restrict__ s,
    _Float16* __restrict__ d, long n4, int b0, int nb){
  for (long i = (long)b0*256 + threadIdx.x; i < n4; i += (long)nb*256){
    float4 v = ((const float4*)s)[i];
    h4 h;
    h[0]=(_Float16)v.x; h[1]=(_Float16)v.y; h[2]=(_Float16)v.z; h[3]=(_Float16)v.w;
    ((h4*)d)[i] = h;
  }
}
// W1/W3 -> interleaved W13 (16-row groups: [w1 16 | w3 16] per 32), plain, slots=experts
__device__ __forceinline__ void job_w13_plain(const float* __restrict__ w1,
    const float* __restrict__ w3, _Float16* __restrict__ dst, int nslot, int b0, int nb){
  const int K8 = C_/8;
  long total = (long)nslot * (2*H_) * K8;
  for (long i = (long)b0*256 + threadIdx.x; i < total; i += (long)nb*256){
    int kv = (int)(i & (K8-1));
    long rs = i >> 7;
    int r  = (int)(rs % (2*H_));
    int slot = (int)(rs / (2*H_));
    int gg = r >> 5, o = r & 31;
    const float* src = ((o<16)? w1 : w3) + (size_t)slot*PEsz + (size_t)(16*gg + (o&15))*C_ + kv*8;
    float4 v0 = *(const float4*)src, v1 = *(const float4*)(src+4);
    float vv[8] = {v0.x,v0.y,v0.z,v0.w,v1.x,v1.y,v1.z,v1.w};
    h8 hh;
#pragma unroll
    for (int jj=0;jj<8;++jj) hh[jj] = (_Float16)vv[jj];
    *(h8*)(dst + (size_t)slot*2*PEsz + (size_t)r*C_ + kv*8) = hh;
  }
}
// split variant with selected experts (2 slots)
__device__ __forceinline__ void job_w13_split_sel(const float* __restrict__ w1,
    const float* __restrict__ w3, int sel0, int sel1,
    _Float16* __restrict__ hi, _Float16* __restrict__ lo, int b0, int nb){
  const int K8 = C_/8;
  long total = 2L * (2*H_) * K8;
  for (long i = (long)b0*256 + threadIdx.x; i < total; i += (long)nb*256){
    int kv = (int)(i & (K8-1));
    long rs = i >> 7;
    int r  = (int)(rs % (2*H_));
    int slot = (int)(rs / (2*H_));
    int e = slot ? sel1 : sel0;
    int gg = r >> 5, o = r & 31;
    const float* src = ((o<16)? w1 : w3) + (size_t)e*PEsz + (size_t)(16*gg + (o&15))*C_ + kv*8;
    float4 v0 = *(const float4*)src, v1 = *(const float4*)(src+4);
    float vv[8] = {v0.x,v0.y,v0.z,v0.w,v1.x,v1.y,v1.z,v1.w};
    h8 hh, ll;
#pragma unroll
    for (int jj=0;jj<8;++jj){
      hh[jj] = (_Float16)vv[jj];
      ll[jj] = (_Float16)(vv[jj]-(float)hh[jj]);
    }
    size_t dof = (size_t)slot*2*PEsz + (size_t)r*C_ + kv*8;
    *(h8*)(hi + dof) = hh;
    *(h8*)(lo + dof) = ll;
  }
}
__device__ __forceinline__ void job_w2_split_sel(const float* __restrict__ w2,
    int sel0, int sel1, _Float16* __restrict__ hi, _Float16* __restrict__ lo, int b0, int nb){
  long per = (long)(PEsz/4);
  for (long i = (long)b0*256 + threadIdx.x; i < 2*per; i += (long)nb*256){
    int slot = (i >= per) ? 1 : 0;
    long ii = i - (long)slot*per;
    float4 v = ((const float4*)(w2 + (size_t)(slot?sel1:sel0)*PEsz))[ii];
    h4 h, L;
    h[0]=(_Float16)v.x; h[1]=(_Float16)v.y; h[2]=(_Float16)v.z; h[3]=(_Float16)v.w;
    L[0]=(_Float16)(v.x-(float)h[0]); L[1]=(_Float16)(v.y-(float)h[1]);
    L[2]=(_Float16)(v.z-(float)h[2]); L[3]=(_Float16)(v.w-(float)h[3]);
    ((h4*)(hi + (size_t)slot*PEsz))[ii] = h;
    ((h4*)(lo + (size_t)slot*PEsz))[ii] = L;
  }
}
// fold_w: Wp[e][k] = sum_c capgw[e][c]*outw[c][k]; bp[e] = sum_c outb[c]*capgw[e][c]
__device__ __forceinline__ void job_foldw(const float* __restrict__ outw,
    const float* __restrict__ capgw, const float* __restrict__ outb,
    float* __restrict__ Wp, float* __restrict__ bp, int b0){
  int e = b0 >> 2;
  int k = ((b0 & 3) << 8) + threadIdx.x;
  const float* cg = capgw + e*C_;
  float acc = 0.f;
  for (int c = 0; c < C_; ++c) acc += cg[c] * outw[(size_t)c*C_ + k];
  Wp[e*C_ + k] = acc;
  if ((b0 & 3) == 0){
    int wv = threadIdx.x >> 6, l = threadIdx.x & 63;
    const float* cg2 = capgw + wv*C_;
    float a2 = 0.f;
    for (int c = l; c < C_; c += 64) a2 += outb[c] * cg2[c];
#pragma unroll
    for (int off = 32; off; off >>= 1) a2 += __shfl_xor(a2, off);
    if (l == 0 && e == 0) bp[wv] = a2;
  }
}

// ---------------- convA: lang gating (inline, redundant per block) + phase-0 conversions ----------------
#define CVA_W13 1024
#define CVA_W2  512
#define CVA_X   256
#define CVA_TOT (CVA_W13+CVA_W2+CVA_X)
__global__ __launch_bounds__(256) void convA(
    const float* __restrict__ lang_embed, const float* __restrict__ gate_w,
    const float* __restrict__ gate_b, const int* __restrict__ language,
    const float* __restrict__ w1, const float* __restrict__ w3, const float* __restrict__ w2,
    const float* __restrict__ x,
    _Float16* __restrict__ w13hi, _Float16* __restrict__ w13lo,
    _Float16* __restrict__ w2hi, _Float16* __restrict__ w2lo,
    _Float16* __restrict__ xhi, _Float16* __restrict__ xlo,
    float* __restrict__ langP, int* __restrict__ counts)
{
  __shared__ float lds8[8];
  const int tid = threadIdx.x, w = tid>>6, l = tid&63;
  for (int p = 2*w; p < 2*w+2; ++p){
    int b = p>>2, e = p&3;
    const float* emb = lang_embed + (size_t)language[b]*C_;
    const float* gw  = gate_w + (size_t)e*C_;
    float acc = 0.f;
    for (int c = l; c < C_; c += 64) acc += emb[c]*gw[c];
#pragma unroll
    for (int off = 32; off; off >>= 1) acc += __shfl_xor(acc, off);
    if (l == 0) lds8[p] = acc + gate_b[e];
  }
  __syncthreads();
  int sel[2];
  for (int b = 0; b < 2; ++b){
    float z[4], m = -3.4e38f;
    for (int e = 0; e < 4; ++e){
      float g = jax_gumbel(0u, 1u, (uint32_t)(b*4 + e));
      z[e] = (lds8[b*4 + e] + g) * 0.5f;
      m = fmaxf(m, z[e]);
    }
    float y[4], sum = 0.f;
    for (int e = 0; e < 4; ++e){ y[e] = expf(z[e]-m); sum += y[e]; }
    for (int e = 0; e < 4; ++e) y[e] = y[e] / sum;
    int best = 0; float bv = y[0];
    for (int e = 1; e < 4; ++e) if (y[e] > bv){ bv = y[e]; best = e; }
    sel[b] = best;
    if (blockIdx.x == 0 && tid == 0){
      for (int e = 0; e < 4; ++e)
        langP[b*4 + e] = ((e == best) ? 1.0f : 0.0f) - y[e] + y[e];
    }
  }
  if (blockIdx.x == 0 && tid == 0){
    for (int e = 0; e < 4; ++e) counts[e] = 0;
  }
  int bid = blockIdx.x;
  if (bid < CVA_W13)                 job_w13_split_sel(w1, w3, sel[0], sel[1], w13hi, w13lo, bid, CVA_W13);
  else if (bid < CVA_W13+CVA_W2)     job_w2_split_sel(w2, sel[0], sel[1], w2hi, w2lo, bid-CVA_W13, CVA_W2);
  else                               job_split(x, xhi, xlo, (long)((size_t)N_*C_/4), bid-CVA_W13-CVA_W2, CVA_X);
}

// ============ deep-pipelined 256x128 split gate GEMM (ffn1_gate) ============
// NEW this round: staging interleaved into compute phases (2 loads/phase),
// vmcnt(6) (one stage outstanding at wait), ONE barrier per K-tile.
// Safety: writes during iter t target buf (t-1)%3, reads target t%3; barrier-locked
// wave skew <= 1 iteration, so no wave can write a buffer another wave still reads.
__global__ __launch_bounds__(512,2) void gemm_gate_split(
    const _Float16* __restrict__ Ahi, const _Float16* __restrict__ Alo,
    const _Float16* __restrict__ Bhi, const _Float16* __restrict__ Blo,
    _Float16* __restrict__ Hhi, _Float16* __restrict__ Hlo)
{
  __shared__ __align__(16) char smem[147456];   // 3 x (A 32KB + B 16KB)
  const int tid = threadIdx.x, w = tid>>6, l = tid&63;
  const int lm = l&15, g = l>>4;
  const int wm = w>>1, wn = w&1;
  int bx = blockIdx.x, by = blockIdx.y;
  xcd_swizzle_cm(bx, by);
  const int n0 = bx<<7;
  const int m0 = by<<8;
  const size_t eoff = (m0 >= T_) ? (size_t)2*PEsz : 0;

  const _Float16* srcA[4]; const _Float16* srcB[2];
#pragma unroll
  for (int jj=0;jj<4;++jj){
    int c = jj*512 + tid, r = c>>3, s = c&7;
    int st = s ^ (r&7);
    srcA[jj] = (st<4 ? Ahi : Alo) + (size_t)(m0 + r)*C_ + ((st&3)<<3);
  }
#pragma unroll
  for (int jj=0;jj<2;++jj){
    int c = jj*512 + tid, r = c>>3, s = c&7;
    int st = s ^ (r&7);
    srcB[jj] = (st<4 ? Bhi : Blo) + eoff + (size_t)(n0 + r)*C_ + ((st&3)<<3);
  }

#define STGF(ts, bi) { \
    int k0 = (ts)<<5; \
    char* db = smem + (bi)*49152; \
    _Pragma("unroll") \
    for (int jj=0;jj<4;++jj) gload16(srcA[jj]+k0, db + (jj*512 + w*64)*16); \
    _Pragma("unroll") \
    for (int jj=0;jj<2;++jj) gload16(srcB[jj]+k0, db + 32768 + (jj*512 + w*64)*16); \
  }

  const int shi = (g ^ (lm&7)) << 4;
  int aoff[4], boff[4];
#pragma unroll
  for (int i=0;i<4;++i){
    aoff[i] = ((wm*64 + i*16 + lm)<<7) + shi;
    boff[i] = 32768 + ((wn*64 + i*16 + lm)<<7) + shi;
  }

  f4 acc[4][4] = {};
  const int nt = C_/32;   // 32
  STGF(0,0) STGF(1,1)
  for (int t=0; t<nt; ++t){
    const int bi = t%3;
    const bool ds = (t+2 < nt);
    const int k2 = (t+2)<<5;
    char* db2 = smem + ((t+2)%3)*49152;
    if (t+1 < nt) { asm volatile("s_waitcnt vmcnt(6)" ::: "memory"); }
    else          { asm volatile("s_waitcnt vmcnt(0)" ::: "memory"); }
    __builtin_amdgcn_s_barrier();
    asm volatile("" ::: "memory");
    const char* base = smem + bi*49152;
    // phase 1: stage A01 of t+2, compute hh
    if (ds){
      gload16(srcA[0]+k2, db2 + (0*512 + w*64)*16);
      gload16(srcA[1]+k2, db2 + (1*512 + w*64)*16);
    }
    h8 ah[4], bh[4];
#pragma unroll
    for (int i=0;i<4;++i){ ah[i] = *(const h8*)(base + aoff[i]); bh[i] = *(const h8*)(base + boff[i]); }
    __builtin_amdgcn_s_setprio(1);
#pragma unroll
    for (int mi=0;mi<4;++mi)
#pragma unroll
      for (int ni=0;ni<4;++ni)
        acc[mi][ni] = __builtin_amdgcn_mfma_f32_16x16x32_f16(ah[mi], bh[ni], acc[mi][ni],0,0,0);
    __builtin_amdgcn_s_setprio(0);
    // phase 2: stage A23 of t+2, compute ah*bl
    if (ds){
      gload16(srcA[2]+k2, db2 + (2*512 + w*64)*16);
      gload16(srcA[3]+k2, db2 + (3*512 + w*64)*16);
    }
    h8 bl[4];
#pragma unroll
    for (int i=0;i<4;++i) bl[i] = *(const h8*)(base + (boff[i]^64));
    __builtin_amdgcn_s_setprio(1);
#pragma unroll
    for (int mi=0;mi<4;++mi)
#pragma unroll
      for (int ni=0;ni<4;++ni)
        acc[mi][ni] = __builtin_amdgcn_mfma_f32_16x16x32_f16(ah[mi], bl[ni], acc[mi][ni],0,0,0);
    __builtin_amdgcn_s_setprio(0);
    // phase 3: stage B01 of t+2, compute al*bh
    if (ds){
      gload16(srcB[0]+k2, db2 + 32768 + (0*512 + w*64)*16);
      gload16(srcB[1]+k2, db2 + 32768 + (1*512 + w*64)*16);
    }
    h8 al[4];
#pragma unroll
    for (int i=0;i<4;++i) al[i] = *(const h8*)(base + (aoff[i]^64));
    __builtin_amdgcn_s_setprio(1);
#pragma unroll
    for (int mi=0;mi<4;++mi)
#pragma unroll
      for (int ni=0;ni<4;++ni)
        acc[mi][ni] = __builtin_amdgcn_mfma_f32_16x16x32_f16(al[mi], bh[ni], acc[mi][ni],0,0,0);
    __builtin_amdgcn_s_setprio(0);
    asm volatile("" ::: "memory");
  }
#undef STGF

#pragma unroll
  for (int mi=0;mi<4;++mi){
#pragma unroll
    for (int p=0;p<2;++p){
      int hc = ((n0 + wn*64)>>1) + p*16 + lm;
#pragma unroll
      for (int j=0;j<4;++j){
        int rl = wm*64 + mi*16 + (g<<2) + j;
        float s1 = acc[mi][2*p][j], s3 = acc[mi][2*p+1][j];
        float hval = s1/(1.f+expf(-s1))*s3;
        size_t row = (size_t)(m0 + rl);
        _Float16 hh = (_Float16)hval;
        Hhi[row*H_ + hc] = hh;
        Hlo[row*H_ + hc] = (_Float16)(hval - (float)hh);
      }
    }
  }
}

// ============ deep-pipelined 256x128 plain gate GEMM (ffn2_gate) ============
// Same interleaved-stage / single-barrier restructure (3 loads per phase x2).
__global__ __launch_bounds__(512,2) void gemm_gate_plain(
    const _Float16* __restrict__ A, const _Float16* __restrict__ Bw,
    _Float16* __restrict__ Hout,
    const int* __restrict__ bmap_e, const int* __restrict__ bmap_s,
    const int* __restrict__ offs, const int* __restrict__ perm)
{
  __shared__ __align__(16) char smem[147456];
  const int tid = threadIdx.x, w = tid>>6, l = tid&63;
  const int lm = l&15, g = l>>4;
  const int wm = w>>1, wn = w&1;
  int bx = blockIdx.x, by = blockIdx.y;
  xcd_swizzle_cm(bx, by);
  const int e = bmap_e[by]; if (e<0) return;
  const int m0 = bmap_s[by];
  int v = offs[e+1]-m0; const int valid = v>256?256:v;
  const size_t eoff = (size_t)e*2*PEsz;
  const int n0 = bx<<7;

  const _Float16* srcA[4]; const _Float16* srcB[2];
#pragma unroll
  for (int jj=0;jj<4;++jj){
    int c = jj*512 + tid, r = c>>3, s = c&7;
    int st = s ^ (r&7);
    int ia = m0 + r; ia = (ia<N_) ? ia : (N_-1);
    srcA[jj] = A + (size_t)perm[ia]*C_ + (st<<3);
  }
#pragma unroll
  for (int jj=0;jj<2;++jj){
    int c = jj*512 + tid, r = c>>3, s = c&7;
    int st = s ^ (r&7);
    srcB[jj] = Bw + eoff + (size_t)(n0 + r)*C_ + (st<<3);
  }

#define STGF(ts, bi) { \
    int k0 = (ts)<<6; \
    char* db = smem + (bi)*49152; \
    _Pragma("unroll") \
    for (int jj=0;jj<4;++jj) gload16(srcA[jj]+k0, db + (jj*512 + w*64)*16); \
    _Pragma("unroll") \
    for (int jj=0;jj<2;++jj) gload16(srcB[jj]+k0, db + 32768 + (jj*512 + w*64)*16); \
  }

  const int shi = (g ^ (lm&7)) << 4;
  int aoff[4], boff[4];
#pragma unroll
  for (int i=0;i<4;++i){
    aoff[i] = ((wm*64 + i*16 + lm)<<7) + shi;
    boff[i] = 32768 + ((wn*64 + i*16 + lm)<<7) + shi;
  }

  f4 acc[4][4] = {};
  const int nt = C_/64;   // 16
  STGF(0,0) STGF(1,1)
  for (int t=0; t<nt; ++t){
    const int bi = t%3;
    const bool ds = (t+2 < nt);
    const int k2 = (t+2)<<6;
    char* db2 = smem + ((t+2)%3)*49152;
    if (t+1 < nt) { asm volatile("s_waitcnt vmcnt(6)" ::: "memory"); }
    else          { asm volatile("s_waitcnt vmcnt(0)" ::: "memory"); }
    __builtin_amdgcn_s_barrier();
    asm volatile("" ::: "memory");
    const char* base = smem + bi*49152;
#pragma unroll
    for (int kk=0;kk<2;++kk){
      if (ds){
        if (kk == 0){
          gload16(srcA[0]+k2, db2 + (0*512 + w*64)*16);
          gload16(srcA[1]+k2, db2 + (1*512 + w*64)*16);
          gload16(srcA[2]+k2, db2 + (2*512 + w*64)*16);
        } else {
          gload16(srcA[3]+k2, db2 + (3*512 + w*64)*16);
          gload16(srcB[0]+k2, db2 + 32768 + (0*512 + w*64)*16);
          gload16(srcB[1]+k2, db2 + 32768 + (1*512 + w*64)*16);
        }
      }
      h8 af[4], bf[4];
      const int x = kk<<6;
#pragma unroll
      for (int i=0;i<4;++i){ af[i] = *(const h8*)(base + (aoff[i]^x)); bf[i] = *(const h8*)(base + (boff[i]^x)); }
      __builtin_amdgcn_s_setprio(1);
#pragma unroll
      for (int mi=0;mi<4;++mi)
#pragma unroll
        for (int ni=0;ni<4;++ni)
          acc[mi][ni] = __builtin_amdgcn_mfma_f32_16x16x32_f16(af[mi], bf[ni], acc[mi][ni],0,0,0);
      __builtin_amdgcn_s_setprio(0);
    }
    asm volatile("" ::: "memory");
  }
#undef STGF

#pragma unroll
  for (int mi=0;mi<4;++mi){
#pragma unroll
    for (int p=0;p<2;++p){
      int hc = ((n0 + wn*64)>>1) + p*16 + lm;
#pragma unroll
      for (int j=0;j<4;++j){
        int rl = wm*64 + mi*16 + (g<<2) + j;
        if (rl >= valid) continue;
        float s1 = acc[mi][2*p][j], s3 = acc[mi][2*p+1][j];
        Hout[(size_t)(m0 + rl)*H_ + hc] = (_Float16)(s1/(1.f+expf(-s1))*s3);
      }
    }
  }
}

// ---------------- unified pipelined GEMM body (128x128, unchanged) ----------------
// EPI: 1 f16 hi/lo (+opt bias), 2 scatter-add
// EXPM: 0 none, 1 lang slot by m-block, 3 grouped rows + linear A
template<int EPI, int NSEG, int EXPM>
__device__ __forceinline__ void gemm8_body(
    char* smem,
    const _Float16* __restrict__ A0, const _Float16* __restrict__ A1,
    const _Float16* __restrict__ B0, const _Float16* __restrict__ B1,
    const float* __restrict__ bias, float* __restrict__ Cf32,
    _Float16* __restrict__ O0, _Float16* __restrict__ O1,
    const int* __restrict__ bmap_e, const int* __restrict__ bmap_s,
    const int* __restrict__ offs, const int* __restrict__ perm,
    int M, int K, int Nw, size_t bstride_e, int bx, int by)
{
  const int tid = threadIdx.x, w = tid>>6, l = tid&63;
  const int lm = l&15, g = l>>4;
  const int wm = w>>1, wn = w&1;
  const int n0 = bx<<7;
  int m0, valid = 128; size_t eoff = 0;
  if constexpr (EXPM==3){
    int e = bmap_e[by]; if (e<0) return;
    m0 = bmap_s[by];
    int v = offs[e+1]-m0; valid = v>128?128:v;
    eoff = (size_t)e*bstride_e;
  } else {
    m0 = by<<7;
    if constexpr (EXPM==1) eoff = (m0>=T_) ? bstride_e : 0;
  }
  const int cAe = (((tid&7) ^ ((tid>>3)&7)) << 3);
  size_t rbA[4], rbB[4];
#pragma unroll
  for (int j=0;j<4;++j){
    int r = (j<<5) + (tid>>3);
    int ia = m0 + r;
    if constexpr (EXPM==3){ ia = (ia < N_) ? ia : (N_-1); }
    else { if (ia > M-1) ia = M-1; }
    rbA[j] = (size_t)ia*K + cAe;
    rbB[j] = eoff + (size_t)(n0+r)*K + cAe;
  }
  const int tps = K>>6, nt = NSEG*tps;

#define STAGE8(tt, cc) { \
    int sg = 0; \
    if constexpr (NSEG==3){ sg = ((tt)>=2*tps) ? 2 : (((tt)>=tps)?1:0); } \
    const _Float16* Asrc = (sg==1) ? A1 : A0; \
    const _Float16* Bsrc = (sg==2) ? B1 : B0; \
    int kk0 = ((tt) - sg*tps)<<6; \
    char* db = smem + (cc)*32768 + w*1024; \
    _Pragma("unroll") \
    for (int j=0;j<4;++j) gload16(Asrc + rbA[j] + kk0, db + j*4096); \
    _Pragma("unroll") \
    for (int j=0;j<4;++j) gload16(Bsrc + rbB[j] + kk0, db + 16384 + j*4096); \
  }

  int aoff[2][4], boff[2][4];
#pragma unroll
  for (int kk=0;kk<2;++kk){
#pragma unroll
    for (int i=0;i<4;++i){
      int ra = wm*64 + i*16 + lm;
      aoff[kk][i] = (ra<<7) + (((kk<<6)+(g<<4)) ^ ((ra&7)<<4));
      int rb = wn*64 + i*16 + lm;
      boff[kk][i] = (rb<<7) + (((kk<<6)+(g<<4)) ^ ((rb&7)<<4));
    }
  }

  f4 acc[4][4] = {};
  STAGE8(0, 0)
  for (int t=0; t<nt; ++t){
    const int c = t&1;
    if (t+1 < nt){
      STAGE8(t+1, c^1)
      asm volatile("s_waitcnt vmcnt(8)" ::: "memory");
    } else {
      asm volatile("s_waitcnt vmcnt(0)" ::: "memory");
    }
    __builtin_amdgcn_s_barrier();
    const char* Ab = smem + c*32768;
    const char* Bb = Ab + 16384;
#pragma unroll
    for (int kk=0;kk<2;++kk){
      h8 af[4], bf[4];
#pragma unroll
      for (int i=0;i<4;++i){
        af[i] = *(const h8*)(Ab + aoff[kk][i]);
        bf[i] = *(const h8*)(Bb + boff[kk][i]);
      }
      __builtin_amdgcn_s_setprio(1);
#pragma unroll
      for (int mi=0;mi<4;++mi)
#pragma unroll
        for (int ni=0;ni<4;++ni)
          acc[mi][ni] = __builtin_amdgcn_mfma_f32_16x16x32_f16(af[mi], bf[ni], acc[mi][ni],0,0,0);
      __builtin_amdgcn_s_setprio(0);
      __builtin_amdgcn_s_barrier();
    }
  }

#pragma unroll
  for (int mi=0;mi<4;++mi){
    const int rl0 = wm*64 + mi*16 + (g<<2);
#pragma unroll
    for (int ni=0;ni<4;++ni){
      int col = n0 + wn*64 + ni*16 + lm;
#pragma unroll
      for (int j=0;j<4;++j){
        int rl = rl0 + j;
        float vv = acc[mi][ni][j];
        if constexpr (EPI==1){
          int grow = m0 + rl;
          if (grow < M){
            float vb = vv + (bias ? bias[col] : 0.f);
            _Float16 hh = (_Float16)vb;
            O0[(size_t)grow*Nw + col] = hh;
            O1[(size_t)grow*Nw + col] = (_Float16)(vb - (float)hh);
          }
        } else {
          if (rl < valid){
            int orig = perm[m0 + rl];
            size_t o = (size_t)orig*C_ + col;
            Cf32[o] = (float)O0[o] + (float)O1[o] + vv;
          }
        }
      }
    }
  }
#undef STAGE8
}

template<int EPI, int NSEG, int EXPM>
__global__ __launch_bounds__(256,2) void gemm8(
    const _Float16* __restrict__ A0, const _Float16* __restrict__ A1,
    const _Float16* __restrict__ B0, const _Float16* __restrict__ B1,
    const float* __restrict__ bias, float* __restrict__ Cf32,
    _Float16* __restrict__ O0, _Float16* __restrict__ O1,
    const int* __restrict__ bmap_e, const int* __restrict__ bmap_s,
    const int* __restrict__ offs, const int* __restrict__ perm,
    int M, int K, int Nw, size_t bstride_e)
{
  __shared__ __align__(16) char smem[65536];
  int bx = blockIdx.x, by = blockIdx.y;
  xcd_swizzle_cm(bx, by);
  gemm8_body<EPI,NSEG,EXPM>(smem, A0,A1,B0,B1,bias,Cf32,O0,O1,
                            bmap_e,bmap_s,offs,perm,M,K,Nw,bstride_e,bx,by);
}

// ---------------- ffn1_out (gemm8<1,3,1>) fused with phase-2 weight conversions ----------------
__global__ __launch_bounds__(256,2) void ffn1_out_fused(
    const _Float16* __restrict__ Hbh, const _Float16* __restrict__ Hbl,
    const _Float16* __restrict__ w2hi, const _Float16* __restrict__ w2lo,
    _Float16* __restrict__ Fh, _Float16* __restrict__ Fl,
    const float* __restrict__ in_w,
    const float* __restrict__ cap_w1, const float* __restrict__ cap_w3,
    const float* __restrict__ caption,
    _Float16* __restrict__ inwh, _Float16* __restrict__ inwl,
    _Float16* __restrict__ capw13,
    _Float16* __restrict__ caph, _Float16* __restrict__ capl)
{
  __shared__ __align__(16) char smem[65536];
  int id = blockIdx.x;
  if (id < 256){
    gemm8_body<1,3,1>(smem, Hbh, Hbl, w2hi, w2lo, nullptr, nullptr, Fh, Fl,
                      nullptr,nullptr,nullptr,nullptr, N_, H_, C_, PEsz, id&7, id>>3);
  } else {
    int cid = id - 256;                    // 512 conversion blocks
    if (cid < 352)      job_w13_plain(cap_w1, cap_w3, capw13, 4, cid, 352);
    else if (cid < 496) job_split(in_w, inwh, inwl, (long)(3*CC_/4), cid-352, 144);
    else                job_split(caption, caph, capl, (long)((size_t)B_*S_*C_/4), cid-496, 16);
  }
}

// ---------------- Q + KV projections + fold_w in one dispatch ----------------
__global__ __launch_bounds__(256,2) void gemm_qkv(
    const _Float16* __restrict__ Fh, const _Float16* __restrict__ Fl,
    const _Float16* __restrict__ caph, const _Float16* __restrict__ capl,
    const _Float16* __restrict__ inwh, const _Float16* __restrict__ inwl,
    const float* __restrict__ in_b,
    _Float16* __restrict__ Qh, _Float16* __restrict__ Ql,
    _Float16* __restrict__ KVh, _Float16* __restrict__ KVl,
    const float* __restrict__ out_w, const float* __restrict__ cap_gw,
    const float* __restrict__ out_b, float* __restrict__ Wp, float* __restrict__ bp)
{
  __shared__ __align__(16) char smem[65536];
  int id = blockIdx.x;
  if (id < 256){
    gemm8_body<1,3,0>(smem, Fh, Fl, inwh, inwl, in_b, nullptr, Qh, Ql,
                      nullptr,nullptr,nullptr,nullptr, N_, C_, C_, 0, id&7, id>>3);
  } else if (id < 288){
    int cid = id - 256;                    // KV: grid (16,2)
    gemm8_body<1,3,0>(smem, caph, capl, inwh + CC_, inwl + CC_, in_b + C_,
                      nullptr, KVh, KVl, nullptr,nullptr,nullptr,nullptr,
                      B_*S_, C_, 2*C_, 0, cid & 15, cid >> 4);
  } else {
    job_foldw(out_w, cap_gw, out_b, Wp, bp, id-288);   // 16 blocks
  }
}

// ---------------- MFMA cross attention (flattened grid) + capw2 conversion ----------------
#define SP5 5
#define KSTR 136
#define VSTR 104
__global__ __launch_bounds__(256) void attn_fused(
    const _Float16* __restrict__ Qh, const _Float16* __restrict__ Ql,
    const _Float16* __restrict__ KVh, const _Float16* __restrict__ KVl,
    _Float16* __restrict__ AOh, _Float16* __restrict__ AOl,
    const float* __restrict__ cap_w2, _Float16* __restrict__ capw2f)
{
  __shared__ __align__(16) _Float16 Usm[2*128*VSTR];
  __shared__ __align__(16) _Float16 Psm[2*64*VSTR];
  int id = blockIdx.x;
  if (id >= 512){ job_plain(cap_w2, capw2f, (long)(4*PEsz/4), id-512, 128); return; }
  _Float16* Kh_s = Usm;
  _Float16* Kl_s = Usm + 128*VSTR;
  _Float16* VTh  = Usm;
  _Float16* VTl  = Usm + 128*VSTR;
  _Float16* Ph   = Psm;
  _Float16* Pl   = Psm + 64*VSTR;

  const int tid = threadIdx.x;
  const int w = tid>>6, l = tid&63, lm = l&15, g = l>>4;
  const int b = id >> 8, h = (id >> 5) & 7, q0 = (id & 31) << 6;
  const float scale = 0.08838834764831845f;

  for (int i = tid; i < 64*VSTR; i += 256) ((uint32_t*)Psm)[i] = 0;
  {
    int oct = tid & 15, s0 = tid >> 4;
    for (int s = s0; s < 80; s += 16){
      h8 vh = {}, vl = {};
      if (s < S_){
        size_t ga = ((size_t)(b*S_ + s))*(2*C_) + h*HD_ + oct*8;
        vh = *(const h8*)(KVh + ga);
        vl = *(const h8*)(KVl + ga);
      }
      *(h8*)(Kh_s + s*KSTR + oct*8) = vh;
      *(h8*)(Kl_s + s*KSTR + oct*8) = vl;
    }
  }
  h8 qh[4], ql[4];
  {
    size_t qrow = (size_t)(b*T_ + q0 + w*16 + lm);
    const _Float16* qph = Qh + qrow*C_ + h*HD_ + g*8;
    const _Float16* qpl = Ql + qrow*C_ + h*HD_ + g*8;
#pragma unroll
    for (int ks=0; ks<4; ++ks){ qh[ks] = *(const h8*)(qph + ks*32); ql[ks] = *(const h8*)(qpl + ks*32); }
  }
  __syncthreads();

  f4 sc[SP5] = {};
#pragma unroll
  for (int ks=0; ks<4; ++ks){
#pragma unroll
    for (int nt=0; nt<SP5; ++nt){
      h8 kh = *(const h8*)(Kh_s + (nt*16+lm)*KSTR + ks*32 + g*8);
      h8 kl = *(const h8*)(Kl_s + (nt*16+lm)*KSTR + ks*32 + g*8);
      sc[nt] = __builtin_amdgcn_mfma_f32_16x16x32_f16(qh[ks], kh, sc[nt],0,0,0);
      sc[nt] = __builtin_amdgcn_mfma_f32_16x16x32_f16(ql[ks], kh, sc[nt],0,0,0);
      sc[nt] = __builtin_amdgcn_mfma_f32_16x16x32_f16(qh[ks], kl, sc[nt],0,0,0);
    }
  }

  float mx[4] = {-3e38f,-3e38f,-3e38f,-3e38f};
#pragma unroll
  for (int nt=0; nt<SP5; ++nt){
    bool valid = (nt*16+lm) < S_;
#pragma unroll
    for (int j=0;j<4;++j){
      float v = valid ? sc[nt][j]*scale : -3e38f;
      sc[nt][j] = v;
      mx[j] = fmaxf(mx[j], v);
    }
  }
#pragma unroll
  for (int off=1; off<16; off<<=1){
#pragma unroll
    for (int j=0;j<4;++j) mx[j] = fmaxf(mx[j], __shfl_xor(mx[j], off));
  }
  float sm[4] = {0,0,0,0};
#pragma unroll
  for (int nt=0; nt<SP5; ++nt){
    bool valid = (nt*16+lm) < S_;
#pragma unroll
    for (int j=0;j<4;++j){
      float p = valid ? expf(sc[nt][j]-mx[j]) : 0.f;
      sc[nt][j] = p; sm[j] += p;
    }
  }
#pragma unroll
  for (int off=1; off<16; off<<=1){
#pragma unroll
    for (int j=0;j<4;++j) sm[j] += __shfl_xor(sm[j], off);
  }
#pragma unroll
  for (int nt=0; nt<SP5; ++nt){
#pragma unroll
    for (int j=0;j<4;++j){
      int col = nt*16 + lm;
      if (col < S_){
        float p = sc[nt][j] / sm[j];
        int row = w*16 + g*4 + j;
        _Float16 ph = (_Float16)p;
        Ph[row*VSTR + col] = ph;
        Pl[row*VSTR + col] = (_Float16)(p - (float)ph);
      }
    }
  }
  __syncthreads();

  for (int i = tid; i < 128*VSTR; i += 256) ((uint32_t*)Usm)[i] = 0;
  __syncthreads();
  {
    int oct = tid & 15, s0 = tid >> 4;
    for (int s = s0; s < S_; s += 16){
      size_t ga = ((size_t)(b*S_ + s))*(2*C_) + C_ + h*HD_ + oct*8;
      h8 vh = *(const h8*)(KVh + ga);
      h8 vl = *(const h8*)(KVl + ga);
#pragma unroll
      for (int i2=0;i2<8;++i2){
        VTh[(oct*8+i2)*VSTR + s] = vh[i2];
        VTl[(oct*8+i2)*VSTR + s] = vl[i2];
      }
    }
  }
  __syncthreads();

  h8 pah[3], pal[3];
#pragma unroll
  for (int ks=0;ks<3;++ks){
    pah[ks] = *(const h8*)(Ph + (w*16+lm)*VSTR + ks*32 + g*8);
    pal[ks] = *(const h8*)(Pl + (w*16+lm)*VSTR + ks*32 + g*8);
  }
#pragma unroll
  for (int nt=0; nt<8; ++nt){
    f4 o = {};
#pragma unroll
    for (int ks=0;ks<3;++ks){
      h8 vh = *(const h8*)(VTh + (nt*16+lm)*VSTR + ks*32 + g*8);
      h8 vl = *(const h8*)(VTl + (nt*16+lm)*VSTR + ks*32 + g*8);
      o = __builtin_amdgcn_mfma_f32_16x16x32_f16(pah[ks], vh, o,0,0,0);
      o = __builtin_amdgcn_mfma_f32_16x16x32_f16(pal[ks], vh, o,0,0,0);
      o = __builtin_amdgcn_mfma_f32_16x16x32_f16(pah[ks], vl, o,0,0,0);
    }
#pragma unroll
    for (int j=0;j<4;++j){
      size_t orow = (size_t)(b*T_ + q0 + w*16 + g*4 + j);
      size_t oa = orow*C_ + h*HD_ + nt*16 + lm;
      _Float16 hh = (_Float16)o[j];
      AOh[oa] = hh;
      AOl[oa] = (_Float16)(o[j] - (float)hh);
    }
  }
}

// ---------------- caption gating from AO (hi/lo) via folded W' ----------------
__global__ __launch_bounds__(256) void cap_gate(
    const _Float16* __restrict__ AOh, const _Float16* __restrict__ AOl,
    const float* __restrict__ Wp, const float* __restrict__ bp,
    const float* __restrict__ gb,
    int* __restrict__ cap_sel, float* __restrict__ capP, int* __restrict__ counts)
{
  int tid = threadIdx.x, wave = tid >> 6, lane = tid & 63;
  for (int r = 0; r < 2; ++r){
    int row = (blockIdx.x << 3) + (wave << 1) + r;
    float av[16];
#pragma unroll
    for (int i = 0; i < 16; ++i){
      int c = lane + (i << 6);
      av[i] = (float)AOh[(size_t)row*C_ + c] + (float)AOl[(size_t)row*C_ + c];
    }
    float lg[E_];
#pragma unroll
    for (int e = 0; e < E_; ++e){
      const float* wv = Wp + (size_t)e * C_;
      float p = 0.f;
#pragma unroll
      for (int i = 0; i < 16; ++i) p += av[i] * wv[lane + (i << 6)];
#pragma unroll
      for (int off = 32; off; off >>= 1) p += __shfl_xor(p, off);
      lg[e] = p + bp[e] + gb[e];
    }
    if (lane == 0){
      float z[E_], m = -3.4e38f;
      for (int e = 0; e < E_; ++e){
        float gmb = jax_gumbel(0u, 2u, (uint32_t)(row*E_ + e));
        z[e] = (lg[e] + gmb) * 0.5f;
        m = fmaxf(m, z[e]);
      }
      float y[E_], sum = 0.f;
      for (int e = 0; e < E_; ++e){ y[e] = expf(z[e] - m); sum += y[e]; }
      for (int e = 0; e < E_; ++e) y[e] = y[e] / sum;
      int best = 0; float bv = y[0];
      for (int e = 1; e < E_; ++e) if (y[e] > bv){ bv = y[e]; best = e; }
      cap_sel[row] = best;
      atomicAdd(&counts[best], 1);
      for (int e = 0; e < E_; ++e)
        capP[(size_t)row*E_ + e] = ((e == best) ? 1.0f : 0.0f) - y[e] + y[e];
    }
  }
}

// ---------------- finalize: groups + perm scatter (block 0) + loss (block 1) ----------------
__global__ __launch_bounds__(256) void finalize(
    const int* __restrict__ counts, const int* __restrict__ cap_sel,
    int* __restrict__ offs,
    int* __restrict__ bmap_e, int* __restrict__ bmap_s,
    int* __restrict__ bmap_e2, int* __restrict__ bmap_s2,
    int* __restrict__ perm,
    const float* __restrict__ capP, const float* __restrict__ langP,
    float* __restrict__ out_loss)
{
  __shared__ int loffs[5];
  __shared__ int lcur[4];
  __shared__ float red[4][256];
  int tid = threadIdx.x;
  if (blockIdx.x == 0){
    if (tid == 0){
      loffs[0] = 0;
      for (int e = 0; e < E_; ++e){ loffs[e+1] = loffs[e] + counts[e]; lcur[e] = loffs[e]; }
      for (int e = 0; e < E_+1; ++e) offs[e] = loffs[e];
      int idx = 0;
      for (int e = 0; e < E_; ++e)
        for (int s = loffs[e]; s < loffs[e+1]; s += 128){ bmap_e[idx] = e; bmap_s[idx] = s; ++idx; }
      for (; idx < MAXGB; ++idx) bmap_e[idx] = -1;
      int idx2 = 0;
      for (int e = 0; e < E_; ++e)
        for (int s = loffs[e]; s < loffs[e+1]; s += 256){ bmap_e2[idx2] = e; bmap_s2[idx2] = s; ++idx2; }
      for (; idx2 < MAXGB2; ++idx2) bmap_e2[idx2] = -1;
    }
    __syncthreads();
    for (int row = tid; row < N_; row += 256){
      int e = cap_sel[row];
      int pos = atomicAdd(&lcur[e], 1);
      perm[pos] = row;
    }
  } else {
    float p0=0.f, p1=0.f, p2=0.f, p3=0.f;
    for (int r = tid; r < N_; r += 256){
      const float* p = capP + (size_t)r*E_;
      p0 += p[0]; p1 += p[1]; p2 += p[2]; p3 += p[3];
    }
    red[0][tid]=p0; red[1][tid]=p1; red[2][tid]=p2; red[3][tid]=p3;
    __syncthreads();
    for (int s = 128; s > 0; s >>= 1){
      if (tid < s){
        red[0][tid]+=red[0][tid+s]; red[1][tid]+=red[1][tid+s];
        red[2][tid]+=red[2][tid+s]; red[3][tid]+=red[3][tid+s];
      }
      __syncthreads();
    }
    if (tid == 0){
      float loss = 0.f;
      for (int e = 0; e < E_; ++e){
        float ul = (langP[e] + langP[E_ + e]) * 0.5f;
        loss += ul * logf(ul + 1e-10f);
      }
      for (int e = 0; e < E_; ++e){
        float uc = red[e][0] * (1.0f / N_);
        loss += uc * logf(uc + 1e-10f);
      }
      out_loss[0] = loss;
    }
  }
}

// ---------------- host launch ----------------
extern "C" void kernel_launch(void* const* d_in, const int* in_sizes, int n_in,
                              void* d_out, int out_size, void* d_ws, size_t ws_size,
                              hipStream_t stream)
{
  const float* x          = (const float*)d_in[0];
  const float* caption    = (const float*)d_in[2];
  const int*   language   = (const int*)  d_in[3];
  const float* lang_embed = (const float*)d_in[4];
  const float* lang_gw    = (const float*)d_in[5];
  const float* lang_gb    = (const float*)d_in[6];
  const float* lang_w1    = (const float*)d_in[7];
  const float* lang_w2    = (const float*)d_in[8];
  const float* lang_w3    = (const float*)d_in[9];
  const float* in_w       = (const float*)d_in[10];
  const float* in_b       = (const float*)d_in[11];
  const float* out_w      = (const float*)d_in[12];
  const float* out_b      = (const float*)d_in[13];
  const float* cap_gw     = (const float*)d_in[14];
  const float* cap_gb     = (const float*)d_in[15];
  const float* cap_w1     = (const float*)d_in[16];
  const float* cap_w2     = (const float*)d_in[17];
  const float* cap_w3     = (const float*)d_in[18];
  float* out = (float*)d_out;

  const size_t NC = (size_t)N_*C_;
  const size_t NHe = (size_t)N_*H_;
  const size_t KVel = (size_t)B_*S_*2*C_;
  const size_t CAPel = (size_t)B_*S_*C_;

  char* base = (char*)d_ws;
  size_t cur = 0;
  auto alloc = [&](size_t bytes)->char*{
    char* p = base + cur;
    cur += (bytes + 255) & ~(size_t)255;
    return p;
  };
  _Float16* Qh = (_Float16*)alloc(NC*2);
  _Float16* Ql = (_Float16*)alloc(NC*2);
  char* kvreg = alloc(KVel*4);
  _Float16* KVh = (_Float16*)kvreg;
  _Float16* KVl = KVh + KVel;
  float* capP   = (float*)alloc((size_t)N_*E_*4);
  float* langP  = (float*)alloc(64);
  float* Wp     = (float*)alloc(E_*C_*4);
  float* bp     = (float*)alloc(64);
  int* cap_sel  = (int*)alloc(N_*4);
  int* counts   = (int*)alloc(64);
  int* offs     = (int*)alloc(64);
  int* bmap_e   = (int*)alloc(MAXGB*4);
  int* bmap_s   = (int*)alloc(MAXGB*4);
  int* bmap_e2  = (int*)alloc(MAXGB2*4);
  int* bmap_s2  = (int*)alloc(MAXGB2*4);
  int* perm     = (int*)alloc(N_*4);
  _Float16* xAO_hi = (_Float16*)alloc(NC*2);      // x_hi, then AO_hi
  _Float16* xAO_lo = (_Float16*)alloc(NC*2);
  _Float16* cap_hi = (_Float16*)alloc(CAPel*2);
  _Float16* cap_lo = (_Float16*)alloc(CAPel*2);
  _Float16* Hb_hi  = (_Float16*)alloc(NHe*2);     // stage-1 hidden hi, then H2
  _Float16* Hb_lo  = (_Float16*)alloc(NHe*2);
  _Float16* F_hi   = (_Float16*)alloc(NC*2);
  _Float16* F_lo   = (_Float16*)alloc(NC*2);
  _Float16* Wreg = (_Float16*)alloc(2*( (size_t)3*CC_*2 + CC_*2 + 3*4*PEsz ));
  // phase-1 (lang): w13 split [0,8PEsz), w2 split [8PEsz,12PEsz)
  _Float16* w13hi = Wreg;
  _Float16* w13lo = Wreg + 4*PEsz;
  _Float16* w2hi  = Wreg + 8*PEsz;
  _Float16* w2lo  = Wreg + 10*PEsz;
  // phase-2: capw13f overlays dead w13; capw2f overlays dead w2; inw in tail
  _Float16* capw13f = Wreg;
  _Float16* capw2f  = Wreg + 8*PEsz;
  _Float16* inw_hi  = Wreg + 12*PEsz;
  _Float16* inw_lo  = inw_hi + 3*CC_;

  // 1) phase-0 conversions (+ inline language gating, langP, counts=0)
  convA<<<CVA_TOT, 256, 0, stream>>>(
      lang_embed, lang_gw, lang_gb, language,
      lang_w1, lang_w3, lang_w2, x,
      w13hi, w13lo, w2hi, w2lo, xAO_hi, xAO_lo, langP, counts);

  // 2) ffn1 gate
  gemm_gate_split<<<dim3((2*H_)/128, N_/256), 512, 0, stream>>>(
      xAO_hi, xAO_lo, w13hi, w13lo, Hb_hi, Hb_lo);

  // 3) ffn1 out + phase-2 conversions (co-resident)
  ffn1_out_fused<<<768, 256, 0, stream>>>(
      Hb_hi, Hb_lo, w2hi, w2lo, F_hi, F_lo,
      in_w, cap_w1, cap_w3, caption,
      inw_hi, inw_lo, capw13f, cap_hi, cap_lo);

  // 4) Q + KV projections + fold_w (W' = cap_gw . out_w)
  gemm_qkv<<<304, 256, 0, stream>>>(
      F_hi, F_lo, cap_hi, cap_lo, inw_hi, inw_lo, in_b,
      Qh, Ql, KVh, KVl, out_w, cap_gw, out_b, Wp, bp);

  // 5) attention + capw2 conversion (w2 region dead after step 3)
  attn_fused<<<640, 256, 0, stream>>>(Qh, Ql, KVh, KVl, xAO_hi, xAO_lo, cap_w2, capw2f);

  // 6) caption gating directly from AO via W'
  cap_gate<<<N_/8, 256, 0, stream>>>(xAO_hi, xAO_lo, Wp, bp, cap_gb, cap_sel, capP, counts);

  // 7) groups + perm + loss
  finalize<<<2, 256, 0, stream>>>(counts, cap_sel, offs, bmap_e, bmap_s,
                                  bmap_e2, bmap_s2, perm, capP, langP, out + NC);

  // 8) ffn2 gate
  _Float16* H2 = Hb_hi;
  gemm_gate_plain<<<dim3((2*H_)/128, MAXGB2), 512, 0, stream>>>(
      F_hi, capw13f, H2, bmap_e2, bmap_s2, offs, perm);

  // 9) ffn2 out + final sum scatter
  gemm8<2,1,3><<<dim3(C_/128, MAXGB), 256, 0, stream>>>(
      H2, nullptr, capw2f, nullptr, nullptr, out, F_hi, F_lo,
      bmap_e, bmap_s, offs, perm, N_, H_, C_, PEsz);
}